// Round 2
// baseline (6725.960 us; speedup 1.0000x reference)
//
#include <hip/hip_runtime.h>
#include <math.h>

#define NN 50000
#define NE 300000
#define DIN 768
#define DHID 256
#define DOUT 128
#define H0 8
#define D0 32

typedef __attribute__((ext_vector_type(8))) short bf16x8;
typedef __attribute__((ext_vector_type(4))) float f32x4;

__device__ __forceinline__ unsigned short f2bf(float f) {
    unsigned u = __float_as_uint(f);
    unsigned r = (u + 0x7fffu + ((u >> 16) & 1u)) >> 16;
    return (unsigned short)r;
}

// ---------------- MFMA GEMM: C[M,Nc] = A[M,K](f32) @ Bt[Nc,K](bf16)^T + bias ----------------
// BM=BN=128, BK=32, 256 threads (4 waves), each wave 64x64 via 4x4 16x16x32 MFMA frags.
// A converted fp32->bf16 during LDS staging. K%32==0, Nc%128==0.
#define LDK 40  // padded row (shorts): 80B rows keep 16B alignment, ~2-way banks
__global__ __launch_bounds__(256) void gemm_mfma_kernel(
    const float* __restrict__ A, const unsigned short* __restrict__ Bt,
    const float* __restrict__ bias, float* __restrict__ C,
    int M, int K, int Nc)
{
    __shared__ unsigned short As[128][LDK];
    __shared__ unsigned short Bs[128][LDK];
    const int t = threadIdx.x;
    const int lane = t & 63, w = t >> 6;
    const int wr = w >> 1, wc = w & 1;
    const int bm = blockIdx.y * 128, bn = blockIdx.x * 128;

    f32x4 acc[4][4];
    #pragma unroll
    for (int m = 0; m < 4; ++m)
        #pragma unroll
        for (int n = 0; n < 4; ++n)
            acc[m][n] = (f32x4){0.f, 0.f, 0.f, 0.f};

    const int ko = (lane >> 4) * 8;
    const int rA = wr * 64 + (lane & 15);
    const int rB = wc * 64 + (lane & 15);

    for (int k0 = 0; k0 < K; k0 += 32) {
        // stage A: 128 rows x 32 k fp32 -> bf16 (1024 float4 slots)
        #pragma unroll
        for (int i = 0; i < 4; ++i) {
            int s = t + i * 256;
            int r = s >> 3, kg = s & 7;
            int row = bm + r;
            float4 v = make_float4(0.f, 0.f, 0.f, 0.f);
            if (row < M) v = *(const float4*)(A + (size_t)row * K + k0 + kg * 4);
            ushort4 b;
            b.x = f2bf(v.x); b.y = f2bf(v.y); b.z = f2bf(v.z); b.w = f2bf(v.w);
            *(ushort4*)&As[r][kg * 4] = b;
        }
        // stage B: 128 n-rows x 32 k bf16 (512 16B slots)
        #pragma unroll
        for (int i = 0; i < 2; ++i) {
            int s = t + i * 256;
            int n = s >> 2, kg = s & 3;
            *(bf16x8*)&Bs[n][kg * 8] =
                *(const bf16x8*)(Bt + (size_t)(bn + n) * K + k0 + kg * 8);
        }
        __syncthreads();
        bf16x8 afr[4], bfr[4];
        #pragma unroll
        for (int m = 0; m < 4; ++m) afr[m] = *(const bf16x8*)&As[rA + m * 16][ko];
        #pragma unroll
        for (int n = 0; n < 4; ++n) bfr[n] = *(const bf16x8*)&Bs[rB + n * 16][ko];
        #pragma unroll
        for (int m = 0; m < 4; ++m)
            #pragma unroll
            for (int n = 0; n < 4; ++n)
                acc[m][n] = __builtin_amdgcn_mfma_f32_16x16x32_bf16(afr[m], bfr[n], acc[m][n], 0, 0, 0);
        __syncthreads();
    }
    #pragma unroll
    for (int m = 0; m < 4; ++m) {
        #pragma unroll
        for (int j = 0; j < 4; ++j) {
            int row = bm + wr * 64 + m * 16 + (lane >> 4) * 4 + j;
            if (row >= M) continue;
            #pragma unroll
            for (int n = 0; n < 4; ++n) {
                int col = bn + wc * 64 + n * 16 + (lane & 15);
                C[(size_t)row * Nc + col] = acc[m][n][j] + bias[col];
            }
        }
    }
}

// Wt[n*K+k] = bf16(W[k*Nc+n])
__global__ void transconv_kernel(const float* __restrict__ W, unsigned short* __restrict__ Wt,
                                 int K, int Nc)
{
    int gid = blockIdx.x * 256 + threadIdx.x;
    if (gid >= K * Nc) return;
    int k = gid / Nc, n = gid - k * Nc;
    Wt[(size_t)n * K + k] = f2bf(W[gid]);
}

// ---------------- per-node attention score dots: s[n,h] = sum_d x[n,h*D+d]*a[h,d] ----------------
__global__ void node_scores_kernel(const float* __restrict__ x, const float* __restrict__ a,
                                   float* __restrict__ s, int n, int H, int D)
{
    int gid = blockIdx.x * blockDim.x + threadIdx.x;
    if (gid >= n * H) return;
    int node = gid / H, h = gid - node * H;
    const float* xr = x + (size_t)node * H * D + h * D;
    const float* ar = a + h * D;
    float acc = 0.f;
    for (int d = 0; d < D; d += 4) {
        float4 xv = *(const float4*)(xr + d);
        float4 av = *(const float4*)(ar + d);
        acc += xv.x * av.x + xv.y * av.y + xv.z * av.z + xv.w * av.w;
    }
    s[gid] = acc;
}

// monotone float<->uint key for atomic max
__device__ __forceinline__ unsigned fkey(float f) {
    unsigned u = __float_as_uint(f);
    return (u & 0x80000000u) ? ~u : (u | 0x80000000u);
}
__device__ __forceinline__ float funkey(unsigned k) {
    unsigned u = (k & 0x80000000u) ? (k & 0x7fffffffu) : ~k;
    return __uint_as_float(u);
}

// per edge: al[h] = leaky_relu(ssrc[src,h]+sdst[dst,h]); segment max via atomicMax
__global__ void edge_max_kernel(const int* __restrict__ src, const int* __restrict__ dst,
                                const float* __restrict__ ssrc, const float* __restrict__ sdst,
                                float* __restrict__ al, unsigned* __restrict__ amax,
                                int E, int H)
{
    int e = blockIdx.x * blockDim.x + threadIdx.x;
    if (e >= E) return;
    int s = src[e], d = dst[e];
    for (int h = 0; h < H; ++h) {
        float v = ssrc[s * H + h] + sdst[d * H + h];
        v = (v >= 0.f) ? v : 0.2f * v;
        al[e * H + h] = v;
        atomicMax(&amax[d * H + h], fkey(v));
    }
}

// per edge: ex[h] = exp(al[h] - amax[dst,h]); denom += ex
__global__ void edge_exp_kernel(const int* __restrict__ dst, float* __restrict__ al,
                                const unsigned* __restrict__ amax, float* __restrict__ denom,
                                int E, int H)
{
    int e = blockIdx.x * blockDim.x + threadIdx.x;
    if (e >= E) return;
    int d = dst[e];
    for (int h = 0; h < H; ++h) {
        float m = funkey(amax[d * H + h]);
        float ex = expf(al[e * H + h] - m);
        al[e * H + h] = ex;
        atomicAdd(&denom[d * H + h], ex);
    }
}

// per (edge, float4): agg[dst, c..c+3] += x[src, c..c+3] * ex/(denom+1e-16)
__global__ void edge_scatter_kernel(const int* __restrict__ src, const int* __restrict__ dst,
                                    const float* __restrict__ x, const float* __restrict__ ex,
                                    const float* __restrict__ denom, float* __restrict__ agg,
                                    int E, int H, int D)
{
    int C4 = (H * D) >> 2;
    long long gid = (long long)blockIdx.x * blockDim.x + threadIdx.x;
    if (gid >= (long long)E * C4) return;
    int e = (int)(gid / C4), c4 = (int)(gid - (long long)e * C4);
    int c = c4 * 4;
    int h = c / D;
    int s = src[e], d = dst[e];
    float alpha = ex[e * H + h] / (denom[d * H + h] + 1e-16f);
    float4 xv = *(const float4*)(x + (size_t)s * (H * D) + c);
    float* ap = agg + (size_t)d * (H * D) + c;
    atomicAdd(ap + 0, xv.x * alpha);
    atomicAdd(ap + 1, xv.y * alpha);
    atomicAdd(ap + 2, xv.z * alpha);
    atomicAdd(ap + 3, xv.w * alpha);
}

// partial[c] += sum_{16 rows} tanh( relu(x_row) @ Wk + bk )[c]
__global__ void sem_tanh_mean_kernel(const float* __restrict__ x, const float* __restrict__ Wk,
                                     const float* __restrict__ bk, float* __restrict__ partial,
                                     int n, int C)
{
    __shared__ float rows[16][256];
    int c = threadIdx.x;
    int r0 = blockIdx.x * 16;
    for (int r = 0; r < 16; ++r)
        rows[r][c] = fmaxf(x[(size_t)(r0 + r) * C + c], 0.f);
    __syncthreads();
    float acc[16];
    float b = bk[c];
    #pragma unroll
    for (int r = 0; r < 16; ++r) acc[r] = b;
    for (int k = 0; k < C; ++k) {
        float w = Wk[(size_t)k * C + c];
        #pragma unroll
        for (int r = 0; r < 16; ++r) acc[r] += rows[r][k] * w;
    }
    float s = 0.f;
    #pragma unroll
    for (int r = 0; r < 16; ++r) s += tanhf(acc[r]);
    atomicAdd(&partial[c], s);
}

__global__ void sem_weights_kernel(const float* __restrict__ partial, const float* __restrict__ q,
                                   float* __restrict__ w, int C, int n)
{
    if (threadIdx.x != 0 || blockIdx.x != 0) return;
    float inv = 1.f / (float)n;
    float s0 = 0.f, s1 = 0.f;
    for (int c = 0; c < C; ++c) {
        s0 += q[c] * partial[c] * inv;
        s1 += q[c] * partial[C + c] * inv;
    }
    float m = fmaxf(s0, s1);
    float e0 = expf(s0 - m), e1 = expf(s1 - m);
    float den = e0 + e1;
    w[0] = e0 / den;
    w[1] = e1 / den;
}

// out = w0*relu(a) + w1*relu(b)   (ELU skipped: result provably >= 0)
__global__ void combine2_kernel(const float* __restrict__ a, const float* __restrict__ b,
                                const float* __restrict__ w, float* __restrict__ out, long long n)
{
    long long gid = (long long)blockIdx.x * blockDim.x + threadIdx.x;
    if (gid >= n) return;
    out[gid] = w[0] * fmaxf(a[gid], 0.f) + w[1] * fmaxf(b[gid], 0.f);
}

__global__ void relu_copy_kernel(const float* __restrict__ a, float* __restrict__ out, long long n)
{
    long long gid = (long long)blockIdx.x * blockDim.x + threadIdx.x;
    if (gid >= n) return;
    out[gid] = fmaxf(a[gid], 0.f);
}

__global__ __launch_bounds__(128) void final_norm_kernel(
    const float* __restrict__ aggW, const float* __restrict__ aggC,
    const float* __restrict__ aggB, const float* __restrict__ w,
    float* __restrict__ out)
{
    __shared__ float red[128];
    int row = blockIdx.x;
    int c = threadIdx.x;
    float v;
    if (row < NN) {
        size_t i = (size_t)row * DOUT + c;
        v = w[0] * fmaxf(aggW[i], 0.f) + w[1] * fmaxf(aggC[i], 0.f);
    } else {
        size_t i = (size_t)(row - NN) * DOUT + c;
        v = fmaxf(aggB[i], 0.f);
    }
    red[c] = v * v;
    __syncthreads();
    for (int s = 64; s > 0; s >>= 1) {
        if (c < s) red[c] += red[c + s];
        __syncthreads();
    }
    float norm = sqrtf(red[0]);
    out[(size_t)row * DOUT + c] = v / fmaxf(norm, 1e-12f);
}

// ------------------------------------------------------------------
static void process_rel(const float* xsrc, const float* xdst,
                        const float* a_s, const float* a_d,
                        const int* ei, int H, int D,
                        float* agg, float* escr, float* ssrc, float* sdst,
                        unsigned* amax, float* denom, hipStream_t stream)
{
    const int* src = ei;
    const int* dst = ei + NE;
    hipMemsetAsync(amax, 0, (size_t)NN * H * sizeof(unsigned), stream);
    hipMemsetAsync(denom, 0, (size_t)NN * H * sizeof(float), stream);
    int nt = NN * H;
    node_scores_kernel<<<(nt + 255) / 256, 256, 0, stream>>>(xsrc, a_s, ssrc, NN, H, D);
    node_scores_kernel<<<(nt + 255) / 256, 256, 0, stream>>>(xdst, a_d, sdst, NN, H, D);
    edge_max_kernel<<<(NE + 255) / 256, 256, 0, stream>>>(src, dst, ssrc, sdst, escr, amax, NE, H);
    edge_exp_kernel<<<(NE + 255) / 256, 256, 0, stream>>>(dst, escr, amax, denom, NE, H);
    long long total = (long long)NE * ((H * D) >> 2);
    edge_scatter_kernel<<<(int)((total + 255) / 256), 256, 0, stream>>>(src, dst, xsrc, escr, denom, agg, NE, H, D);
}

extern "C" void kernel_launch(void* const* d_in, const int* in_sizes, int n_in,
                              void* d_out, int out_size, void* d_ws, size_t ws_size,
                              hipStream_t stream)
{
    const float* x_paper   = (const float*)d_in[0];
    const float* x_author  = (const float*)d_in[1];
    const int*   ei_writes = (const int*)d_in[2];
    const int*   ei_wb     = (const int*)d_in[3];
    const int*   ei_cites  = (const int*)d_in[4];
    const float* W0p = (const float*)d_in[5];  const float* b0p = (const float*)d_in[6];
    const float* W0a = (const float*)d_in[7];  const float* b0a = (const float*)d_in[8];
    const float* a0s_w  = (const float*)d_in[9];  const float* a0d_w  = (const float*)d_in[10];
    const float* a0s_wb = (const float*)d_in[11]; const float* a0d_wb = (const float*)d_in[12];
    const float* a0s_c  = (const float*)d_in[13]; const float* a0d_c  = (const float*)d_in[14];
    const float* Wk0 = (const float*)d_in[15]; const float* bk0 = (const float*)d_in[16];
    const float* q0  = (const float*)d_in[17];
    const float* W1p = (const float*)d_in[18]; const float* b1p = (const float*)d_in[19];
    const float* W1a = (const float*)d_in[20]; const float* b1a = (const float*)d_in[21];
    const float* a1s_w  = (const float*)d_in[22]; const float* a1d_w  = (const float*)d_in[23];
    const float* a1s_wb = (const float*)d_in[24]; const float* a1d_wb = (const float*)d_in[25];
    const float* a1s_c  = (const float*)d_in[26]; const float* a1d_c  = (const float*)d_in[27];
    const float* Wk1 = (const float*)d_in[28]; const float* bk1 = (const float*)d_in[29];
    const float* q1  = (const float*)d_in[30];

    float* out = (float*)d_out;

    // ---- workspace layout (floats) ----
    float* w    = (float*)d_ws;
    float* xhP  = w;                                  // N*256
    float* xhA  = xhP + (size_t)NN * DHID;            // N*256
    float* aggW = xhA + (size_t)NN * DHID;            // N*256
    float* aggC = aggW + (size_t)NN * DHID;           // N*256
    float* aggB = aggC + (size_t)NN * DHID;           // N*256
    float* escr = aggB + (size_t)NN * DHID;           // E*8
    float* ssrc = escr + (size_t)NE * H0;             // N*8
    float* sdst = ssrc + (size_t)NN * H0;             // N*8
    unsigned* amax = (unsigned*)(sdst + (size_t)NN * H0); // N*8
    float* denom = (float*)amax + (size_t)NN * H0;    // N*8
    float* tsum  = denom + (size_t)NN * H0;           // 512
    float* wsem  = tsum + 512;                        // 2 (padded)

    // bf16 transposed weights, aliased over escr (dead at GEMM time)
    unsigned short* wt0p = (unsigned short*)escr;               // 256*768
    unsigned short* wt0a = wt0p + (size_t)DHID * DIN;           // 256*768
    unsigned short* wt1p = (unsigned short*)escr;               // 128*256 (written after L0 rels)
    unsigned short* wt1a = wt1p + (size_t)DOUT * DHID;

    // layer-1 aliases (over dead layer-0 buffers)
    float* x1P   = aggW;
    float* x1A   = aggC;
    float* agg1W = aggB;
    float* agg1C = aggB + (size_t)NN * DOUT;
    float* agg1B = xhP;

    // ================= layer 0 =================
    hipMemsetAsync(aggW, 0, 3 * (size_t)NN * DHID * sizeof(float), stream); // aggW,aggC,aggB
    hipMemsetAsync(tsum, 0, 512 * sizeof(float), stream);

    transconv_kernel<<<(DIN * DHID + 255) / 256, 256, 0, stream>>>(W0p, wt0p, DIN, DHID);
    transconv_kernel<<<(DIN * DHID + 255) / 256, 256, 0, stream>>>(W0a, wt0a, DIN, DHID);

    dim3 g0(DHID / 128, (NN + 127) / 128);
    gemm_mfma_kernel<<<g0, 256, 0, stream>>>(x_paper,  wt0p, b0p, xhP, NN, DIN, DHID);
    gemm_mfma_kernel<<<g0, 256, 0, stream>>>(x_author, wt0a, b0a, xhA, NN, DIN, DHID);

    // writes: author -> paper ; written_by: paper -> author ; cites: paper -> paper
    process_rel(xhA, xhP, a0s_w,  a0d_w,  ei_writes, H0, D0, aggW, escr, ssrc, sdst, amax, denom, stream);
    process_rel(xhP, xhA, a0s_wb, a0d_wb, ei_wb,     H0, D0, aggB, escr, ssrc, sdst, amax, denom, stream);
    process_rel(xhP, xhP, a0s_c,  a0d_c,  ei_cites,  H0, D0, aggC, escr, ssrc, sdst, amax, denom, stream);

    // semantic attention (paper only: M=2; author M=1 -> identity)
    sem_tanh_mean_kernel<<<NN / 16, DHID, 0, stream>>>(aggW, Wk0, bk0, tsum,        NN, DHID);
    sem_tanh_mean_kernel<<<NN / 16, DHID, 0, stream>>>(aggC, Wk0, bk0, tsum + DHID, NN, DHID);
    sem_weights_kernel<<<1, 64, 0, stream>>>(tsum, q0, wsem, DHID, NN);

    long long nel0 = (long long)NN * DHID;
    combine2_kernel<<<(int)((nel0 + 255) / 256), 256, 0, stream>>>(aggW, aggC, wsem, xhP, nel0); // h_paper
    relu_copy_kernel<<<(int)((nel0 + 255) / 256), 256, 0, stream>>>(aggB, xhA, nel0);            // h_author

    // ================= layer 1 =================
    transconv_kernel<<<(DHID * DOUT + 255) / 256, 256, 0, stream>>>(W1p, wt1p, DHID, DOUT);
    transconv_kernel<<<(DHID * DOUT + 255) / 256, 256, 0, stream>>>(W1a, wt1a, DHID, DOUT);

    dim3 g1(DOUT / 128, (NN + 127) / 128);
    gemm_mfma_kernel<<<g1, 256, 0, stream>>>(xhP, wt1p, b1p, x1P, NN, DHID, DOUT);
    gemm_mfma_kernel<<<g1, 256, 0, stream>>>(xhA, wt1a, b1a, x1A, NN, DHID, DOUT);

    hipMemsetAsync(agg1W, 0, 2 * (size_t)NN * DOUT * sizeof(float), stream);
    hipMemsetAsync(agg1B, 0, (size_t)NN * DOUT * sizeof(float), stream);
    hipMemsetAsync(tsum, 0, 2 * DOUT * sizeof(float), stream);

    process_rel(x1A, x1P, a1s_w,  a1d_w,  ei_writes, 1, DOUT, agg1W, escr, ssrc, sdst, amax, denom, stream);
    process_rel(x1P, x1A, a1s_wb, a1d_wb, ei_wb,     1, DOUT, agg1B, escr, ssrc, sdst, amax, denom, stream);
    process_rel(x1P, x1P, a1s_c,  a1d_c,  ei_cites,  1, DOUT, agg1C, escr, ssrc, sdst, amax, denom, stream);

    sem_tanh_mean_kernel<<<NN / 16, DOUT, 0, stream>>>(agg1W, Wk1, bk1, tsum,        NN, DOUT);
    sem_tanh_mean_kernel<<<NN / 16, DOUT, 0, stream>>>(agg1C, Wk1, bk1, tsum + DOUT, NN, DOUT);
    sem_weights_kernel<<<1, 64, 0, stream>>>(tsum, q1, wsem, DOUT, NN);

    final_norm_kernel<<<2 * NN, 128, 0, stream>>>(agg1W, agg1C, agg1B, wsem, out);
}

// Round 3
// 1993.701 us; speedup vs baseline: 3.3736x; 3.3736x over previous
//
#include <hip/hip_runtime.h>
#include <math.h>

#define NN 50000
#define NE 300000
#define DIN 768
#define DHID 256
#define DOUT 128
#define H0 8
#define D0 32

typedef __attribute__((ext_vector_type(8))) short bf16x8;
typedef __attribute__((ext_vector_type(4))) float f32x4;

__device__ __forceinline__ unsigned short f2bf(float f) {
    unsigned u = __float_as_uint(f);
    unsigned r = (u + 0x7fffu + ((u >> 16) & 1u)) >> 16;
    return (unsigned short)r;
}

// ---------------- MFMA GEMM: C[M,Nc] = A[M,K](f32) @ Bt[Nc,K](bf16)^T + bias ----------------
#define LDK 40
__global__ __launch_bounds__(256) void gemm_mfma_kernel(
    const float* __restrict__ A, const unsigned short* __restrict__ Bt,
    const float* __restrict__ bias, float* __restrict__ C,
    int M, int K, int Nc)
{
    __shared__ unsigned short As[128][LDK];
    __shared__ unsigned short Bs[128][LDK];
    const int t = threadIdx.x;
    const int lane = t & 63, w = t >> 6;
    const int wr = w >> 1, wc = w & 1;
    const int bm = blockIdx.y * 128, bn = blockIdx.x * 128;

    f32x4 acc[4][4];
    #pragma unroll
    for (int m = 0; m < 4; ++m)
        #pragma unroll
        for (int n = 0; n < 4; ++n)
            acc[m][n] = (f32x4){0.f, 0.f, 0.f, 0.f};

    const int ko = (lane >> 4) * 8;
    const int rA = wr * 64 + (lane & 15);
    const int rB = wc * 64 + (lane & 15);

    for (int k0 = 0; k0 < K; k0 += 32) {
        #pragma unroll
        for (int i = 0; i < 4; ++i) {
            int s = t + i * 256;
            int r = s >> 3, kg = s & 7;
            int row = bm + r;
            float4 v = make_float4(0.f, 0.f, 0.f, 0.f);
            if (row < M) v = *(const float4*)(A + (size_t)row * K + k0 + kg * 4);
            ushort4 b;
            b.x = f2bf(v.x); b.y = f2bf(v.y); b.z = f2bf(v.z); b.w = f2bf(v.w);
            *(ushort4*)&As[r][kg * 4] = b;
        }
        #pragma unroll
        for (int i = 0; i < 2; ++i) {
            int s = t + i * 256;
            int n = s >> 2, kg = s & 3;
            *(bf16x8*)&Bs[n][kg * 8] =
                *(const bf16x8*)(Bt + (size_t)(bn + n) * K + k0 + kg * 8);
        }
        __syncthreads();
        bf16x8 afr[4], bfr[4];
        #pragma unroll
        for (int m = 0; m < 4; ++m) afr[m] = *(const bf16x8*)&As[rA + m * 16][ko];
        #pragma unroll
        for (int n = 0; n < 4; ++n) bfr[n] = *(const bf16x8*)&Bs[rB + n * 16][ko];
        #pragma unroll
        for (int m = 0; m < 4; ++m)
            #pragma unroll
            for (int n = 0; n < 4; ++n)
                acc[m][n] = __builtin_amdgcn_mfma_f32_16x16x32_bf16(afr[m], bfr[n], acc[m][n], 0, 0, 0);
        __syncthreads();
    }
    #pragma unroll
    for (int m = 0; m < 4; ++m) {
        #pragma unroll
        for (int j = 0; j < 4; ++j) {
            int row = bm + wr * 64 + m * 16 + (lane >> 4) * 4 + j;
            if (row >= M) continue;
            #pragma unroll
            for (int n = 0; n < 4; ++n) {
                int col = bn + wc * 64 + n * 16 + (lane & 15);
                C[(size_t)row * Nc + col] = acc[m][n][j] + bias[col];
            }
        }
    }
}

// Wt[n*K+k] = bf16(W[k*Nc+n])
__global__ void transconv_kernel(const float* __restrict__ W, unsigned short* __restrict__ Wt,
                                 int K, int Nc)
{
    int gid = blockIdx.x * 256 + threadIdx.x;
    if (gid >= K * Nc) return;
    int k = gid / Nc, n = gid - k * Nc;
    Wt[(size_t)n * K + k] = f2bf(W[gid]);
}

// ---------------- CSR build (per relation, shared across both layers) ----------------
__global__ void hist_kernel(const int* __restrict__ dst, int* __restrict__ deg, int E)
{
    int e = blockIdx.x * 256 + threadIdx.x;
    if (e < E) atomicAdd(&deg[dst[e]], 1);
}

__global__ void block_sum_kernel(const int* __restrict__ deg, int* __restrict__ bsum, int n)
{
    __shared__ int buf[256];
    int i = blockIdx.x * 256 + threadIdx.x;
    buf[threadIdx.x] = (i < n) ? deg[i] : 0;
    __syncthreads();
    for (int s = 128; s > 0; s >>= 1) {
        if (threadIdx.x < s) buf[threadIdx.x] += buf[threadIdx.x + s];
        __syncthreads();
    }
    if (threadIdx.x == 0) bsum[blockIdx.x] = buf[0];
}

// single block, nb <= 256: exclusive scan of block sums
__global__ void scan_bsum_kernel(const int* __restrict__ bsum, int* __restrict__ boff, int nb)
{
    __shared__ int buf[256];
    int tid = threadIdx.x;
    int v = (tid < nb) ? bsum[tid] : 0;
    buf[tid] = v;
    __syncthreads();
    for (int off = 1; off < 256; off <<= 1) {
        int t = (tid >= off) ? buf[tid - off] : 0;
        __syncthreads();
        buf[tid] += t;
        __syncthreads();
    }
    if (tid < nb) boff[tid] = buf[tid] - v;
}

__global__ void scan_final_kernel(const int* __restrict__ deg, const int* __restrict__ boff,
                                  int* __restrict__ offs, int n)
{
    __shared__ int buf[256];
    int tid = threadIdx.x, b = blockIdx.x;
    int i = b * 256 + tid;
    int v = (i < n) ? deg[i] : 0;
    buf[tid] = v;
    __syncthreads();
    for (int off = 1; off < 256; off <<= 1) {
        int t = (tid >= off) ? buf[tid - off] : 0;
        __syncthreads();
        buf[tid] += t;
        __syncthreads();
    }
    if (i < n) offs[i] = boff[b] + buf[tid] - v;
    if (i == n - 1) offs[n] = boff[b] + buf[tid];
}

__global__ void place_kernel(const int* __restrict__ src, const int* __restrict__ dst,
                             const int* __restrict__ offs, int* __restrict__ cnt,
                             int* __restrict__ esrc, int E)
{
    int e = blockIdx.x * 256 + threadIdx.x;
    if (e >= E) return;
    int d = dst[e];
    int p = offs[d] + atomicAdd(&cnt[d], 1);
    esrc[p] = src[e];
}

// ---------------- per-node attention score dots: s[n,h] = sum_d x[n,h*D+d]*a[h,d] ----------------
__global__ void node_scores_kernel(const float* __restrict__ x, const float* __restrict__ a,
                                   float* __restrict__ s, int n, int H, int D)
{
    int gid = blockIdx.x * blockDim.x + threadIdx.x;
    if (gid >= n * H) return;
    int node = gid / H, h = gid - node * H;
    const float* xr = x + (size_t)node * H * D + h * D;
    const float* ar = a + h * D;
    float acc = 0.f;
    for (int d = 0; d < D; d += 4) {
        float4 xv = *(const float4*)(xr + d);
        float4 av = *(const float4*)(ar + d);
        acc += xv.x * av.x + xv.y * av.y + xv.z * av.z + xv.w * av.w;
    }
    s[gid] = acc;
}

// ---------------- fused GAT gather: one block per dst node, blockDim == C ----------------
// pass1: segment max over in-edges (per head); pass2: exp-sum + weighted gather.
__global__ void gather_attn_kernel(const int* __restrict__ offs, const int* __restrict__ esrc,
                                   const float* __restrict__ x, const float* __restrict__ ssrc,
                                   const float* __restrict__ sdst, float* __restrict__ outp,
                                   int C, int H, int dsh)
{
    int d = blockIdx.x;
    int c = threadIdx.x;
    int h = c >> dsh;
    int beg = offs[d], end = offs[d + 1];
    float sd = sdst[d * H + h];
    float m = -INFINITY;
    for (int i = beg; i < end; ++i) {
        int s = esrc[i];
        float v = ssrc[s * H + h] + sd;
        v = (v >= 0.f) ? v : 0.2f * v;
        m = fmaxf(m, v);
    }
    float den = 0.f, acc = 0.f;
    for (int i = beg; i < end; ++i) {
        int s = esrc[i];
        float v = ssrc[s * H + h] + sd;
        v = (v >= 0.f) ? v : 0.2f * v;
        float ex = expf(v - m);
        den += ex;
        acc += ex * x[(size_t)s * C + c];
    }
    outp[(size_t)d * C + c] = acc / (den + 1e-16f);
}

// partial[c] += sum_{16 rows} tanh( relu(x_row) @ Wk + bk )[c]
__global__ void sem_tanh_mean_kernel(const float* __restrict__ x, const float* __restrict__ Wk,
                                     const float* __restrict__ bk, float* __restrict__ partial,
                                     int n, int C)
{
    __shared__ float rows[16][256];
    int c = threadIdx.x;
    int r0 = blockIdx.x * 16;
    for (int r = 0; r < 16; ++r)
        rows[r][c] = fmaxf(x[(size_t)(r0 + r) * C + c], 0.f);
    __syncthreads();
    float acc[16];
    float b = bk[c];
    #pragma unroll
    for (int r = 0; r < 16; ++r) acc[r] = b;
    for (int k = 0; k < C; ++k) {
        float w = Wk[(size_t)k * C + c];
        #pragma unroll
        for (int r = 0; r < 16; ++r) acc[r] += rows[r][k] * w;
    }
    float s = 0.f;
    #pragma unroll
    for (int r = 0; r < 16; ++r) s += tanhf(acc[r]);
    atomicAdd(&partial[c], s);
}

__global__ void sem_weights_kernel(const float* __restrict__ partial, const float* __restrict__ q,
                                   float* __restrict__ w, int C, int n)
{
    if (threadIdx.x != 0 || blockIdx.x != 0) return;
    float inv = 1.f / (float)n;
    float s0 = 0.f, s1 = 0.f;
    for (int c = 0; c < C; ++c) {
        s0 += q[c] * partial[c] * inv;
        s1 += q[c] * partial[C + c] * inv;
    }
    float m = fmaxf(s0, s1);
    float e0 = expf(s0 - m), e1 = expf(s1 - m);
    float den = e0 + e1;
    w[0] = e0 / den;
    w[1] = e1 / den;
}

__global__ void combine2_kernel(const float* __restrict__ a, const float* __restrict__ b,
                                const float* __restrict__ w, float* __restrict__ out, long long n)
{
    long long gid = (long long)blockIdx.x * blockDim.x + threadIdx.x;
    if (gid >= n) return;
    out[gid] = w[0] * fmaxf(a[gid], 0.f) + w[1] * fmaxf(b[gid], 0.f);
}

__global__ void relu_copy_kernel(const float* __restrict__ a, float* __restrict__ out, long long n)
{
    long long gid = (long long)blockIdx.x * blockDim.x + threadIdx.x;
    if (gid >= n) return;
    out[gid] = fmaxf(a[gid], 0.f);
}

__global__ __launch_bounds__(128) void final_norm_kernel(
    const float* __restrict__ aggW, const float* __restrict__ aggC,
    const float* __restrict__ aggB, const float* __restrict__ w,
    float* __restrict__ out)
{
    __shared__ float red[128];
    int row = blockIdx.x;
    int c = threadIdx.x;
    float v;
    if (row < NN) {
        size_t i = (size_t)row * DOUT + c;
        v = w[0] * fmaxf(aggW[i], 0.f) + w[1] * fmaxf(aggC[i], 0.f);
    } else {
        size_t i = (size_t)(row - NN) * DOUT + c;
        v = fmaxf(aggB[i], 0.f);
    }
    red[c] = v * v;
    __syncthreads();
    for (int s = 64; s > 0; s >>= 1) {
        if (c < s) red[c] += red[c + s];
        __syncthreads();
    }
    float norm = sqrtf(red[0]);
    out[(size_t)row * DOUT + c] = v / fmaxf(norm, 1e-12f);
}

// ------------------------------------------------------------------
static void build_csr(const int* ei, int* offs, int* esrc, int* deg, int* bsum, int* boff,
                      hipStream_t stream)
{
    const int* src = ei;
    const int* dst = ei + NE;
    const int NB = (NN + 255) / 256;  // 196
    hipMemsetAsync(deg, 0, NN * sizeof(int), stream);
    hist_kernel<<<(NE + 255) / 256, 256, 0, stream>>>(dst, deg, NE);
    block_sum_kernel<<<NB, 256, 0, stream>>>(deg, bsum, NN);
    scan_bsum_kernel<<<1, 256, 0, stream>>>(bsum, boff, NB);
    scan_final_kernel<<<NB, 256, 0, stream>>>(deg, boff, offs, NN);
    hipMemsetAsync(deg, 0, NN * sizeof(int), stream);  // reuse as cnt
    place_kernel<<<(NE + 255) / 256, 256, 0, stream>>>(src, dst, offs, deg, esrc, NE);
}

static void process_rel(const float* xsrc, const float* xdst,
                        const float* a_s, const float* a_d,
                        const int* offs, const int* esrc, int H, int D,
                        float* agg, float* ssrc, float* sdst, hipStream_t stream)
{
    const int C = H * D;
    int nt = NN * H;
    node_scores_kernel<<<(nt + 255) / 256, 256, 0, stream>>>(xsrc, a_s, ssrc, NN, H, D);
    node_scores_kernel<<<(nt + 255) / 256, 256, 0, stream>>>(xdst, a_d, sdst, NN, H, D);
    int dsh = (D == 32) ? 5 : 7;
    gather_attn_kernel<<<NN, C, 0, stream>>>(offs, esrc, xsrc, ssrc, sdst, agg, C, H, dsh);
}

extern "C" void kernel_launch(void* const* d_in, const int* in_sizes, int n_in,
                              void* d_out, int out_size, void* d_ws, size_t ws_size,
                              hipStream_t stream)
{
    const float* x_paper   = (const float*)d_in[0];
    const float* x_author  = (const float*)d_in[1];
    const int*   ei_writes = (const int*)d_in[2];
    const int*   ei_wb     = (const int*)d_in[3];
    const int*   ei_cites  = (const int*)d_in[4];
    const float* W0p = (const float*)d_in[5];  const float* b0p = (const float*)d_in[6];
    const float* W0a = (const float*)d_in[7];  const float* b0a = (const float*)d_in[8];
    const float* a0s_w  = (const float*)d_in[9];  const float* a0d_w  = (const float*)d_in[10];
    const float* a0s_wb = (const float*)d_in[11]; const float* a0d_wb = (const float*)d_in[12];
    const float* a0s_c  = (const float*)d_in[13]; const float* a0d_c  = (const float*)d_in[14];
    const float* Wk0 = (const float*)d_in[15]; const float* bk0 = (const float*)d_in[16];
    const float* q0  = (const float*)d_in[17];
    const float* W1p = (const float*)d_in[18]; const float* b1p = (const float*)d_in[19];
    const float* W1a = (const float*)d_in[20]; const float* b1a = (const float*)d_in[21];
    const float* a1s_w  = (const float*)d_in[22]; const float* a1d_w  = (const float*)d_in[23];
    const float* a1s_wb = (const float*)d_in[24]; const float* a1d_wb = (const float*)d_in[25];
    const float* a1s_c  = (const float*)d_in[26]; const float* a1d_c  = (const float*)d_in[27];
    const float* Wk1 = (const float*)d_in[28]; const float* bk1 = (const float*)d_in[29];
    const float* q1  = (const float*)d_in[30];

    float* out = (float*)d_out;

    // ---- workspace layout ----
    float* xhP  = (float*)d_ws;                       // N*256
    float* xhA  = xhP + (size_t)NN * DHID;            // N*256
    float* aggW = xhA + (size_t)NN * DHID;            // N*256
    float* aggC = aggW + (size_t)NN * DHID;           // N*256
    float* aggB = aggC + (size_t)NN * DHID;           // N*256
    float* ssrc = aggB + (size_t)NN * DHID;           // N*8
    float* sdst = ssrc + (size_t)NN * H0;             // N*8
    float* tsum = sdst + (size_t)NN * H0;             // 512
    float* wsem = tsum + 512;                         // 8 pad
    int* ip      = (int*)(wsem + 8);
    int* offsW   = ip;               ip += NN + 4;    // CSR offsets (NN+1, padded)
    int* offsWB  = ip;               ip += NN + 4;
    int* offsC   = ip;               ip += NN + 4;
    int* esrcW   = ip;               ip += NE;
    int* esrcWB  = ip;               ip += NE;
    int* esrcC   = ip;               ip += NE;
    int* deg     = ip;               ip += NN;
    int* bsum    = ip;               ip += 256;
    int* boff    = ip;               ip += 256;
    unsigned short* wt0p = (unsigned short*)ip;       // 256*768 bf16
    unsigned short* wt0a = wt0p + (size_t)DHID * DIN;
    unsigned short* wt1p = wt0p;                      // reuse after L0 GEMMs
    unsigned short* wt1a = wt1p + (size_t)DOUT * DHID;

    // layer-1 aliases (over dead layer-0 buffers)
    float* x1P   = aggW;
    float* x1A   = aggC;
    float* agg1W = aggB;
    float* agg1C = aggB + (size_t)NN * DOUT;
    float* agg1B = xhP;

    // ---- CSR build (shared by both layers) ----
    build_csr(ei_writes, offsW,  esrcW,  deg, bsum, boff, stream);
    build_csr(ei_wb,     offsWB, esrcWB, deg, bsum, boff, stream);
    build_csr(ei_cites,  offsC,  esrcC,  deg, bsum, boff, stream);

    // ================= layer 0 =================
    hipMemsetAsync(tsum, 0, 512 * sizeof(float), stream);
    transconv_kernel<<<(DIN * DHID + 255) / 256, 256, 0, stream>>>(W0p, wt0p, DIN, DHID);
    transconv_kernel<<<(DIN * DHID + 255) / 256, 256, 0, stream>>>(W0a, wt0a, DIN, DHID);

    dim3 g0(DHID / 128, (NN + 127) / 128);
    gemm_mfma_kernel<<<g0, 256, 0, stream>>>(x_paper,  wt0p, b0p, xhP, NN, DIN, DHID);
    gemm_mfma_kernel<<<g0, 256, 0, stream>>>(x_author, wt0a, b0a, xhA, NN, DIN, DHID);

    // writes: author->paper ; written_by: paper->author ; cites: paper->paper
    process_rel(xhA, xhP, a0s_w,  a0d_w,  offsW,  esrcW,  H0, D0, aggW, ssrc, sdst, stream);
    process_rel(xhP, xhA, a0s_wb, a0d_wb, offsWB, esrcWB, H0, D0, aggB, ssrc, sdst, stream);
    process_rel(xhP, xhP, a0s_c,  a0d_c,  offsC,  esrcC,  H0, D0, aggC, ssrc, sdst, stream);

    // semantic attention (paper: M=2; author: M=1 -> identity)
    sem_tanh_mean_kernel<<<NN / 16, DHID, 0, stream>>>(aggW, Wk0, bk0, tsum,        NN, DHID);
    sem_tanh_mean_kernel<<<NN / 16, DHID, 0, stream>>>(aggC, Wk0, bk0, tsum + DHID, NN, DHID);
    sem_weights_kernel<<<1, 64, 0, stream>>>(tsum, q0, wsem, DHID, NN);

    long long nel0 = (long long)NN * DHID;
    combine2_kernel<<<(int)((nel0 + 255) / 256), 256, 0, stream>>>(aggW, aggC, wsem, xhP, nel0);
    relu_copy_kernel<<<(int)((nel0 + 255) / 256), 256, 0, stream>>>(aggB, xhA, nel0);

    // ================= layer 1 =================
    transconv_kernel<<<(DHID * DOUT + 255) / 256, 256, 0, stream>>>(W1p, wt1p, DHID, DOUT);
    transconv_kernel<<<(DHID * DOUT + 255) / 256, 256, 0, stream>>>(W1a, wt1a, DHID, DOUT);

    dim3 g1(DOUT / 128, (NN + 127) / 128);
    gemm_mfma_kernel<<<g1, 256, 0, stream>>>(xhP, wt1p, b1p, x1P, NN, DHID, DOUT);
    gemm_mfma_kernel<<<g1, 256, 0, stream>>>(xhA, wt1a, b1a, x1A, NN, DHID, DOUT);

    hipMemsetAsync(tsum, 0, 2 * DOUT * sizeof(float), stream);

    process_rel(x1A, x1P, a1s_w,  a1d_w,  offsW,  esrcW,  1, DOUT, agg1W, ssrc, sdst, stream);
    process_rel(x1P, x1A, a1s_wb, a1d_wb, offsWB, esrcWB, 1, DOUT, agg1B, ssrc, sdst, stream);
    process_rel(x1P, x1P, a1s_c,  a1d_c,  offsC,  esrcC,  1, DOUT, agg1C, ssrc, sdst, stream);

    sem_tanh_mean_kernel<<<NN / 16, DOUT, 0, stream>>>(agg1W, Wk1, bk1, tsum,        NN, DOUT);
    sem_tanh_mean_kernel<<<NN / 16, DOUT, 0, stream>>>(agg1C, Wk1, bk1, tsum + DOUT, NN, DOUT);
    sem_weights_kernel<<<1, 64, 0, stream>>>(tsum, q1, wsem, DOUT, NN);

    final_norm_kernel<<<2 * NN, 128, 0, stream>>>(agg1W, agg1C, agg1B, wsem, out);
}

// Round 4
// 1504.821 us; speedup vs baseline: 4.4696x; 1.3249x over previous
//
#include <hip/hip_runtime.h>
#include <math.h>

#define NN 50000
#define NE 300000
#define DIN 768
#define DHID 256
#define DOUT 128
#define H0 8
#define D0 32

typedef __attribute__((ext_vector_type(8))) short bf16x8;
typedef __attribute__((ext_vector_type(4))) float f32x4;

__device__ __forceinline__ unsigned short f2bf(float f) {
    unsigned u = __float_as_uint(f);
    unsigned r = (u + 0x7fffu + ((u >> 16) & 1u)) >> 16;
    return (unsigned short)r;
}

// ---------------- MFMA GEMM: C[M,Nc] = A[M,K](f32) @ Bt[Nc,K](bf16)^T + bias ----------------
#define LDK 40
__global__ __launch_bounds__(256) void gemm_mfma_kernel(
    const float* __restrict__ A, const unsigned short* __restrict__ Bt,
    const float* __restrict__ bias, float* __restrict__ C,
    int M, int K, int Nc)
{
    __shared__ unsigned short As[128][LDK];
    __shared__ unsigned short Bs[128][LDK];
    const int t = threadIdx.x;
    const int lane = t & 63, w = t >> 6;
    const int wr = w >> 1, wc = w & 1;
    const int bm = blockIdx.y * 128, bn = blockIdx.x * 128;

    f32x4 acc[4][4];
    #pragma unroll
    for (int m = 0; m < 4; ++m)
        #pragma unroll
        for (int n = 0; n < 4; ++n)
            acc[m][n] = (f32x4){0.f, 0.f, 0.f, 0.f};

    const int ko = (lane >> 4) * 8;
    const int rA = wr * 64 + (lane & 15);
    const int rB = wc * 64 + (lane & 15);

    for (int k0 = 0; k0 < K; k0 += 32) {
        #pragma unroll
        for (int i = 0; i < 4; ++i) {
            int s = t + i * 256;
            int r = s >> 3, kg = s & 7;
            int row = bm + r;
            float4 v = make_float4(0.f, 0.f, 0.f, 0.f);
            if (row < M) v = *(const float4*)(A + (size_t)row * K + k0 + kg * 4);
            ushort4 b;
            b.x = f2bf(v.x); b.y = f2bf(v.y); b.z = f2bf(v.z); b.w = f2bf(v.w);
            *(ushort4*)&As[r][kg * 4] = b;
        }
        #pragma unroll
        for (int i = 0; i < 2; ++i) {
            int s = t + i * 256;
            int n = s >> 2, kg = s & 3;
            *(bf16x8*)&Bs[n][kg * 8] =
                *(const bf16x8*)(Bt + (size_t)(bn + n) * K + k0 + kg * 8);
        }
        __syncthreads();
        bf16x8 afr[4], bfr[4];
        #pragma unroll
        for (int m = 0; m < 4; ++m) afr[m] = *(const bf16x8*)&As[rA + m * 16][ko];
        #pragma unroll
        for (int n = 0; n < 4; ++n) bfr[n] = *(const bf16x8*)&Bs[rB + n * 16][ko];
        #pragma unroll
        for (int m = 0; m < 4; ++m)
            #pragma unroll
            for (int n = 0; n < 4; ++n)
                acc[m][n] = __builtin_amdgcn_mfma_f32_16x16x32_bf16(afr[m], bfr[n], acc[m][n], 0, 0, 0);
        __syncthreads();
    }
    #pragma unroll
    for (int m = 0; m < 4; ++m) {
        #pragma unroll
        for (int j = 0; j < 4; ++j) {
            int row = bm + wr * 64 + m * 16 + (lane >> 4) * 4 + j;
            if (row >= M) continue;
            #pragma unroll
            for (int n = 0; n < 4; ++n) {
                int col = bn + wc * 64 + n * 16 + (lane & 15);
                C[(size_t)row * Nc + col] = acc[m][n][j] + bias[col];
            }
        }
    }
}

// ---------------- sem MFMA: partial[c] += sum_rows tanh( relu(A) @ Wkt^T + bk )[c] ----------------
// Same tile as gemm_mfma; relu fused into A staging; tanh+column-sum epilogue.
__global__ __launch_bounds__(256) void sem_mfma_kernel(
    const float* __restrict__ A, const unsigned short* __restrict__ Bt,
    const float* __restrict__ bk, float* __restrict__ partial,
    int M, int K, int Nc)
{
    __shared__ unsigned short As[128][LDK];
    __shared__ unsigned short Bs[128][LDK];
    __shared__ float red[128];
    const int t = threadIdx.x;
    const int lane = t & 63, w = t >> 6;
    const int wr = w >> 1, wc = w & 1;
    const int bm = blockIdx.y * 128, bn = blockIdx.x * 128;

    f32x4 acc[4][4];
    #pragma unroll
    for (int m = 0; m < 4; ++m)
        #pragma unroll
        for (int n = 0; n < 4; ++n)
            acc[m][n] = (f32x4){0.f, 0.f, 0.f, 0.f};

    const int ko = (lane >> 4) * 8;
    const int rA = wr * 64 + (lane & 15);
    const int rB = wc * 64 + (lane & 15);

    for (int k0 = 0; k0 < K; k0 += 32) {
        #pragma unroll
        for (int i = 0; i < 4; ++i) {
            int s = t + i * 256;
            int r = s >> 3, kg = s & 7;
            int row = bm + r;
            float4 v = make_float4(0.f, 0.f, 0.f, 0.f);
            if (row < M) v = *(const float4*)(A + (size_t)row * K + k0 + kg * 4);
            ushort4 b;
            b.x = f2bf(fmaxf(v.x, 0.f)); b.y = f2bf(fmaxf(v.y, 0.f));
            b.z = f2bf(fmaxf(v.z, 0.f)); b.w = f2bf(fmaxf(v.w, 0.f));
            *(ushort4*)&As[r][kg * 4] = b;
        }
        #pragma unroll
        for (int i = 0; i < 2; ++i) {
            int s = t + i * 256;
            int n = s >> 2, kg = s & 3;
            *(bf16x8*)&Bs[n][kg * 8] =
                *(const bf16x8*)(Bt + (size_t)(bn + n) * K + k0 + kg * 8);
        }
        __syncthreads();
        bf16x8 afr[4], bfr[4];
        #pragma unroll
        for (int m = 0; m < 4; ++m) afr[m] = *(const bf16x8*)&As[rA + m * 16][ko];
        #pragma unroll
        for (int n = 0; n < 4; ++n) bfr[n] = *(const bf16x8*)&Bs[rB + n * 16][ko];
        #pragma unroll
        for (int m = 0; m < 4; ++m)
            #pragma unroll
            for (int n = 0; n < 4; ++n)
                acc[m][n] = __builtin_amdgcn_mfma_f32_16x16x32_bf16(afr[m], bfr[n], acc[m][n], 0, 0, 0);
        __syncthreads();
    }
    if (t < 128) red[t] = 0.f;
    __syncthreads();
    #pragma unroll
    for (int n = 0; n < 4; ++n) {
        int lcol = wc * 64 + n * 16 + (lane & 15);
        float b = bk[bn + lcol];
        float s = 0.f;
        #pragma unroll
        for (int m = 0; m < 4; ++m) {
            #pragma unroll
            for (int j = 0; j < 4; ++j) {
                int row = bm + wr * 64 + m * 16 + (lane >> 4) * 4 + j;
                if (row < M) s += tanhf(acc[m][n][j] + b);
            }
        }
        atomicAdd(&red[lcol], s);
    }
    __syncthreads();
    if (t < 128) atomicAdd(&partial[bn + t], red[t]);
}

// Wt[n*K+k] = bf16(W[k*Nc+n])
__global__ void transconv_kernel(const float* __restrict__ W, unsigned short* __restrict__ Wt,
                                 int K, int Nc)
{
    int gid = blockIdx.x * 256 + threadIdx.x;
    if (gid >= K * Nc) return;
    int k = gid / Nc, n = gid - k * Nc;
    Wt[(size_t)n * K + k] = f2bf(W[gid]);
}

// ---------------- CSR build (per relation, shared across both layers) ----------------
__global__ void hist_kernel(const int* __restrict__ dst, int* __restrict__ deg, int E)
{
    int e = blockIdx.x * 256 + threadIdx.x;
    if (e < E) atomicAdd(&deg[dst[e]], 1);
}

__global__ void block_sum_kernel(const int* __restrict__ deg, int* __restrict__ bsum, int n)
{
    __shared__ int buf[256];
    int i = blockIdx.x * 256 + threadIdx.x;
    buf[threadIdx.x] = (i < n) ? deg[i] : 0;
    __syncthreads();
    for (int s = 128; s > 0; s >>= 1) {
        if (threadIdx.x < s) buf[threadIdx.x] += buf[threadIdx.x + s];
        __syncthreads();
    }
    if (threadIdx.x == 0) bsum[blockIdx.x] = buf[0];
}

__global__ void scan_bsum_kernel(const int* __restrict__ bsum, int* __restrict__ boff, int nb)
{
    __shared__ int buf[256];
    int tid = threadIdx.x;
    int v = (tid < nb) ? bsum[tid] : 0;
    buf[tid] = v;
    __syncthreads();
    for (int off = 1; off < 256; off <<= 1) {
        int t = (tid >= off) ? buf[tid - off] : 0;
        __syncthreads();
        buf[tid] += t;
        __syncthreads();
    }
    if (tid < nb) boff[tid] = buf[tid] - v;
}

__global__ void scan_final_kernel(const int* __restrict__ deg, const int* __restrict__ boff,
                                  int* __restrict__ offs, int n)
{
    __shared__ int buf[256];
    int tid = threadIdx.x, b = blockIdx.x;
    int i = b * 256 + tid;
    int v = (i < n) ? deg[i] : 0;
    buf[tid] = v;
    __syncthreads();
    for (int off = 1; off < 256; off <<= 1) {
        int t = (tid >= off) ? buf[tid - off] : 0;
        __syncthreads();
        buf[tid] += t;
        __syncthreads();
    }
    if (i < n) offs[i] = boff[b] + buf[tid] - v;
    if (i == n - 1) offs[n] = boff[b] + buf[tid];
}

__global__ void place_kernel(const int* __restrict__ src, const int* __restrict__ dst,
                             const int* __restrict__ offs, int* __restrict__ cnt,
                             int* __restrict__ esrc, int E)
{
    int e = blockIdx.x * 256 + threadIdx.x;
    if (e >= E) return;
    int d = dst[e];
    int p = offs[d] + atomicAdd(&cnt[d], 1);
    esrc[p] = src[e];
}

// ---------------- per-node attention score dots ----------------
__global__ void node_scores_kernel(const float* __restrict__ x, const float* __restrict__ a,
                                   float* __restrict__ s, int n, int H, int D)
{
    int gid = blockIdx.x * blockDim.x + threadIdx.x;
    if (gid >= n * H) return;
    int node = gid / H, h = gid - node * H;
    const float* xr = x + (size_t)node * H * D + h * D;
    const float* ar = a + h * D;
    float acc = 0.f;
    for (int d = 0; d < D; d += 4) {
        float4 xv = *(const float4*)(xr + d);
        float4 av = *(const float4*)(ar + d);
        acc += xv.x * av.x + xv.y * av.y + xv.z * av.z + xv.w * av.w;
    }
    s[gid] = acc;
}

// ---------------- fused GAT gather: one block per dst node, blockDim == C ----------------
__global__ void gather_attn_kernel(const int* __restrict__ offs, const int* __restrict__ esrc,
                                   const float* __restrict__ x, const float* __restrict__ ssrc,
                                   const float* __restrict__ sdst, float* __restrict__ outp,
                                   int C, int H, int dsh)
{
    int d = blockIdx.x;
    int c = threadIdx.x;
    int h = c >> dsh;
    int beg = offs[d], end = offs[d + 1];
    float sd = sdst[d * H + h];
    float m = -INFINITY;
    for (int i = beg; i < end; ++i) {
        int s = esrc[i];
        float v = ssrc[s * H + h] + sd;
        v = (v >= 0.f) ? v : 0.2f * v;
        m = fmaxf(m, v);
    }
    float den = 0.f, acc = 0.f;
    for (int i = beg; i < end; ++i) {
        int s = esrc[i];
        float v = ssrc[s * H + h] + sd;
        v = (v >= 0.f) ? v : 0.2f * v;
        float ex = expf(v - m);
        den += ex;
        acc += ex * x[(size_t)s * C + c];
    }
    outp[(size_t)d * C + c] = acc / (den + 1e-16f);
}

__global__ void sem_weights_kernel(const float* __restrict__ partial, const float* __restrict__ q,
                                   float* __restrict__ w, int C, int n)
{
    if (threadIdx.x != 0 || blockIdx.x != 0) return;
    float inv = 1.f / (float)n;
    float s0 = 0.f, s1 = 0.f;
    for (int c = 0; c < C; ++c) {
        s0 += q[c] * partial[c] * inv;
        s1 += q[c] * partial[C + c] * inv;
    }
    float m = fmaxf(s0, s1);
    float e0 = expf(s0 - m), e1 = expf(s1 - m);
    float den = e0 + e1;
    w[0] = e0 / den;
    w[1] = e1 / den;
}

__global__ void combine2_kernel(const float* __restrict__ a, const float* __restrict__ b,
                                const float* __restrict__ w, float* __restrict__ out, long long n)
{
    long long gid = (long long)blockIdx.x * blockDim.x + threadIdx.x;
    if (gid >= n) return;
    out[gid] = w[0] * fmaxf(a[gid], 0.f) + w[1] * fmaxf(b[gid], 0.f);
}

__global__ void relu_copy_kernel(const float* __restrict__ a, float* __restrict__ out, long long n)
{
    long long gid = (long long)blockIdx.x * blockDim.x + threadIdx.x;
    if (gid >= n) return;
    out[gid] = fmaxf(a[gid], 0.f);
}

__global__ __launch_bounds__(128) void final_norm_kernel(
    const float* __restrict__ aggW, const float* __restrict__ aggC,
    const float* __restrict__ aggB, const float* __restrict__ w,
    float* __restrict__ out)
{
    __shared__ float red[128];
    int row = blockIdx.x;
    int c = threadIdx.x;
    float v;
    if (row < NN) {
        size_t i = (size_t)row * DOUT + c;
        v = w[0] * fmaxf(aggW[i], 0.f) + w[1] * fmaxf(aggC[i], 0.f);
    } else {
        size_t i = (size_t)(row - NN) * DOUT + c;
        v = fmaxf(aggB[i], 0.f);
    }
    red[c] = v * v;
    __syncthreads();
    for (int s = 64; s > 0; s >>= 1) {
        if (c < s) red[c] += red[c + s];
        __syncthreads();
    }
    float norm = sqrtf(red[0]);
    out[(size_t)row * DOUT + c] = v / fmaxf(norm, 1e-12f);
}

// ------------------------------------------------------------------
static void build_csr(const int* ei, int* offs, int* esrc, int* deg, int* bsum, int* boff,
                      hipStream_t stream)
{
    const int* src = ei;
    const int* dst = ei + NE;
    const int NB = (NN + 255) / 256;
    hipMemsetAsync(deg, 0, NN * sizeof(int), stream);
    hist_kernel<<<(NE + 255) / 256, 256, 0, stream>>>(dst, deg, NE);
    block_sum_kernel<<<NB, 256, 0, stream>>>(deg, bsum, NN);
    scan_bsum_kernel<<<1, 256, 0, stream>>>(bsum, boff, NB);
    scan_final_kernel<<<NB, 256, 0, stream>>>(deg, boff, offs, NN);
    hipMemsetAsync(deg, 0, NN * sizeof(int), stream);
    place_kernel<<<(NE + 255) / 256, 256, 0, stream>>>(src, dst, offs, deg, esrc, NE);
}

static void process_rel(const float* xsrc, const float* xdst,
                        const float* a_s, const float* a_d,
                        const int* offs, const int* esrc, int H, int D,
                        float* agg, float* ssrc, float* sdst, hipStream_t stream)
{
    const int C = H * D;
    int nt = NN * H;
    node_scores_kernel<<<(nt + 255) / 256, 256, 0, stream>>>(xsrc, a_s, ssrc, NN, H, D);
    node_scores_kernel<<<(nt + 255) / 256, 256, 0, stream>>>(xdst, a_d, sdst, NN, H, D);
    int dsh = (D == 32) ? 5 : 7;
    gather_attn_kernel<<<NN, C, 0, stream>>>(offs, esrc, xsrc, ssrc, sdst, agg, C, H, dsh);
}

extern "C" void kernel_launch(void* const* d_in, const int* in_sizes, int n_in,
                              void* d_out, int out_size, void* d_ws, size_t ws_size,
                              hipStream_t stream)
{
    const float* x_paper   = (const float*)d_in[0];
    const float* x_author  = (const float*)d_in[1];
    const int*   ei_writes = (const int*)d_in[2];
    const int*   ei_wb     = (const int*)d_in[3];
    const int*   ei_cites  = (const int*)d_in[4];
    const float* W0p = (const float*)d_in[5];  const float* b0p = (const float*)d_in[6];
    const float* W0a = (const float*)d_in[7];  const float* b0a = (const float*)d_in[8];
    const float* a0s_w  = (const float*)d_in[9];  const float* a0d_w  = (const float*)d_in[10];
    const float* a0s_wb = (const float*)d_in[11]; const float* a0d_wb = (const float*)d_in[12];
    const float* a0s_c  = (const float*)d_in[13]; const float* a0d_c  = (const float*)d_in[14];
    const float* Wk0 = (const float*)d_in[15]; const float* bk0 = (const float*)d_in[16];
    const float* q0  = (const float*)d_in[17];
    const float* W1p = (const float*)d_in[18]; const float* b1p = (const float*)d_in[19];
    const float* W1a = (const float*)d_in[20]; const float* b1a = (const float*)d_in[21];
    const float* a1s_w  = (const float*)d_in[22]; const float* a1d_w  = (const float*)d_in[23];
    const float* a1s_wb = (const float*)d_in[24]; const float* a1d_wb = (const float*)d_in[25];
    const float* a1s_c  = (const float*)d_in[26]; const float* a1d_c  = (const float*)d_in[27];
    const float* Wk1 = (const float*)d_in[28]; const float* bk1 = (const float*)d_in[29];
    const float* q1  = (const float*)d_in[30];

    float* out = (float*)d_out;

    // ---- workspace layout ----
    float* xhP  = (float*)d_ws;                       // N*256
    float* xhA  = xhP + (size_t)NN * DHID;            // N*256
    float* aggW = xhA + (size_t)NN * DHID;            // N*256
    float* aggC = aggW + (size_t)NN * DHID;           // N*256
    float* aggB = aggC + (size_t)NN * DHID;           // N*256
    float* ssrc = aggB + (size_t)NN * DHID;           // N*8
    float* sdst = ssrc + (size_t)NN * H0;             // N*8
    float* tsum = sdst + (size_t)NN * H0;             // 512
    float* wsem = tsum + 512;                         // 8 pad
    int* ip      = (int*)(wsem + 8);
    int* offsW   = ip;               ip += NN + 4;
    int* offsWB  = ip;               ip += NN + 4;
    int* offsC   = ip;               ip += NN + 4;
    int* esrcW   = ip;               ip += NE;
    int* esrcWB  = ip;               ip += NE;
    int* esrcC   = ip;               ip += NE;
    int* deg     = ip;               ip += NN;
    int* bsum    = ip;               ip += 256;
    int* boff    = ip;               ip += 256;
    unsigned short* wt0p = (unsigned short*)ip;       // 256*768 bf16
    unsigned short* wt0a = wt0p + (size_t)DHID * DIN;
    unsigned short* wkt  = wt0a + (size_t)DHID * DIN; // max 256*256 bf16
    unsigned short* wt1p = wt0p;                      // reuse after L0 GEMMs
    unsigned short* wt1a = wt1p + (size_t)DOUT * DHID;

    // layer-1 aliases (over dead layer-0 buffers)
    float* x1P   = aggW;
    float* x1A   = aggC;
    float* agg1W = aggB;
    float* agg1C = aggB + (size_t)NN * DOUT;
    float* agg1B = xhP;

    // ---- CSR build (shared by both layers) ----
    build_csr(ei_writes, offsW,  esrcW,  deg, bsum, boff, stream);
    build_csr(ei_wb,     offsWB, esrcWB, deg, bsum, boff, stream);
    build_csr(ei_cites,  offsC,  esrcC,  deg, bsum, boff, stream);

    // ================= layer 0 =================
    hipMemsetAsync(tsum, 0, 512 * sizeof(float), stream);
    transconv_kernel<<<(DIN * DHID + 255) / 256, 256, 0, stream>>>(W0p, wt0p, DIN, DHID);
    transconv_kernel<<<(DIN * DHID + 255) / 256, 256, 0, stream>>>(W0a, wt0a, DIN, DHID);
    transconv_kernel<<<(DHID * DHID + 255) / 256, 256, 0, stream>>>(Wk0, wkt, DHID, DHID);

    dim3 g0(DHID / 128, (NN + 127) / 128);
    gemm_mfma_kernel<<<g0, 256, 0, stream>>>(x_paper,  wt0p, b0p, xhP, NN, DIN, DHID);
    gemm_mfma_kernel<<<g0, 256, 0, stream>>>(x_author, wt0a, b0a, xhA, NN, DIN, DHID);

    // writes: author->paper ; written_by: paper->author ; cites: paper->paper
    process_rel(xhA, xhP, a0s_w,  a0d_w,  offsW,  esrcW,  H0, D0, aggW, ssrc, sdst, stream);
    process_rel(xhP, xhA, a0s_wb, a0d_wb, offsWB, esrcWB, H0, D0, aggB, ssrc, sdst, stream);
    process_rel(xhP, xhP, a0s_c,  a0d_c,  offsC,  esrcC,  H0, D0, aggC, ssrc, sdst, stream);

    // semantic attention (paper: M=2; author: M=1 -> identity)
    dim3 gs0(DHID / 128, (NN + 127) / 128);
    sem_mfma_kernel<<<gs0, 256, 0, stream>>>(aggW, wkt, bk0, tsum,        NN, DHID, DHID);
    sem_mfma_kernel<<<gs0, 256, 0, stream>>>(aggC, wkt, bk0, tsum + DHID, NN, DHID, DHID);
    sem_weights_kernel<<<1, 64, 0, stream>>>(tsum, q0, wsem, DHID, NN);

    long long nel0 = (long long)NN * DHID;
    combine2_kernel<<<(int)((nel0 + 255) / 256), 256, 0, stream>>>(aggW, aggC, wsem, xhP, nel0);
    relu_copy_kernel<<<(int)((nel0 + 255) / 256), 256, 0, stream>>>(aggB, xhA, nel0);

    // ================= layer 1 =================
    transconv_kernel<<<(DHID * DOUT + 255) / 256, 256, 0, stream>>>(W1p, wt1p, DHID, DOUT);
    transconv_kernel<<<(DHID * DOUT + 255) / 256, 256, 0, stream>>>(W1a, wt1a, DHID, DOUT);
    transconv_kernel<<<(DOUT * DOUT + 255) / 256, 256, 0, stream>>>(Wk1, wkt, DOUT, DOUT);

    dim3 g1(DOUT / 128, (NN + 127) / 128);
    gemm_mfma_kernel<<<g1, 256, 0, stream>>>(xhP, wt1p, b1p, x1P, NN, DHID, DOUT);
    gemm_mfma_kernel<<<g1, 256, 0, stream>>>(xhA, wt1a, b1a, x1A, NN, DHID, DOUT);

    hipMemsetAsync(tsum, 0, 2 * DOUT * sizeof(float), stream);

    process_rel(x1A, x1P, a1s_w,  a1d_w,  offsW,  esrcW,  1, DOUT, agg1W, ssrc, sdst, stream);
    process_rel(x1P, x1A, a1s_wb, a1d_wb, offsWB, esrcWB, 1, DOUT, agg1B, ssrc, sdst, stream);
    process_rel(x1P, x1P, a1s_c,  a1d_c,  offsC,  esrcC,  1, DOUT, agg1C, ssrc, sdst, stream);

    dim3 gs1(DOUT / 128, (NN + 127) / 128);
    sem_mfma_kernel<<<gs1, 256, 0, stream>>>(agg1W, wkt, bk1, tsum,        NN, DOUT, DOUT);
    sem_mfma_kernel<<<gs1, 256, 0, stream>>>(agg1C, wkt, bk1, tsum + DOUT, NN, DOUT, DOUT);
    sem_weights_kernel<<<1, 64, 0, stream>>>(tsum, q1, wsem, DOUT, NN);

    final_norm_kernel<<<2 * NN, 128, 0, stream>>>(agg1W, agg1C, agg1B, wsem, out);
}

// Round 5
// 1348.153 us; speedup vs baseline: 4.9890x; 1.1162x over previous
//
#include <hip/hip_runtime.h>
#include <math.h>

#define NN 50000
#define NE 300000
#define DIN 768
#define DHID 256
#define DOUT 128
#define H0 8
#define D0 32

typedef __attribute__((ext_vector_type(8))) short bf16x8;
typedef __attribute__((ext_vector_type(8))) unsigned short u16x8;
typedef __attribute__((ext_vector_type(4))) float f32x4;

__device__ __forceinline__ unsigned short f2bf(float f) {
    unsigned u = __float_as_uint(f);
    unsigned r = (u + 0x7fffu + ((u >> 16) & 1u)) >> 16;
    return (unsigned short)r;
}
__device__ __forceinline__ float bf2f(unsigned short u) {
    return __uint_as_float(((unsigned)u) << 16);
}

// async global(16B) -> LDS, wave-uniform dst base + lane*16
__device__ __forceinline__ void gload16(const void* g, void* l) {
    __builtin_amdgcn_global_load_lds(
        (const __attribute__((address_space(1))) unsigned int*)g,
        (__attribute__((address_space(3))) unsigned int*)l, 16, 0, 0);
}

// ---------------- f32 -> bf16 stream convert (8 elems/thread) ----------------
__global__ void convert_bf16_kernel(const float* __restrict__ in, unsigned short* __restrict__ out, int n8)
{
    int i = blockIdx.x * 256 + threadIdx.x;
    if (i >= n8) return;
    float4 a = ((const float4*)in)[i * 2];
    float4 b = ((const float4*)in)[i * 2 + 1];
    u16x8 o;
    o[0] = f2bf(a.x); o[1] = f2bf(a.y); o[2] = f2bf(a.z); o[3] = f2bf(a.w);
    o[4] = f2bf(b.x); o[5] = f2bf(b.y); o[6] = f2bf(b.z); o[7] = f2bf(b.w);
    ((u16x8*)out)[i] = o;
}

// ---------------- MFMA GEMM, A bf16 [M,K] @ Bt bf16 [Nc,K]^T + bias ----------------
// 128x128 tile, BK=32, 4 waves, global_load_lds staging, chunk-XOR LDS swizzle.
// blockIdx.z selects {A,Bt,bias,C} pair (two independent same-shape GEMMs batched).
// OUTBF: 0 -> C f32, 1 -> C bf16.
template<int OUTBF>
__global__ __launch_bounds__(256) void gemm_bf16_kernel(
    const unsigned short* __restrict__ A0, const unsigned short* __restrict__ A1,
    const unsigned short* __restrict__ Bt0, const unsigned short* __restrict__ Bt1,
    const float* __restrict__ bias0, const float* __restrict__ bias1,
    void* __restrict__ Cv0, void* __restrict__ Cv1,
    int M, int K, int Nc)
{
    __shared__ __align__(16) unsigned short As[128 * 32];
    __shared__ __align__(16) unsigned short Bs[128 * 32];
    const int z = blockIdx.z;
    const unsigned short* A  = z ? A1  : A0;
    const unsigned short* Bt = z ? Bt1 : Bt0;
    const float* bias = z ? bias1 : bias0;
    const int t = threadIdx.x;
    const int lane = t & 63, w = t >> 6;
    const int wr = w >> 1, wc = w & 1;
    const int bm = blockIdx.y * 128, bn = blockIdx.x * 128;

    f32x4 acc[4][4];
    #pragma unroll
    for (int m = 0; m < 4; ++m)
        #pragma unroll
        for (int n = 0; n < 4; ++n)
            acc[m][n] = (f32x4){0.f, 0.f, 0.f, 0.f};

    // staging: 512 16B chunks per tile (A and B each); thread does chunks c0, c0+256.
    // LDS linear chunk c = (row, gdst=c&3); data from global chunk gsrc = gdst ^ ((row>>1)&3).
    const int c0 = w * 64 + lane, c1 = c0 + 256;
    const int row0 = c0 >> 2, row1 = c1 >> 2;
    const int g0 = (c0 & 3) ^ ((row0 >> 1) & 3);
    const int g1 = (c1 & 3) ^ ((row1 >> 1) & 3);
    const int ar0 = (bm + row0 < M) ? (bm + row0) : (M - 1);
    const int ar1 = (bm + row1 < M) ? (bm + row1) : (M - 1);
    const unsigned short* pA0 = A + (size_t)ar0 * K + g0 * 8;
    const unsigned short* pA1 = A + (size_t)ar1 * K + g1 * 8;
    const unsigned short* pB0 = Bt + (size_t)(bn + row0) * K + g0 * 8;
    const unsigned short* pB1 = Bt + (size_t)(bn + row1) * K + g1 * 8;
    unsigned short* lA0 = As + c0 * 8;
    unsigned short* lA1 = As + c1 * 8;
    unsigned short* lB0 = Bs + c0 * 8;
    unsigned short* lB1 = Bs + c1 * 8;

    const int rA = wr * 64 + (lane & 15);
    const int rB = wc * 64 + (lane & 15);
    const int gw = lane >> 4;   // wanted k-chunk

    for (int k0 = 0; k0 < K; k0 += 32) {
        gload16(pA0 + k0, lA0);
        gload16(pA1 + k0, lA1);
        gload16(pB0 + k0, lB0);
        gload16(pB1 + k0, lB1);
        __syncthreads();   // drains vmcnt -> LDS ready
        bf16x8 afr[4], bfr[4];
        #pragma unroll
        for (int m = 0; m < 4; ++m) {
            int r = rA + m * 16;
            afr[m] = *(const bf16x8*)&As[r * 32 + ((gw ^ ((r >> 1) & 3)) * 8)];
        }
        #pragma unroll
        for (int n = 0; n < 4; ++n) {
            int r = rB + n * 16;
            bfr[n] = *(const bf16x8*)&Bs[r * 32 + ((gw ^ ((r >> 1) & 3)) * 8)];
        }
        #pragma unroll
        for (int m = 0; m < 4; ++m)
            #pragma unroll
            for (int n = 0; n < 4; ++n)
                acc[m][n] = __builtin_amdgcn_mfma_f32_16x16x32_bf16(afr[m], bfr[n], acc[m][n], 0, 0, 0);
        __syncthreads();   // protect LDS before next stage
    }
    #pragma unroll
    for (int m = 0; m < 4; ++m) {
        #pragma unroll
        for (int j = 0; j < 4; ++j) {
            int row = bm + wr * 64 + m * 16 + (lane >> 4) * 4 + j;
            if (row >= M) continue;
            #pragma unroll
            for (int n = 0; n < 4; ++n) {
                int col = bn + wc * 64 + n * 16 + (lane & 15);
                float v = acc[m][n][j] + bias[col];
                if (OUTBF) ((unsigned short*)(z ? Cv1 : Cv0))[(size_t)row * Nc + col] = f2bf(v);
                else       ((float*)(z ? Cv1 : Cv0))[(size_t)row * Nc + col] = v;
            }
        }
    }
}

// ---------------- sem MFMA: partial[c] += sum_rows tanh( relu(A) @ Wkt^T + bk )[c] ----------------
#define LDK 40
__global__ __launch_bounds__(256) void sem_mfma_kernel(
    const float* __restrict__ A, const unsigned short* __restrict__ Bt,
    const float* __restrict__ bk, float* __restrict__ partial,
    int M, int K, int Nc)
{
    __shared__ unsigned short As[128][LDK];
    __shared__ unsigned short Bs[128][LDK];
    __shared__ float red[128];
    const int t = threadIdx.x;
    const int lane = t & 63, w = t >> 6;
    const int wr = w >> 1, wc = w & 1;
    const int bm = blockIdx.y * 128, bn = blockIdx.x * 128;

    f32x4 acc[4][4];
    #pragma unroll
    for (int m = 0; m < 4; ++m)
        #pragma unroll
        for (int n = 0; n < 4; ++n)
            acc[m][n] = (f32x4){0.f, 0.f, 0.f, 0.f};

    const int ko = (lane >> 4) * 8;
    const int rA = wr * 64 + (lane & 15);
    const int rB = wc * 64 + (lane & 15);

    for (int k0 = 0; k0 < K; k0 += 32) {
        #pragma unroll
        for (int i = 0; i < 4; ++i) {
            int s = t + i * 256;
            int r = s >> 3, kg = s & 7;
            int row = bm + r;
            float4 v = make_float4(0.f, 0.f, 0.f, 0.f);
            if (row < M) v = *(const float4*)(A + (size_t)row * K + k0 + kg * 4);
            ushort4 b;
            b.x = f2bf(fmaxf(v.x, 0.f)); b.y = f2bf(fmaxf(v.y, 0.f));
            b.z = f2bf(fmaxf(v.z, 0.f)); b.w = f2bf(fmaxf(v.w, 0.f));
            *(ushort4*)&As[r][kg * 4] = b;
        }
        #pragma unroll
        for (int i = 0; i < 2; ++i) {
            int s = t + i * 256;
            int n = s >> 2, kg = s & 3;
            *(bf16x8*)&Bs[n][kg * 8] =
                *(const bf16x8*)(Bt + (size_t)(bn + n) * K + k0 + kg * 8);
        }
        __syncthreads();
        bf16x8 afr[4], bfr[4];
        #pragma unroll
        for (int m = 0; m < 4; ++m) afr[m] = *(const bf16x8*)&As[rA + m * 16][ko];
        #pragma unroll
        for (int n = 0; n < 4; ++n) bfr[n] = *(const bf16x8*)&Bs[rB + n * 16][ko];
        #pragma unroll
        for (int m = 0; m < 4; ++m)
            #pragma unroll
            for (int n = 0; n < 4; ++n)
                acc[m][n] = __builtin_amdgcn_mfma_f32_16x16x32_bf16(afr[m], bfr[n], acc[m][n], 0, 0, 0);
        __syncthreads();
    }
    if (t < 128) red[t] = 0.f;
    __syncthreads();
    #pragma unroll
    for (int n = 0; n < 4; ++n) {
        int lcol = wc * 64 + n * 16 + (lane & 15);
        float b = bk[bn + lcol];
        float s = 0.f;
        #pragma unroll
        for (int m = 0; m < 4; ++m) {
            #pragma unroll
            for (int j = 0; j < 4; ++j) {
                int row = bm + wr * 64 + m * 16 + (lane >> 4) * 4 + j;
                if (row < M) s += tanhf(acc[m][n][j] + b);
            }
        }
        atomicAdd(&red[lcol], s);
    }
    __syncthreads();
    if (t < 128) atomicAdd(&partial[bn + t], red[t]);
}

// Wt[n*K+k] = bf16(W[k*Nc+n])
__global__ void transconv_kernel(const float* __restrict__ W, unsigned short* __restrict__ Wt,
                                 int K, int Nc)
{
    int gid = blockIdx.x * 256 + threadIdx.x;
    if (gid >= K * Nc) return;
    int k = gid / Nc, n = gid - k * Nc;
    Wt[(size_t)n * K + k] = f2bf(W[gid]);
}

// ---------------- CSR build ----------------
__global__ void hist_kernel(const int* __restrict__ dst, int* __restrict__ deg, int E)
{
    int e = blockIdx.x * 256 + threadIdx.x;
    if (e < E) atomicAdd(&deg[dst[e]], 1);
}

__global__ void block_sum_kernel(const int* __restrict__ deg, int* __restrict__ bsum, int n)
{
    __shared__ int buf[256];
    int i = blockIdx.x * 256 + threadIdx.x;
    buf[threadIdx.x] = (i < n) ? deg[i] : 0;
    __syncthreads();
    for (int s = 128; s > 0; s >>= 1) {
        if (threadIdx.x < s) buf[threadIdx.x] += buf[threadIdx.x + s];
        __syncthreads();
    }
    if (threadIdx.x == 0) bsum[blockIdx.x] = buf[0];
}

__global__ void scan_bsum_kernel(const int* __restrict__ bsum, int* __restrict__ boff, int nb)
{
    __shared__ int buf[256];
    int tid = threadIdx.x;
    int v = (tid < nb) ? bsum[tid] : 0;
    buf[tid] = v;
    __syncthreads();
    for (int off = 1; off < 256; off <<= 1) {
        int t = (tid >= off) ? buf[tid - off] : 0;
        __syncthreads();
        buf[tid] += t;
        __syncthreads();
    }
    if (tid < nb) boff[tid] = buf[tid] - v;
}

__global__ void scan_final_kernel(const int* __restrict__ deg, const int* __restrict__ boff,
                                  int* __restrict__ offs, int n)
{
    __shared__ int buf[256];
    int tid = threadIdx.x, b = blockIdx.x;
    int i = b * 256 + tid;
    int v = (i < n) ? deg[i] : 0;
    buf[tid] = v;
    __syncthreads();
    for (int off = 1; off < 256; off <<= 1) {
        int t = (tid >= off) ? buf[tid - off] : 0;
        __syncthreads();
        buf[tid] += t;
        __syncthreads();
    }
    if (i < n) offs[i] = boff[b] + buf[tid] - v;
    if (i == n - 1) offs[n] = boff[b] + buf[tid];
}

__global__ void place_kernel(const int* __restrict__ src, const int* __restrict__ dst,
                             const int* __restrict__ offs, int* __restrict__ cnt,
                             int* __restrict__ esrc, int E)
{
    int e = blockIdx.x * 256 + threadIdx.x;
    if (e >= E) return;
    int d = dst[e];
    int p = offs[d] + atomicAdd(&cnt[d], 1);
    esrc[p] = src[e];
}

// ---------------- node score dots ----------------
__global__ void node_scores_kernel(const float* __restrict__ x, const float* __restrict__ a,
                                   float* __restrict__ s, int n, int H, int D)
{
    int gid = blockIdx.x * blockDim.x + threadIdx.x;
    if (gid >= n * H) return;
    int node = gid / H, h = gid - node * H;
    const float* xr = x + (size_t)node * H * D + h * D;
    const float* ar = a + h * D;
    float acc = 0.f;
    for (int d = 0; d < D; d += 4) {
        float4 xv = *(const float4*)(xr + d);
        float4 av = *(const float4*)(ar + d);
        acc += xv.x * av.x + xv.y * av.y + xv.z * av.z + xv.w * av.w;
    }
    s[gid] = acc;
}

__global__ void node_scores_bf16_kernel(const unsigned short* __restrict__ x, const float* __restrict__ a,
                                        float* __restrict__ s, int n, int H, int D)
{
    int gid = blockIdx.x * blockDim.x + threadIdx.x;
    if (gid >= n * H) return;
    int node = gid / H, h = gid - node * H;
    const unsigned short* xr = x + (size_t)node * H * D + h * D;
    const float* ar = a + h * D;
    float acc = 0.f;
    for (int d = 0; d < D; d += 8) {
        u16x8 xv = *(const u16x8*)(xr + d);
        #pragma unroll
        for (int j = 0; j < 8; ++j) acc += bf2f(xv[j]) * ar[d + j];
    }
    s[gid] = acc;
}

// ---------------- fused GAT gather ----------------
__global__ void gather_attn_kernel(const int* __restrict__ offs, const int* __restrict__ esrc,
                                   const float* __restrict__ x, const float* __restrict__ ssrc,
                                   const float* __restrict__ sdst, float* __restrict__ outp,
                                   int C, int H, int dsh)
{
    int d = blockIdx.x;
    int c = threadIdx.x;
    int h = c >> dsh;
    int beg = offs[d], end = offs[d + 1];
    float sd = sdst[d * H + h];
    float m = -INFINITY;
    for (int i = beg; i < end; ++i) {
        int s = esrc[i];
        float v = ssrc[s * H + h] + sd;
        v = (v >= 0.f) ? v : 0.2f * v;
        m = fmaxf(m, v);
    }
    float den = 0.f, acc = 0.f;
    for (int i = beg; i < end; ++i) {
        int s = esrc[i];
        float v = ssrc[s * H + h] + sd;
        v = (v >= 0.f) ? v : 0.2f * v;
        float ex = expf(v - m);
        den += ex;
        acc += ex * x[(size_t)s * C + c];
    }
    outp[(size_t)d * C + c] = acc / (den + 1e-16f);
}

__global__ void gather_attn_bf16_kernel(const int* __restrict__ offs, const int* __restrict__ esrc,
                                        const unsigned short* __restrict__ x, const float* __restrict__ ssrc,
                                        const float* __restrict__ sdst, float* __restrict__ outp,
                                        int C, int H, int dsh)
{
    int d = blockIdx.x;
    int c = threadIdx.x;
    int h = c >> dsh;
    int beg = offs[d], end = offs[d + 1];
    float sd = sdst[d * H + h];
    float m = -INFINITY;
    for (int i = beg; i < end; ++i) {
        int s = esrc[i];
        float v = ssrc[s * H + h] + sd;
        v = (v >= 0.f) ? v : 0.2f * v;
        m = fmaxf(m, v);
    }
    float den = 0.f, acc = 0.f;
    for (int i = beg; i < end; ++i) {
        int s = esrc[i];
        float v = ssrc[s * H + h] + sd;
        v = (v >= 0.f) ? v : 0.2f * v;
        float ex = expf(v - m);
        den += ex;
        acc += ex * bf2f(x[(size_t)s * C + c]);
    }
    outp[(size_t)d * C + c] = acc / (den + 1e-16f);
}

__global__ void sem_weights_kernel(const float* __restrict__ partial, const float* __restrict__ q,
                                   float* __restrict__ w, int C, int n)
{
    if (threadIdx.x != 0 || blockIdx.x != 0) return;
    float inv = 1.f / (float)n;
    float s0 = 0.f, s1 = 0.f;
    for (int c = 0; c < C; ++c) {
        s0 += q[c] * partial[c] * inv;
        s1 += q[c] * partial[C + c] * inv;
    }
    float m = fmaxf(s0, s1);
    float e0 = expf(s0 - m), e1 = expf(s1 - m);
    float den = e0 + e1;
    w[0] = e0 / den;
    w[1] = e1 / den;
}

// out(bf16) = w0*relu(a) + w1*relu(b)
__global__ void combine2_bf16_kernel(const float* __restrict__ a, const float* __restrict__ b,
                                     const float* __restrict__ w, unsigned short* __restrict__ out,
                                     long long n)
{
    long long gid = (long long)blockIdx.x * blockDim.x + threadIdx.x;
    if (gid >= n) return;
    out[gid] = f2bf(w[0] * fmaxf(a[gid], 0.f) + w[1] * fmaxf(b[gid], 0.f));
}

__global__ void relu_copy_bf16_kernel(const float* __restrict__ a, unsigned short* __restrict__ out,
                                      long long n)
{
    long long gid = (long long)blockIdx.x * blockDim.x + threadIdx.x;
    if (gid >= n) return;
    out[gid] = f2bf(fmaxf(a[gid], 0.f));
}

__global__ __launch_bounds__(128) void final_norm_kernel(
    const float* __restrict__ aggW, const float* __restrict__ aggC,
    const float* __restrict__ aggB, const float* __restrict__ w,
    float* __restrict__ out)
{
    __shared__ float red[128];
    int row = blockIdx.x;
    int c = threadIdx.x;
    float v;
    if (row < NN) {
        size_t i = (size_t)row * DOUT + c;
        v = w[0] * fmaxf(aggW[i], 0.f) + w[1] * fmaxf(aggC[i], 0.f);
    } else {
        size_t i = (size_t)(row - NN) * DOUT + c;
        v = fmaxf(aggB[i], 0.f);
    }
    red[c] = v * v;
    __syncthreads();
    for (int s = 64; s > 0; s >>= 1) {
        if (c < s) red[c] += red[c + s];
        __syncthreads();
    }
    float norm = sqrtf(red[0]);
    out[(size_t)row * DOUT + c] = v / fmaxf(norm, 1e-12f);
}

// ------------------------------------------------------------------
static void build_csr(const int* ei, int* offs, int* esrc, int* deg, int* bsum, int* boff,
                      hipStream_t stream)
{
    const int* src = ei;
    const int* dst = ei + NE;
    const int NB = (NN + 255) / 256;
    hipMemsetAsync(deg, 0, NN * sizeof(int), stream);
    hist_kernel<<<(NE + 255) / 256, 256, 0, stream>>>(dst, deg, NE);
    block_sum_kernel<<<NB, 256, 0, stream>>>(deg, bsum, NN);
    scan_bsum_kernel<<<1, 256, 0, stream>>>(bsum, boff, NB);
    scan_final_kernel<<<NB, 256, 0, stream>>>(deg, boff, offs, NN);
    hipMemsetAsync(deg, 0, NN * sizeof(int), stream);
    place_kernel<<<(NE + 255) / 256, 256, 0, stream>>>(src, dst, offs, deg, esrc, NE);
}

static void process_rel_f32(const float* xsrc, const float* xdst,
                            const float* a_s, const float* a_d,
                            const int* offs, const int* esrc, int H, int D,
                            float* agg, float* ssrc, float* sdst, hipStream_t stream)
{
    const int C = H * D;
    int nt = NN * H;
    node_scores_kernel<<<(nt + 255) / 256, 256, 0, stream>>>(xsrc, a_s, ssrc, NN, H, D);
    node_scores_kernel<<<(nt + 255) / 256, 256, 0, stream>>>(xdst, a_d, sdst, NN, H, D);
    int dsh = (D == 32) ? 5 : 7;
    gather_attn_kernel<<<NN, C, 0, stream>>>(offs, esrc, xsrc, ssrc, sdst, agg, C, H, dsh);
}

static void process_rel_bf16(const unsigned short* xsrc, const unsigned short* xdst,
                             const float* a_s, const float* a_d,
                             const int* offs, const int* esrc, int H, int D,
                             float* agg, float* ssrc, float* sdst, hipStream_t stream)
{
    const int C = H * D;
    int nt = NN * H;
    node_scores_bf16_kernel<<<(nt + 255) / 256, 256, 0, stream>>>(xsrc, a_s, ssrc, NN, H, D);
    node_scores_bf16_kernel<<<(nt + 255) / 256, 256, 0, stream>>>(xdst, a_d, sdst, NN, H, D);
    int dsh = (D == 32) ? 5 : 7;
    gather_attn_bf16_kernel<<<NN, C, 0, stream>>>(offs, esrc, xsrc, ssrc, sdst, agg, C, H, dsh);
}

extern "C" void kernel_launch(void* const* d_in, const int* in_sizes, int n_in,
                              void* d_out, int out_size, void* d_ws, size_t ws_size,
                              hipStream_t stream)
{
    const float* x_paper   = (const float*)d_in[0];
    const float* x_author  = (const float*)d_in[1];
    const int*   ei_writes = (const int*)d_in[2];
    const int*   ei_wb     = (const int*)d_in[3];
    const int*   ei_cites  = (const int*)d_in[4];
    const float* W0p = (const float*)d_in[5];  const float* b0p = (const float*)d_in[6];
    const float* W0a = (const float*)d_in[7];  const float* b0a = (const float*)d_in[8];
    const float* a0s_w  = (const float*)d_in[9];  const float* a0d_w  = (const float*)d_in[10];
    const float* a0s_wb = (const float*)d_in[11]; const float* a0d_wb = (const float*)d_in[12];
    const float* a0s_c  = (const float*)d_in[13]; const float* a0d_c  = (const float*)d_in[14];
    const float* Wk0 = (const float*)d_in[15]; const float* bk0 = (const float*)d_in[16];
    const float* q0  = (const float*)d_in[17];
    const float* W1p = (const float*)d_in[18]; const float* b1p = (const float*)d_in[19];
    const float* W1a = (const float*)d_in[20]; const float* b1a = (const float*)d_in[21];
    const float* a1s_w  = (const float*)d_in[22]; const float* a1d_w  = (const float*)d_in[23];
    const float* a1s_wb = (const float*)d_in[24]; const float* a1d_wb = (const float*)d_in[25];
    const float* a1s_c  = (const float*)d_in[26]; const float* a1d_c  = (const float*)d_in[27];
    const float* Wk1 = (const float*)d_in[28]; const float* bk1 = (const float*)d_in[29];
    const float* q1  = (const float*)d_in[30];

    float* out = (float*)d_out;

    const size_t NH = (size_t)NN * DHID;   // 12.8M
    const size_t NI = (size_t)NN * DIN;    // 38.4M
    const size_t NO = (size_t)NN * DOUT;   // 6.4M

    // ---- workspace layout ----
    float* xhP = (float*)d_ws;            // NH f32 (later: hbP bf16 (NH u16) in same region)
    float* xhA = xhP + NH;                // NH f32 (later: hbA bf16 + x1Pb + x1Ab)
    float* R   = xhA + NH;                // 38.4M f32 region, multi-phase
    // phase A: bf16 inputs
    unsigned short* xbP = (unsigned short*)R;          // NI u16
    unsigned short* xbA = xbP + NI;                    // NI u16
    // phase B: layer-0 aggregates
    float* aggW = R;
    float* aggC = R + NH;
    float* aggB = R + 2 * NH;
    // phase C: layer-1 aggregates
    float* agg1W = R;
    float* agg1C = R + NO;
    float* agg1B = R + 2 * NO;
    // h (bf16) aliases over xhP/xhA; x1 bf16 after hbA
    unsigned short* hbP  = (unsigned short*)xhP;       // NH u16 (25.6MB of 51.2)
    unsigned short* hbA  = (unsigned short*)xhA;       // NH u16
    unsigned short* x1Pb = (unsigned short*)xhA + NH;  // NO u16
    unsigned short* x1Ab = x1Pb + NO;                  // NO u16

    float* ssrc = R + 3 * NH;             // NN*H0
    float* sdst = ssrc + (size_t)NN * H0;
    float* tsum = sdst + (size_t)NN * H0; // 512
    float* wsem = tsum + 512;             // 8
    int* ip      = (int*)(wsem + 8);
    int* offsW   = ip;               ip += NN + 4;
    int* offsWB  = ip;               ip += NN + 4;
    int* offsC   = ip;               ip += NN + 4;
    int* esrcW   = ip;               ip += NE;
    int* esrcWB  = ip;               ip += NE;
    int* esrcC   = ip;               ip += NE;
    int* deg     = ip;               ip += NN;
    int* bsum    = ip;               ip += 256;
    int* boff    = ip;               ip += 256;
    unsigned short* wt0p = (unsigned short*)ip;        // DHID*DIN u16
    unsigned short* wt0a = wt0p + (size_t)DHID * DIN;
    unsigned short* wkt  = wt0a + (size_t)DHID * DIN;  // up to DHID*DHID
    unsigned short* wt1p = wt0p;                       // alias after L0 GEMMs done
    unsigned short* wt1a = wt1p + (size_t)DOUT * DHID;

    // ---- CSR build (shared by both layers) ----
    build_csr(ei_writes, offsW,  esrcW,  deg, bsum, boff, stream);
    build_csr(ei_wb,     offsWB, esrcWB, deg, bsum, boff, stream);
    build_csr(ei_cites,  offsC,  esrcC,  deg, bsum, boff, stream);

    // ================= layer 0 =================
    hipMemsetAsync(tsum, 0, 512 * sizeof(float), stream);
    convert_bf16_kernel<<<(int)((NI / 8 + 255) / 256), 256, 0, stream>>>(x_paper,  xbP, (int)(NI / 8));
    convert_bf16_kernel<<<(int)((NI / 8 + 255) / 256), 256, 0, stream>>>(x_author, xbA, (int)(NI / 8));
    transconv_kernel<<<(DIN * DHID + 255) / 256, 256, 0, stream>>>(W0p, wt0p, DIN, DHID);
    transconv_kernel<<<(DIN * DHID + 255) / 256, 256, 0, stream>>>(W0a, wt0a, DIN, DHID);
    transconv_kernel<<<(DHID * DHID + 255) / 256, 256, 0, stream>>>(Wk0, wkt, DHID, DHID);

    dim3 g0(DHID / 128, (NN + 127) / 128, 2);
    gemm_bf16_kernel<0><<<g0, 256, 0, stream>>>(xbP, xbA, wt0p, wt0a, b0p, b0a, xhP, xhA, NN, DIN, DHID);

    // writes: author->paper ; written_by: paper->author ; cites: paper->paper
    process_rel_f32(xhA, xhP, a0s_w,  a0d_w,  offsW,  esrcW,  H0, D0, aggW, ssrc, sdst, stream);
    process_rel_f32(xhP, xhA, a0s_wb, a0d_wb, offsWB, esrcWB, H0, D0, aggB, ssrc, sdst, stream);
    process_rel_f32(xhP, xhP, a0s_c,  a0d_c,  offsC,  esrcC,  H0, D0, aggC, ssrc, sdst, stream);

    // semantic attention (paper: M=2; author: M=1 -> identity)
    dim3 gs0(DHID / 128, (NN + 127) / 128);
    sem_mfma_kernel<<<gs0, 256, 0, stream>>>(aggW, wkt, bk0, tsum,        NN, DHID, DHID);
    sem_mfma_kernel<<<gs0, 256, 0, stream>>>(aggC, wkt, bk0, tsum + DHID, NN, DHID, DHID);
    sem_weights_kernel<<<1, 64, 0, stream>>>(tsum, q0, wsem, DHID, NN);

    long long nel0 = (long long)NH;
    combine2_bf16_kernel<<<(int)((nel0 + 255) / 256), 256, 0, stream>>>(aggW, aggC, wsem, hbP, nel0);
    relu_copy_bf16_kernel<<<(int)((nel0 + 255) / 256), 256, 0, stream>>>(aggB, hbA, nel0);

    // ================= layer 1 =================
    transconv_kernel<<<(DHID * DOUT + 255) / 256, 256, 0, stream>>>(W1p, wt1p, DHID, DOUT);
    transconv_kernel<<<(DHID * DOUT + 255) / 256, 256, 0, stream>>>(W1a, wt1a, DHID, DOUT);
    transconv_kernel<<<(DOUT * DOUT + 255) / 256, 256, 0, stream>>>(Wk1, wkt, DOUT, DOUT);

    dim3 g1(DOUT / 128, (NN + 127) / 128, 2);
    gemm_bf16_kernel<1><<<g1, 256, 0, stream>>>(hbP, hbA, wt1p, wt1a, b1p, b1a, x1Pb, x1Ab, NN, DHID, DOUT);

    hipMemsetAsync(tsum, 0, 2 * DOUT * sizeof(float), stream);

    process_rel_bf16(x1Ab, x1Pb, a1s_w,  a1d_w,  offsW,  esrcW,  1, DOUT, agg1W, ssrc, sdst, stream);
    process_rel_bf16(x1Pb, x1Ab, a1s_wb, a1d_wb, offsWB, esrcWB, 1, DOUT, agg1B, ssrc, sdst, stream);
    process_rel_bf16(x1Pb, x1Pb, a1s_c,  a1d_c,  offsC,  esrcC,  1, DOUT, agg1C, ssrc, sdst, stream);

    dim3 gs1(DOUT / 128, (NN + 127) / 128);
    sem_mfma_kernel<<<gs1, 256, 0, stream>>>(agg1W, wkt, bk1, tsum,        NN, DOUT, DOUT);
    sem_mfma_kernel<<<gs1, 256, 0, stream>>>(agg1C, wkt, bk1, tsum + DOUT, NN, DOUT, DOUT);
    sem_weights_kernel<<<1, 64, 0, stream>>>(tsum, q1, wsem, DOUT, NN);

    final_norm_kernel<<<2 * NN, 128, 0, stream>>>(agg1W, agg1C, agg1B, wsem, out);
}

// Round 6
// 1039.993 us; speedup vs baseline: 6.4673x; 1.2963x over previous
//
#include <hip/hip_runtime.h>
#include <math.h>

#define NN 50000
#define NE 300000
#define DIN 768
#define DHID 256
#define DOUT 128
#define H0 8
#define D0 32

typedef __attribute__((ext_vector_type(8))) short bf16x8;
typedef __attribute__((ext_vector_type(8))) unsigned short u16x8;
typedef __attribute__((ext_vector_type(4))) float f32x4;

__device__ __forceinline__ unsigned short f2bf(float f) {
    unsigned u = __float_as_uint(f);
    unsigned r = (u + 0x7fffu + ((u >> 16) & 1u)) >> 16;
    return (unsigned short)r;
}
__device__ __forceinline__ float bf2f(unsigned short u) {
    return __uint_as_float(((unsigned)u) << 16);
}

// async global(16B) -> LDS, wave-uniform dst base + lane*16
__device__ __forceinline__ void gload16(const void* g, void* l) {
    __builtin_amdgcn_global_load_lds(
        (const __attribute__((address_space(1))) unsigned int*)g,
        (__attribute__((address_space(3))) unsigned int*)l, 16, 0, 0);
}

// ---------------- f32 -> bf16 stream convert ----------------
__global__ void convert_bf16_kernel(const float* __restrict__ in, unsigned short* __restrict__ out, int n8)
{
    int i = blockIdx.x * 256 + threadIdx.x;
    if (i >= n8) return;
    float4 a = ((const float4*)in)[i * 2];
    float4 b = ((const float4*)in)[i * 2 + 1];
    u16x8 o;
    o[0] = f2bf(a.x); o[1] = f2bf(a.y); o[2] = f2bf(a.z); o[3] = f2bf(a.w);
    o[4] = f2bf(b.x); o[5] = f2bf(b.y); o[6] = f2bf(b.z); o[7] = f2bf(b.w);
    ((u16x8*)out)[i] = o;
}

// ---------------- MFMA GEMM, A bf16 [M,K] @ Bt bf16 [Nc,K]^T + bias ----------------
// 128x128 tile, BK=32, 4 waves, global_load_lds staging, chunk-XOR LDS swizzle.
// blockIdx.z selects pair. OUTBF: 0 -> C f32, 1 -> C bf16.
template<int OUTBF>
__global__ __launch_bounds__(256) void gemm_bf16_kernel(
    const unsigned short* __restrict__ A0, const unsigned short* __restrict__ A1,
    const unsigned short* __restrict__ Bt0, const unsigned short* __restrict__ Bt1,
    const float* __restrict__ bias0, const float* __restrict__ bias1,
    void* __restrict__ Cv0, void* __restrict__ Cv1,
    int M, int K, int Nc)
{
    __shared__ __align__(16) unsigned short As[128 * 32];
    __shared__ __align__(16) unsigned short Bs[128 * 32];
    const int z = blockIdx.z;
    const unsigned short* A  = z ? A1  : A0;
    const unsigned short* Bt = z ? Bt1 : Bt0;
    const float* bias = z ? bias1 : bias0;
    const int t = threadIdx.x;
    const int lane = t & 63, w = t >> 6;
    const int wr = w >> 1, wc = w & 1;
    const int bm = blockIdx.y * 128, bn = blockIdx.x * 128;

    f32x4 acc[4][4];
    #pragma unroll
    for (int m = 0; m < 4; ++m)
        #pragma unroll
        for (int n = 0; n < 4; ++n)
            acc[m][n] = (f32x4){0.f, 0.f, 0.f, 0.f};

    const int c0 = w * 64 + lane, c1 = c0 + 256;
    const int row0 = c0 >> 2, row1 = c1 >> 2;
    const int g0 = (c0 & 3) ^ ((row0 >> 1) & 3);
    const int g1 = (c1 & 3) ^ ((row1 >> 1) & 3);
    const int ar0 = (bm + row0 < M) ? (bm + row0) : (M - 1);
    const int ar1 = (bm + row1 < M) ? (bm + row1) : (M - 1);
    const unsigned short* pA0 = A + (size_t)ar0 * K + g0 * 8;
    const unsigned short* pA1 = A + (size_t)ar1 * K + g1 * 8;
    const unsigned short* pB0 = Bt + (size_t)(bn + row0) * K + g0 * 8;
    const unsigned short* pB1 = Bt + (size_t)(bn + row1) * K + g1 * 8;
    unsigned short* lA0 = As + c0 * 8;
    unsigned short* lA1 = As + c1 * 8;
    unsigned short* lB0 = Bs + c0 * 8;
    unsigned short* lB1 = Bs + c1 * 8;

    const int rA = wr * 64 + (lane & 15);
    const int rB = wc * 64 + (lane & 15);
    const int gw = lane >> 4;

    for (int k0 = 0; k0 < K; k0 += 32) {
        gload16(pA0 + k0, lA0);
        gload16(pA1 + k0, lA1);
        gload16(pB0 + k0, lB0);
        gload16(pB1 + k0, lB1);
        __syncthreads();
        bf16x8 afr[4], bfr[4];
        #pragma unroll
        for (int m = 0; m < 4; ++m) {
            int r = rA + m * 16;
            afr[m] = *(const bf16x8*)&As[r * 32 + ((gw ^ ((r >> 1) & 3)) * 8)];
        }
        #pragma unroll
        for (int n = 0; n < 4; ++n) {
            int r = rB + n * 16;
            bfr[n] = *(const bf16x8*)&Bs[r * 32 + ((gw ^ ((r >> 1) & 3)) * 8)];
        }
        #pragma unroll
        for (int m = 0; m < 4; ++m)
            #pragma unroll
            for (int n = 0; n < 4; ++n)
                acc[m][n] = __builtin_amdgcn_mfma_f32_16x16x32_bf16(afr[m], bfr[n], acc[m][n], 0, 0, 0);
        __syncthreads();
    }
    #pragma unroll
    for (int m = 0; m < 4; ++m) {
        #pragma unroll
        for (int j = 0; j < 4; ++j) {
            int row = bm + wr * 64 + m * 16 + (lane >> 4) * 4 + j;
            if (row >= M) continue;
            #pragma unroll
            for (int n = 0; n < 4; ++n) {
                int col = bn + wc * 64 + n * 16 + (lane & 15);
                float v = acc[m][n][j] + bias[col];
                if (OUTBF) ((unsigned short*)(z ? Cv1 : Cv0))[(size_t)row * Nc + col] = f2bf(v);
                else       ((float*)(z ? Cv1 : Cv0))[(size_t)row * Nc + col] = v;
            }
        }
    }
}

// ---------------- sem MFMA: partial[c] += sum_rows tanh( relu(A) @ Wkt^T + bk )[c] ----------------
#define LDK 40
__global__ __launch_bounds__(256) void sem_mfma_kernel(
    const float* __restrict__ A, const unsigned short* __restrict__ Bt,
    const float* __restrict__ bk, float* __restrict__ partial,
    int M, int K, int Nc)
{
    __shared__ unsigned short As[128][LDK];
    __shared__ unsigned short Bs[128][LDK];
    __shared__ float red[128];
    const int t = threadIdx.x;
    const int lane = t & 63, w = t >> 6;
    const int wr = w >> 1, wc = w & 1;
    const int bm = blockIdx.y * 128, bn = blockIdx.x * 128;

    f32x4 acc[4][4];
    #pragma unroll
    for (int m = 0; m < 4; ++m)
        #pragma unroll
        for (int n = 0; n < 4; ++n)
            acc[m][n] = (f32x4){0.f, 0.f, 0.f, 0.f};

    const int ko = (lane >> 4) * 8;
    const int rA = wr * 64 + (lane & 15);
    const int rB = wc * 64 + (lane & 15);

    for (int k0 = 0; k0 < K; k0 += 32) {
        #pragma unroll
        for (int i = 0; i < 4; ++i) {
            int s = t + i * 256;
            int r = s >> 3, kg = s & 7;
            int row = bm + r;
            float4 v = make_float4(0.f, 0.f, 0.f, 0.f);
            if (row < M) v = *(const float4*)(A + (size_t)row * K + k0 + kg * 4);
            ushort4 b;
            b.x = f2bf(fmaxf(v.x, 0.f)); b.y = f2bf(fmaxf(v.y, 0.f));
            b.z = f2bf(fmaxf(v.z, 0.f)); b.w = f2bf(fmaxf(v.w, 0.f));
            *(ushort4*)&As[r][kg * 4] = b;
        }
        #pragma unroll
        for (int i = 0; i < 2; ++i) {
            int s = t + i * 256;
            int n = s >> 2, kg = s & 3;
            *(bf16x8*)&Bs[n][kg * 8] =
                *(const bf16x8*)(Bt + (size_t)(bn + n) * K + k0 + kg * 8);
        }
        __syncthreads();
        bf16x8 afr[4], bfr[4];
        #pragma unroll
        for (int m = 0; m < 4; ++m) afr[m] = *(const bf16x8*)&As[rA + m * 16][ko];
        #pragma unroll
        for (int n = 0; n < 4; ++n) bfr[n] = *(const bf16x8*)&Bs[rB + n * 16][ko];
        #pragma unroll
        for (int m = 0; m < 4; ++m)
            #pragma unroll
            for (int n = 0; n < 4; ++n)
                acc[m][n] = __builtin_amdgcn_mfma_f32_16x16x32_bf16(afr[m], bfr[n], acc[m][n], 0, 0, 0);
        __syncthreads();
    }
    if (t < 128) red[t] = 0.f;
    __syncthreads();
    #pragma unroll
    for (int n = 0; n < 4; ++n) {
        int lcol = wc * 64 + n * 16 + (lane & 15);
        float b = bk[bn + lcol];
        float s = 0.f;
        #pragma unroll
        for (int m = 0; m < 4; ++m) {
            #pragma unroll
            for (int j = 0; j < 4; ++j) {
                int row = bm + wr * 64 + m * 16 + (lane >> 4) * 4 + j;
                if (row < M) s += tanhf(acc[m][n][j] + b);
            }
        }
        atomicAdd(&red[lcol], s);
    }
    __syncthreads();
    if (t < 128) atomicAdd(&partial[bn + t], red[t]);
}

// Wt[n*K+k] = bf16(W[k*Nc+n])
__global__ void transconv_kernel(const float* __restrict__ W, unsigned short* __restrict__ Wt,
                                 int K, int Nc)
{
    int gid = blockIdx.x * 256 + threadIdx.x;
    if (gid >= K * Nc) return;
    int k = gid / Nc, n = gid - k * Nc;
    Wt[(size_t)n * K + k] = f2bf(W[gid]);
}

// ---------------- CSR build ----------------
__global__ void hist_kernel(const int* __restrict__ dst, int* __restrict__ deg, int E)
{
    int e = blockIdx.x * 256 + threadIdx.x;
    if (e < E) atomicAdd(&deg[dst[e]], 1);
}

__global__ void block_sum_kernel(const int* __restrict__ deg, int* __restrict__ bsum, int n)
{
    __shared__ int buf[256];
    int i = blockIdx.x * 256 + threadIdx.x;
    buf[threadIdx.x] = (i < n) ? deg[i] : 0;
    __syncthreads();
    for (int s = 128; s > 0; s >>= 1) {
        if (threadIdx.x < s) buf[threadIdx.x] += buf[threadIdx.x + s];
        __syncthreads();
    }
    if (threadIdx.x == 0) bsum[blockIdx.x] = buf[0];
}

__global__ void scan_bsum_kernel(const int* __restrict__ bsum, int* __restrict__ boff, int nb)
{
    __shared__ int buf[256];
    int tid = threadIdx.x;
    int v = (tid < nb) ? bsum[tid] : 0;
    buf[tid] = v;
    __syncthreads();
    for (int off = 1; off < 256; off <<= 1) {
        int t = (tid >= off) ? buf[tid - off] : 0;
        __syncthreads();
        buf[tid] += t;
        __syncthreads();
    }
    if (tid < nb) boff[tid] = buf[tid] - v;
}

__global__ void scan_final_kernel(const int* __restrict__ deg, const int* __restrict__ boff,
                                  int* __restrict__ offs, int n)
{
    __shared__ int buf[256];
    int tid = threadIdx.x, b = blockIdx.x;
    int i = b * 256 + tid;
    int v = (i < n) ? deg[i] : 0;
    buf[tid] = v;
    __syncthreads();
    for (int off = 1; off < 256; off <<= 1) {
        int t = (tid >= off) ? buf[tid - off] : 0;
        __syncthreads();
        buf[tid] += t;
        __syncthreads();
    }
    if (i < n) offs[i] = boff[b] + buf[tid] - v;
    if (i == n - 1) offs[n] = boff[b] + buf[tid];
}

__global__ void place_kernel(const int* __restrict__ src, const int* __restrict__ dst,
                             const int* __restrict__ offs, int* __restrict__ cnt,
                             int* __restrict__ esrc, int E)
{
    int e = blockIdx.x * 256 + threadIdx.x;
    if (e >= E) return;
    int d = dst[e];
    int p = offs[d] + atomicAdd(&cnt[d], 1);
    esrc[p] = src[e];
}

// ---------------- node score dots (bf16 features) ----------------
__global__ void node_scores_bf16_kernel(const unsigned short* __restrict__ x, const float* __restrict__ a,
                                        float* __restrict__ s, int n, int H, int D)
{
    int gid = blockIdx.x * blockDim.x + threadIdx.x;
    if (gid >= n * H) return;
    int node = gid / H, h = gid - node * H;
    const unsigned short* xr = x + (size_t)node * H * D + h * D;
    const float* ar = a + h * D;
    float acc = 0.f;
    for (int d = 0; d < D; d += 8) {
        u16x8 xv = *(const u16x8*)(xr + d);
        #pragma unroll
        for (int j = 0; j < 8; ++j) acc += bf2f(xv[j]) * ar[d + j];
    }
    s[gid] = acc;
}

// ---------------- per-(dst,head) segment softmax -> normalized alpha ----------------
__global__ void seg_alpha_kernel(const int* __restrict__ offs, const int* __restrict__ esrc,
                                 const float* __restrict__ ssrc, const float* __restrict__ sdst,
                                 float* __restrict__ alpha, int H)
{
    int gid = blockIdx.x * 256 + threadIdx.x;
    if (gid >= NN * H) return;
    int d = gid / H, h = gid - d * H;
    int beg = offs[d], end = offs[d + 1];
    float sd = sdst[gid];
    float m = -INFINITY, den = 0.f;
    for (int i = beg; i < end; ++i) {
        int s = esrc[i];
        float v = ssrc[s * H + h] + sd;
        v = (v >= 0.f) ? v : 0.2f * v;
        if (v > m) { den = den * expf(m - v) + 1.f; m = v; }
        else       den += expf(v - m);
    }
    float inv = 1.f / (den + 1e-16f);
    for (int i = beg; i < end; ++i) {
        int s = esrc[i];
        float v = ssrc[s * H + h] + sd;
        v = (v >= 0.f) ? v : 0.2f * v;
        alpha[(size_t)i * H + h] = expf(v - m) * inv;
    }
}

// ---------------- weighted gather: one wave per dst node ----------------
// CPL channels per lane (C = 64*CPL). DSH: h = c >> DSH.
template<int CPL, int HH, int DSH>
__global__ __launch_bounds__(256) void gather_w_kernel(
    const int* __restrict__ offs, const int* __restrict__ esrc,
    const float* __restrict__ alpha, const unsigned short* __restrict__ x,
    float* __restrict__ outp, int C)
{
    int wid = threadIdx.x >> 6, lane = threadIdx.x & 63;
    int d = blockIdx.x * 4 + wid;
    int c0 = lane * CPL;
    int h = c0 >> DSH;
    int beg = offs[d], end = offs[d + 1];
    float acc[CPL];
    #pragma unroll
    for (int j = 0; j < CPL; ++j) acc[j] = 0.f;
    for (int i = beg; i < end; ++i) {
        int s = esrc[i];
        float a = alpha[(size_t)i * HH + h];
        const unsigned short* xp = x + (size_t)s * C + c0;
        if (CPL == 4) {
            ushort4 xv = *(const ushort4*)xp;
            acc[0] += a * bf2f(xv.x); acc[1] += a * bf2f(xv.y);
            acc[2] += a * bf2f(xv.z); acc[3] += a * bf2f(xv.w);
        } else {
            ushort2 xv = *(const ushort2*)xp;
            acc[0] += a * bf2f(xv.x); acc[1] += a * bf2f(xv.y);
        }
    }
    float* op = outp + (size_t)d * C + c0;
    #pragma unroll
    for (int j = 0; j < CPL; ++j) op[j] = acc[j];
}

__global__ void sem_weights_kernel(const float* __restrict__ partial, const float* __restrict__ q,
                                   float* __restrict__ w, int C, int n)
{
    if (threadIdx.x != 0 || blockIdx.x != 0) return;
    float inv = 1.f / (float)n;
    float s0 = 0.f, s1 = 0.f;
    for (int c = 0; c < C; ++c) {
        s0 += q[c] * partial[c] * inv;
        s1 += q[c] * partial[C + c] * inv;
    }
    float m = fmaxf(s0, s1);
    float e0 = expf(s0 - m), e1 = expf(s1 - m);
    float den = e0 + e1;
    w[0] = e0 / den;
    w[1] = e1 / den;
}

__global__ void combine2_bf16_kernel(const float* __restrict__ a, const float* __restrict__ b,
                                     const float* __restrict__ w, unsigned short* __restrict__ out,
                                     long long n)
{
    long long gid = (long long)blockIdx.x * blockDim.x + threadIdx.x;
    if (gid >= n) return;
    out[gid] = f2bf(w[0] * fmaxf(a[gid], 0.f) + w[1] * fmaxf(b[gid], 0.f));
}

__global__ void relu_copy_bf16_kernel(const float* __restrict__ a, unsigned short* __restrict__ out,
                                      long long n)
{
    long long gid = (long long)blockIdx.x * blockDim.x + threadIdx.x;
    if (gid >= n) return;
    out[gid] = f2bf(fmaxf(a[gid], 0.f));
}

__global__ __launch_bounds__(128) void final_norm_kernel(
    const float* __restrict__ aggW, const float* __restrict__ aggC,
    const float* __restrict__ aggB, const float* __restrict__ w,
    float* __restrict__ out)
{
    __shared__ float red[128];
    int row = blockIdx.x;
    int c = threadIdx.x;
    float v;
    if (row < NN) {
        size_t i = (size_t)row * DOUT + c;
        v = w[0] * fmaxf(aggW[i], 0.f) + w[1] * fmaxf(aggC[i], 0.f);
    } else {
        size_t i = (size_t)(row - NN) * DOUT + c;
        v = fmaxf(aggB[i], 0.f);
    }
    red[c] = v * v;
    __syncthreads();
    for (int s = 64; s > 0; s >>= 1) {
        if (c < s) red[c] += red[c + s];
        __syncthreads();
    }
    float norm = sqrtf(red[0]);
    out[(size_t)row * DOUT + c] = v / fmaxf(norm, 1e-12f);
}

// ------------------------------------------------------------------
static void build_csr(const int* ei, int* offs, int* esrc, int* deg, int* bsum, int* boff,
                      hipStream_t stream)
{
    const int* src = ei;
    const int* dst = ei + NE;
    const int NB = (NN + 255) / 256;
    hipMemsetAsync(deg, 0, NN * sizeof(int), stream);
    hist_kernel<<<(NE + 255) / 256, 256, 0, stream>>>(dst, deg, NE);
    block_sum_kernel<<<NB, 256, 0, stream>>>(deg, bsum, NN);
    scan_bsum_kernel<<<1, 256, 0, stream>>>(bsum, boff, NB);
    scan_final_kernel<<<NB, 256, 0, stream>>>(deg, boff, offs, NN);
    hipMemsetAsync(deg, 0, NN * sizeof(int), stream);
    place_kernel<<<(NE + 255) / 256, 256, 0, stream>>>(src, dst, offs, deg, esrc, NE);
}

// L0 relation (H=8, D=32, C=256, CPL=4)
static void process_rel_L0(const unsigned short* xsrc, const unsigned short* xdst,
                           const float* a_s, const float* a_d,
                           const int* offs, const int* esrc,
                           float* agg, float* ssrc, float* sdst, float* alpha,
                           hipStream_t stream)
{
    int nt = NN * H0;
    node_scores_bf16_kernel<<<(nt + 255) / 256, 256, 0, stream>>>(xsrc, a_s, ssrc, NN, H0, D0);
    node_scores_bf16_kernel<<<(nt + 255) / 256, 256, 0, stream>>>(xdst, a_d, sdst, NN, H0, D0);
    seg_alpha_kernel<<<(nt + 255) / 256, 256, 0, stream>>>(offs, esrc, ssrc, sdst, alpha, H0);
    gather_w_kernel<4, H0, 5><<<NN / 4, 256, 0, stream>>>(offs, esrc, alpha, xsrc, agg, DHID);
}

// L1 relation (H=1, D=128, C=128, CPL=2)
static void process_rel_L1(const unsigned short* xsrc, const unsigned short* xdst,
                           const float* a_s, const float* a_d,
                           const int* offs, const int* esrc,
                           float* agg, float* ssrc, float* sdst, float* alpha,
                           hipStream_t stream)
{
    int nt = NN;
    node_scores_bf16_kernel<<<(nt + 255) / 256, 256, 0, stream>>>(xsrc, a_s, ssrc, NN, 1, DOUT);
    node_scores_bf16_kernel<<<(nt + 255) / 256, 256, 0, stream>>>(xdst, a_d, sdst, NN, 1, DOUT);
    seg_alpha_kernel<<<(nt + 255) / 256, 256, 0, stream>>>(offs, esrc, ssrc, sdst, alpha, 1);
    gather_w_kernel<2, 1, 7><<<NN / 4, 256, 0, stream>>>(offs, esrc, alpha, xsrc, agg, DOUT);
}

extern "C" void kernel_launch(void* const* d_in, const int* in_sizes, int n_in,
                              void* d_out, int out_size, void* d_ws, size_t ws_size,
                              hipStream_t stream)
{
    const float* x_paper   = (const float*)d_in[0];
    const float* x_author  = (const float*)d_in[1];
    const int*   ei_writes = (const int*)d_in[2];
    const int*   ei_wb     = (const int*)d_in[3];
    const int*   ei_cites  = (const int*)d_in[4];
    const float* W0p = (const float*)d_in[5];  const float* b0p = (const float*)d_in[6];
    const float* W0a = (const float*)d_in[7];  const float* b0a = (const float*)d_in[8];
    const float* a0s_w  = (const float*)d_in[9];  const float* a0d_w  = (const float*)d_in[10];
    const float* a0s_wb = (const float*)d_in[11]; const float* a0d_wb = (const float*)d_in[12];
    const float* a0s_c  = (const float*)d_in[13]; const float* a0d_c  = (const float*)d_in[14];
    const float* Wk0 = (const float*)d_in[15]; const float* bk0 = (const float*)d_in[16];
    const float* q0  = (const float*)d_in[17];
    const float* W1p = (const float*)d_in[18]; const float* b1p = (const float*)d_in[19];
    const float* W1a = (const float*)d_in[20]; const float* b1a = (const float*)d_in[21];
    const float* a1s_w  = (const float*)d_in[22]; const float* a1d_w  = (const float*)d_in[23];
    const float* a1s_wb = (const float*)d_in[24]; const float* a1d_wb = (const float*)d_in[25];
    const float* a1s_c  = (const float*)d_in[26]; const float* a1d_c  = (const float*)d_in[27];
    const float* Wk1 = (const float*)d_in[28]; const float* bk1 = (const float*)d_in[29];
    const float* q1  = (const float*)d_in[30];

    float* out = (float*)d_out;

    const size_t NH = (size_t)NN * DHID;   // 12.8M
    const size_t NI = (size_t)NN * DIN;    // 38.4M
    const size_t NO = (size_t)NN * DOUT;   // 6.4M

    // ---- workspace layout ----
    float* xhP = (float*)d_ws;            // region A0 (51.2MB)
    float* xhA = xhP + NH;                // region A1 (51.2MB)
    float* R   = xhA + NH;                // 153.6MB multi-phase region
    // phase A: bf16 raw inputs
    unsigned short* xbP = (unsigned short*)R;
    unsigned short* xbA = xbP + NI;
    // phase B: layer-0 aggregates (f32)
    float* aggW = R;
    float* aggC = R + NH;
    float* aggB = R + 2 * NH;
    // phase C: layer-1 aggregates (f32)
    float* agg1W = R;
    float* agg1C = R + NO;
    float* agg1B = R + 2 * NO;
    // L0 bf16 features live in region A; h bf16 aliases same region later
    unsigned short* xbhP = (unsigned short*)xhP;       // NH u16
    unsigned short* xbhA = (unsigned short*)xhA;       // NH u16
    unsigned short* hbP  = (unsigned short*)xhP;       // NH u16 (after gathers done)
    unsigned short* hbA  = (unsigned short*)xhA;       // NH u16
    unsigned short* x1Pb = (unsigned short*)xhA + NH;  // NO u16
    unsigned short* x1Ab = x1Pb + NO;                  // NO u16

    float* ssrc = R + 3 * NH;             // NN*H0
    float* sdst = ssrc + (size_t)NN * H0;
    float* tsum = sdst + (size_t)NN * H0; // 512
    float* wsem = tsum + 512;             // 8
    int* ip      = (int*)(wsem + 8);
    int* offsW   = ip;               ip += NN + 4;
    int* offsWB  = ip;               ip += NN + 4;
    int* offsC   = ip;               ip += NN + 4;
    int* esrcW   = ip;               ip += NE;
    int* esrcWB  = ip;               ip += NE;
    int* esrcC   = ip;               ip += NE;
    int* deg     = ip;               ip += NN;
    int* bsum    = ip;               ip += 256;
    int* boff    = ip;               ip += 256;
    unsigned short* wt0p = (unsigned short*)ip;        // DHID*DIN u16
    unsigned short* wt0a = wt0p + (size_t)DHID * DIN;
    unsigned short* wkt  = wt0a + (size_t)DHID * DIN;  // up to DHID*DHID u16
    unsigned short* wt1p = wt0p;                       // alias after L0 GEMMs
    unsigned short* wt1a = wt1p + (size_t)DOUT * DHID;
    float* alpha = (float*)(wkt + (size_t)DHID * DHID); // NE*H0 f32 (9.6MB)

    // ---- CSR build (shared by both layers) ----
    build_csr(ei_writes, offsW,  esrcW,  deg, bsum, boff, stream);
    build_csr(ei_wb,     offsWB, esrcWB, deg, bsum, boff, stream);
    build_csr(ei_cites,  offsC,  esrcC,  deg, bsum, boff, stream);

    // ================= layer 0 =================
    hipMemsetAsync(tsum, 0, 512 * sizeof(float), stream);
    convert_bf16_kernel<<<(int)((NI / 8 + 255) / 256), 256, 0, stream>>>(x_paper,  xbP, (int)(NI / 8));
    convert_bf16_kernel<<<(int)((NI / 8 + 255) / 256), 256, 0, stream>>>(x_author, xbA, (int)(NI / 8));
    transconv_kernel<<<(DIN * DHID + 255) / 256, 256, 0, stream>>>(W0p, wt0p, DIN, DHID);
    transconv_kernel<<<(DIN * DHID + 255) / 256, 256, 0, stream>>>(W0a, wt0a, DIN, DHID);
    transconv_kernel<<<(DHID * DHID + 255) / 256, 256, 0, stream>>>(Wk0, wkt, DHID, DHID);

    dim3 g0(DHID / 128, (NN + 127) / 128, 2);
    gemm_bf16_kernel<1><<<g0, 256, 0, stream>>>(xbP, xbA, wt0p, wt0a, b0p, b0a, xbhP, xbhA, NN, DIN, DHID);

    // writes: author->paper ; written_by: paper->author ; cites: paper->paper
    process_rel_L0(xbhA, xbhP, a0s_w,  a0d_w,  offsW,  esrcW,  aggW, ssrc, sdst, alpha, stream);
    process_rel_L0(xbhP, xbhA, a0s_wb, a0d_wb, offsWB, esrcWB, aggB, ssrc, sdst, alpha, stream);
    process_rel_L0(xbhP, xbhP, a0s_c,  a0d_c,  offsC,  esrcC,  aggC, ssrc, sdst, alpha, stream);

    // semantic attention (paper: M=2; author: M=1 -> identity)
    dim3 gs0(DHID / 128, (NN + 127) / 128);
    sem_mfma_kernel<<<gs0, 256, 0, stream>>>(aggW, wkt, bk0, tsum,        NN, DHID, DHID);
    sem_mfma_kernel<<<gs0, 256, 0, stream>>>(aggC, wkt, bk0, tsum + DHID, NN, DHID, DHID);
    sem_weights_kernel<<<1, 64, 0, stream>>>(tsum, q0, wsem, DHID, NN);

    long long nel0 = (long long)NH;
    combine2_bf16_kernel<<<(int)((nel0 + 255) / 256), 256, 0, stream>>>(aggW, aggC, wsem, hbP, nel0);
    relu_copy_bf16_kernel<<<(int)((nel0 + 255) / 256), 256, 0, stream>>>(aggB, hbA, nel0);

    // ================= layer 1 =================
    transconv_kernel<<<(DHID * DOUT + 255) / 256, 256, 0, stream>>>(W1p, wt1p, DHID, DOUT);
    transconv_kernel<<<(DHID * DOUT + 255) / 256, 256, 0, stream>>>(W1a, wt1a, DHID, DOUT);
    transconv_kernel<<<(DOUT * DOUT + 255) / 256, 256, 0, stream>>>(Wk1, wkt, DOUT, DOUT);

    dim3 g1(DOUT / 128, (NN + 127) / 128, 2);
    gemm_bf16_kernel<1><<<g1, 256, 0, stream>>>(hbP, hbA, wt1p, wt1a, b1p, b1a, x1Pb, x1Ab, NN, DHID, DOUT);

    hipMemsetAsync(tsum, 0, 2 * DOUT * sizeof(float), stream);

    process_rel_L1(x1Ab, x1Pb, a1s_w,  a1d_w,  offsW,  esrcW,  agg1W, ssrc, sdst, alpha, stream);
    process_rel_L1(x1Pb, x1Ab, a1s_wb, a1d_wb, offsWB, esrcWB, agg1B, ssrc, sdst, alpha, stream);
    process_rel_L1(x1Pb, x1Pb, a1s_c,  a1d_c,  offsC,  esrcC,  agg1C, ssrc, sdst, alpha, stream);

    dim3 gs1(DOUT / 128, (NN + 127) / 128);
    sem_mfma_kernel<<<gs1, 256, 0, stream>>>(agg1W, wkt, bk1, tsum,        NN, DOUT, DOUT);
    sem_mfma_kernel<<<gs1, 256, 0, stream>>>(agg1C, wkt, bk1, tsum + DOUT, NN, DOUT, DOUT);
    sem_weights_kernel<<<1, 64, 0, stream>>>(tsum, q1, wsem, DOUT, NN);

    final_norm_kernel<<<2 * NN, 128, 0, stream>>>(agg1W, agg1C, agg1B, wsem, out);
}

// Round 7
// 871.836 us; speedup vs baseline: 7.7147x; 1.1929x over previous
//
#include <hip/hip_runtime.h>
#include <math.h>

#define NN 50000
#define NE 300000
#define DIN 768
#define DHID 256
#define DOUT 128
#define H0 8
#define D0 32

typedef __attribute__((ext_vector_type(8))) short bf16x8;
typedef __attribute__((ext_vector_type(8))) unsigned short u16x8;
typedef __attribute__((ext_vector_type(4))) float f32x4;

__device__ __forceinline__ unsigned short f2bf(float f) {
    unsigned u = __float_as_uint(f);
    unsigned r = (u + 0x7fffu + ((u >> 16) & 1u)) >> 16;
    return (unsigned short)r;
}
__device__ __forceinline__ float bf2f(unsigned short u) {
    return __uint_as_float(((unsigned)u) << 16);
}

__device__ __forceinline__ void gload16(const void* g, void* l) {
    __builtin_amdgcn_global_load_lds(
        (const __attribute__((address_space(1))) unsigned int*)g,
        (__attribute__((address_space(3))) unsigned int*)l, 16, 0, 0);
}

// ---------------- f32 -> bf16 stream convert ----------------
__global__ void convert_bf16_kernel(const float* __restrict__ in, unsigned short* __restrict__ out, int n8)
{
    int i = blockIdx.x * 256 + threadIdx.x;
    if (i >= n8) return;
    float4 a = ((const float4*)in)[i * 2];
    float4 b = ((const float4*)in)[i * 2 + 1];
    u16x8 o;
    o[0] = f2bf(a.x); o[1] = f2bf(a.y); o[2] = f2bf(a.z); o[3] = f2bf(a.w);
    o[4] = f2bf(b.x); o[5] = f2bf(b.y); o[6] = f2bf(b.z); o[7] = f2bf(b.w);
    ((u16x8*)out)[i] = o;
}

// Wt[n*K+k] = bf16(W[k*Nc+n])
__global__ void transconv_kernel(const float* __restrict__ W, unsigned short* __restrict__ Wt,
                                 int K, int Nc)
{
    int gid = blockIdx.x * 256 + threadIdx.x;
    if (gid >= K * Nc) return;
    int k = gid / Nc, n = gid - k * Nc;
    Wt[(size_t)n * K + k] = f2bf(W[gid]);
}

// ---------------- MFMA GEMM, double-buffered 2-phase prefetch ----------------
// A bf16 [M,K] @ Bt bf16 [Nc,K]^T + bias -> C bf16. 128x128 tile, BK=32, 4 waves.
// global_load_lds staging with chunk-XOR swizzle; blockIdx.z selects GEMM pair.
__global__ __launch_bounds__(256) void gemm_bf16_kernel(
    const unsigned short* __restrict__ A0, const unsigned short* __restrict__ A1,
    const unsigned short* __restrict__ Bt0, const unsigned short* __restrict__ Bt1,
    const float* __restrict__ bias0, const float* __restrict__ bias1,
    unsigned short* __restrict__ C0, unsigned short* __restrict__ C1,
    int M, int K, int Nc)
{
    __shared__ __align__(16) unsigned short As[2][128 * 32];
    __shared__ __align__(16) unsigned short Bs[2][128 * 32];
    const int z = blockIdx.z;
    const unsigned short* A  = z ? A1  : A0;
    const unsigned short* Bt = z ? Bt1 : Bt0;
    const float* bias = z ? bias1 : bias0;
    unsigned short* C = z ? C1 : C0;
    const int t = threadIdx.x;
    const int lane = t & 63, w = t >> 6;
    const int wr = w >> 1, wc = w & 1;
    const int bm = blockIdx.y * 128, bn = blockIdx.x * 128;

    f32x4 acc[4][4];
    #pragma unroll
    for (int m = 0; m < 4; ++m)
        #pragma unroll
        for (int n = 0; n < 4; ++n)
            acc[m][n] = (f32x4){0.f, 0.f, 0.f, 0.f};

    const int c0 = w * 64 + lane, c1 = c0 + 256;
    const int row0 = c0 >> 2, row1 = c1 >> 2;
    const int g0 = (c0 & 3) ^ ((row0 >> 1) & 3);
    const int g1 = (c1 & 3) ^ ((row1 >> 1) & 3);
    const int ar0 = (bm + row0 < M) ? (bm + row0) : (M - 1);
    const int ar1 = (bm + row1 < M) ? (bm + row1) : (M - 1);
    const unsigned short* pA0 = A + (size_t)ar0 * K + g0 * 8;
    const unsigned short* pA1 = A + (size_t)ar1 * K + g1 * 8;
    const unsigned short* pB0 = Bt + (size_t)(bn + row0) * K + g0 * 8;
    const unsigned short* pB1 = Bt + (size_t)(bn + row1) * K + g1 * 8;

    const int rA = wr * 64 + (lane & 15);
    const int rB = wc * 64 + (lane & 15);
    const int gw = lane >> 4;
    const int nt = K >> 5;

    gload16(pA0, &As[0][c0 * 8]);
    gload16(pA1, &As[0][c1 * 8]);
    gload16(pB0, &Bs[0][c0 * 8]);
    gload16(pB1, &Bs[0][c1 * 8]);
    __syncthreads();
    for (int ti = 0; ti < nt; ++ti) {
        const int cur = ti & 1;
        if (ti + 1 < nt) {
            const int nk = (ti + 1) << 5;
            const int nb = cur ^ 1;
            gload16(pA0 + nk, &As[nb][c0 * 8]);
            gload16(pA1 + nk, &As[nb][c1 * 8]);
            gload16(pB0 + nk, &Bs[nb][c0 * 8]);
            gload16(pB1 + nk, &Bs[nb][c1 * 8]);
        }
        bf16x8 afr[4], bfr[4];
        #pragma unroll
        for (int m = 0; m < 4; ++m) {
            int r = rA + m * 16;
            afr[m] = *(const bf16x8*)&As[cur][r * 32 + ((gw ^ ((r >> 1) & 3)) * 8)];
        }
        #pragma unroll
        for (int n = 0; n < 4; ++n) {
            int r = rB + n * 16;
            bfr[n] = *(const bf16x8*)&Bs[cur][r * 32 + ((gw ^ ((r >> 1) & 3)) * 8)];
        }
        #pragma unroll
        for (int m = 0; m < 4; ++m)
            #pragma unroll
            for (int n = 0; n < 4; ++n)
                acc[m][n] = __builtin_amdgcn_mfma_f32_16x16x32_bf16(afr[m], bfr[n], acc[m][n], 0, 0, 0);
        __syncthreads();
    }
    #pragma unroll
    for (int m = 0; m < 4; ++m) {
        #pragma unroll
        for (int j = 0; j < 4; ++j) {
            int row = bm + wr * 64 + m * 16 + (lane >> 4) * 4 + j;
            if (row >= M) continue;
            #pragma unroll
            for (int n = 0; n < 4; ++n) {
                int col = bn + wc * 64 + n * 16 + (lane & 15);
                C[(size_t)row * Nc + col] = f2bf(acc[m][n][j] + bias[col]);
            }
        }
    }
}

// ---------------- sem GEMM (same dbuf structure, bf16 A already relu'd):
// partial[c] += sum_rows tanh( A @ Wkt^T + bk )[c]
__global__ __launch_bounds__(256) void sem_bf16_kernel(
    const unsigned short* __restrict__ A, const unsigned short* __restrict__ Bt,
    const float* __restrict__ bk, float* __restrict__ partial,
    int M, int K, int Nc)
{
    __shared__ __align__(16) unsigned short As[2][128 * 32];
    __shared__ __align__(16) unsigned short Bs[2][128 * 32];
    __shared__ float red[128];
    const int t = threadIdx.x;
    const int lane = t & 63, w = t >> 6;
    const int wr = w >> 1, wc = w & 1;
    const int bm = blockIdx.y * 128, bn = blockIdx.x * 128;

    f32x4 acc[4][4];
    #pragma unroll
    for (int m = 0; m < 4; ++m)
        #pragma unroll
        for (int n = 0; n < 4; ++n)
            acc[m][n] = (f32x4){0.f, 0.f, 0.f, 0.f};

    const int c0 = w * 64 + lane, c1 = c0 + 256;
    const int row0 = c0 >> 2, row1 = c1 >> 2;
    const int g0 = (c0 & 3) ^ ((row0 >> 1) & 3);
    const int g1 = (c1 & 3) ^ ((row1 >> 1) & 3);
    const int ar0 = (bm + row0 < M) ? (bm + row0) : (M - 1);
    const int ar1 = (bm + row1 < M) ? (bm + row1) : (M - 1);
    const unsigned short* pA0 = A + (size_t)ar0 * K + g0 * 8;
    const unsigned short* pA1 = A + (size_t)ar1 * K + g1 * 8;
    const unsigned short* pB0 = Bt + (size_t)(bn + row0) * K + g0 * 8;
    const unsigned short* pB1 = Bt + (size_t)(bn + row1) * K + g1 * 8;

    const int rA = wr * 64 + (lane & 15);
    const int rB = wc * 64 + (lane & 15);
    const int gw = lane >> 4;
    const int nt = K >> 5;

    gload16(pA0, &As[0][c0 * 8]);
    gload16(pA1, &As[0][c1 * 8]);
    gload16(pB0, &Bs[0][c0 * 8]);
    gload16(pB1, &Bs[0][c1 * 8]);
    __syncthreads();
    for (int ti = 0; ti < nt; ++ti) {
        const int cur = ti & 1;
        if (ti + 1 < nt) {
            const int nk = (ti + 1) << 5;
            const int nb = cur ^ 1;
            gload16(pA0 + nk, &As[nb][c0 * 8]);
            gload16(pA1 + nk, &As[nb][c1 * 8]);
            gload16(pB0 + nk, &Bs[nb][c0 * 8]);
            gload16(pB1 + nk, &Bs[nb][c1 * 8]);
        }
        bf16x8 afr[4], bfr[4];
        #pragma unroll
        for (int m = 0; m < 4; ++m) {
            int r = rA + m * 16;
            afr[m] = *(const bf16x8*)&As[cur][r * 32 + ((gw ^ ((r >> 1) & 3)) * 8)];
        }
        #pragma unroll
        for (int n = 0; n < 4; ++n) {
            int r = rB + n * 16;
            bfr[n] = *(const bf16x8*)&Bs[cur][r * 32 + ((gw ^ ((r >> 1) & 3)) * 8)];
        }
        #pragma unroll
        for (int m = 0; m < 4; ++m)
            #pragma unroll
            for (int n = 0; n < 4; ++n)
                acc[m][n] = __builtin_amdgcn_mfma_f32_16x16x32_bf16(afr[m], bfr[n], acc[m][n], 0, 0, 0);
        __syncthreads();
    }
    if (t < 128) red[t] = 0.f;
    __syncthreads();
    #pragma unroll
    for (int n = 0; n < 4; ++n) {
        int lcol = wc * 64 + n * 16 + (lane & 15);
        float b = bk[bn + lcol];
        float s = 0.f;
        #pragma unroll
        for (int m = 0; m < 4; ++m) {
            #pragma unroll
            for (int j = 0; j < 4; ++j) {
                int row = bm + wr * 64 + m * 16 + (lane >> 4) * 4 + j;
                if (row < M) s += tanhf(acc[m][n][j] + b);
            }
        }
        atomicAdd(&red[lcol], s);
    }
    __syncthreads();
    if (t < 128) atomicAdd(&partial[bn + t], red[t]);
}

// ---------------- CSR build ----------------
__global__ void hist_kernel(const int* __restrict__ dst, int* __restrict__ deg, int E)
{
    int e = blockIdx.x * 256 + threadIdx.x;
    if (e < E) atomicAdd(&deg[dst[e]], 1);
}

__global__ void block_sum_kernel(const int* __restrict__ deg, int* __restrict__ bsum, int n)
{
    __shared__ int buf[256];
    int i = blockIdx.x * 256 + threadIdx.x;
    buf[threadIdx.x] = (i < n) ? deg[i] : 0;
    __syncthreads();
    for (int s = 128; s > 0; s >>= 1) {
        if (threadIdx.x < s) buf[threadIdx.x] += buf[threadIdx.x + s];
        __syncthreads();
    }
    if (threadIdx.x == 0) bsum[blockIdx.x] = buf[0];
}

__global__ void scan_bsum_kernel(const int* __restrict__ bsum, int* __restrict__ boff, int nb)
{
    __shared__ int buf[256];
    int tid = threadIdx.x;
    int v = (tid < nb) ? bsum[tid] : 0;
    buf[tid] = v;
    __syncthreads();
    for (int off = 1; off < 256; off <<= 1) {
        int t = (tid >= off) ? buf[tid - off] : 0;
        __syncthreads();
        buf[tid] += t;
        __syncthreads();
    }
    if (tid < nb) boff[tid] = buf[tid] - v;
}

__global__ void scan_final_kernel(const int* __restrict__ deg, const int* __restrict__ boff,
                                  int* __restrict__ offs, int n)
{
    __shared__ int buf[256];
    int tid = threadIdx.x, b = blockIdx.x;
    int i = b * 256 + tid;
    int v = (i < n) ? deg[i] : 0;
    buf[tid] = v;
    __syncthreads();
    for (int off = 1; off < 256; off <<= 1) {
        int t = (tid >= off) ? buf[tid - off] : 0;
        __syncthreads();
        buf[tid] += t;
        __syncthreads();
    }
    if (i < n) offs[i] = boff[b] + buf[tid] - v;
    if (i == n - 1) offs[n] = boff[b] + buf[tid];
}

__global__ void place_kernel(const int* __restrict__ src, const int* __restrict__ dst,
                             const int* __restrict__ offs, int* __restrict__ cnt,
                             int* __restrict__ esrc, int E)
{
    int e = blockIdx.x * 256 + threadIdx.x;
    if (e >= E) return;
    int d = dst[e];
    int p = offs[d] + atomicAdd(&cnt[d], 1);
    esrc[p] = src[e];
}

// ---------------- fused per-layer node scores ----------------
// L0: paper -> 4 dots (a0d_w, a0s_wb, a0s_c, a0d_c); author -> 2 dots (a0s_w, a0d_wb)
__global__ void scores_L0_kernel(
    const unsigned short* __restrict__ xp, const unsigned short* __restrict__ xa,
    const float* __restrict__ a_dw, const float* __restrict__ a_swb,
    const float* __restrict__ a_sc, const float* __restrict__ a_dc,
    const float* __restrict__ a_sw, const float* __restrict__ a_dwb,
    float* __restrict__ sW_dst, float* __restrict__ sWB_src,
    float* __restrict__ sC_src, float* __restrict__ sC_dst,
    float* __restrict__ sW_src, float* __restrict__ sWB_dst)
{
    int gid = blockIdx.x * 256 + threadIdx.x;
    int half = NN * H0;
    if (gid >= 2 * half) return;
    if (gid < half) {
        int node = gid >> 3, h = gid & 7;
        const unsigned short* xr = xp + (size_t)node * DHID + h * D0;
        float xv[D0];
        #pragma unroll
        for (int j = 0; j < 4; ++j) {
            u16x8 v = ((const u16x8*)xr)[j];
            #pragma unroll
            for (int k = 0; k < 8; ++k) xv[j * 8 + k] = bf2f(v[k]);
        }
        const float* p0 = a_dw  + h * D0;
        const float* p1 = a_swb + h * D0;
        const float* p2 = a_sc  + h * D0;
        const float* p3 = a_dc  + h * D0;
        float d0 = 0.f, d1 = 0.f, d2 = 0.f, d3 = 0.f;
        #pragma unroll
        for (int k = 0; k < D0; ++k) {
            float x = xv[k];
            d0 += x * p0[k]; d1 += x * p1[k]; d2 += x * p2[k]; d3 += x * p3[k];
        }
        sW_dst[gid] = d0; sWB_src[gid] = d1; sC_src[gid] = d2; sC_dst[gid] = d3;
    } else {
        int g = gid - half;
        int node = g >> 3, h = g & 7;
        const unsigned short* xr = xa + (size_t)node * DHID + h * D0;
        float xv[D0];
        #pragma unroll
        for (int j = 0; j < 4; ++j) {
            u16x8 v = ((const u16x8*)xr)[j];
            #pragma unroll
            for (int k = 0; k < 8; ++k) xv[j * 8 + k] = bf2f(v[k]);
        }
        const float* p0 = a_sw  + h * D0;
        const float* p1 = a_dwb + h * D0;
        float d0 = 0.f, d1 = 0.f;
        #pragma unroll
        for (int k = 0; k < D0; ++k) {
            float x = xv[k];
            d0 += x * p0[k]; d1 += x * p1[k];
        }
        sW_src[g] = d0; sWB_dst[g] = d1;
    }
}

// L1 (H=1, D=128)
__global__ void scores_L1_kernel(
    const unsigned short* __restrict__ xp, const unsigned short* __restrict__ xa,
    const float* __restrict__ a_dw, const float* __restrict__ a_swb,
    const float* __restrict__ a_sc, const float* __restrict__ a_dc,
    const float* __restrict__ a_sw, const float* __restrict__ a_dwb,
    float* __restrict__ sW_dst, float* __restrict__ sWB_src,
    float* __restrict__ sC_src, float* __restrict__ sC_dst,
    float* __restrict__ sW_src, float* __restrict__ sWB_dst)
{
    int gid = blockIdx.x * 256 + threadIdx.x;
    if (gid >= 2 * NN) return;
    if (gid < NN) {
        const unsigned short* xr = xp + (size_t)gid * DOUT;
        float d0 = 0.f, d1 = 0.f, d2 = 0.f, d3 = 0.f;
        for (int j = 0; j < DOUT / 8; ++j) {
            u16x8 v = ((const u16x8*)xr)[j];
            #pragma unroll
            for (int k = 0; k < 8; ++k) {
                float x = bf2f(v[k]);
                int c = j * 8 + k;
                d0 += x * a_dw[c]; d1 += x * a_swb[c]; d2 += x * a_sc[c]; d3 += x * a_dc[c];
            }
        }
        sW_dst[gid] = d0; sWB_src[gid] = d1; sC_src[gid] = d2; sC_dst[gid] = d3;
    } else {
        int g = gid - NN;
        const unsigned short* xr = xa + (size_t)g * DOUT;
        float d0 = 0.f, d1 = 0.f;
        for (int j = 0; j < DOUT / 8; ++j) {
            u16x8 v = ((const u16x8*)xr)[j];
            #pragma unroll
            for (int k = 0; k < 8; ++k) {
                float x = bf2f(v[k]);
                int c = j * 8 + k;
                d0 += x * a_sw[c]; d1 += x * a_dwb[c];
            }
        }
        sW_src[g] = d0; sWB_dst[g] = d1;
    }
}

// ---------------- batched per-(dst,head) segment softmax -> alpha ----------------
__global__ void seg_alpha3_kernel(
    const int* __restrict__ of0, const int* __restrict__ of1, const int* __restrict__ of2,
    const int* __restrict__ es0, const int* __restrict__ es1, const int* __restrict__ es2,
    const float* __restrict__ ss0, const float* __restrict__ ss1, const float* __restrict__ ss2,
    const float* __restrict__ sd0, const float* __restrict__ sd1, const float* __restrict__ sd2,
    float* __restrict__ al0, float* __restrict__ al1, float* __restrict__ al2, int H)
{
    int rel = blockIdx.y;
    const int* offs = rel == 0 ? of0 : (rel == 1 ? of1 : of2);
    const int* esrc = rel == 0 ? es0 : (rel == 1 ? es1 : es2);
    const float* ssrc = rel == 0 ? ss0 : (rel == 1 ? ss1 : ss2);
    const float* sdst = rel == 0 ? sd0 : (rel == 1 ? sd1 : sd2);
    float* alpha = rel == 0 ? al0 : (rel == 1 ? al1 : al2);
    int gid = blockIdx.x * 256 + threadIdx.x;
    if (gid >= NN * H) return;
    int d = gid / H, h = gid - d * H;
    int beg = offs[d], end = offs[d + 1];
    float sd = sdst[gid];
    float m = -INFINITY, den = 0.f;
    for (int i = beg; i < end; ++i) {
        int s = esrc[i];
        float v = ssrc[s * H + h] + sd;
        v = (v >= 0.f) ? v : 0.2f * v;
        if (v > m) { den = den * expf(m - v) + 1.f; m = v; }
        else       den += expf(v - m);
    }
    float inv = 1.f / (den + 1e-16f);
    for (int i = beg; i < end; ++i) {
        int s = esrc[i];
        float v = ssrc[s * H + h] + sd;
        v = (v >= 0.f) ? v : 0.2f * v;
        alpha[(size_t)i * H + h] = expf(v - m) * inv;
    }
}

// ---------------- batched weighted gather: one wave per dst node; out = bf16(relu(sum)) ----------------
template<int CPL, int HH, int DSH>
__global__ __launch_bounds__(256) void gather3_kernel(
    const int* __restrict__ of0, const int* __restrict__ of1, const int* __restrict__ of2,
    const int* __restrict__ es0, const int* __restrict__ es1, const int* __restrict__ es2,
    const float* __restrict__ al0, const float* __restrict__ al1, const float* __restrict__ al2,
    const unsigned short* __restrict__ x0, const unsigned short* __restrict__ x1,
    const unsigned short* __restrict__ x2,
    unsigned short* __restrict__ o0, unsigned short* __restrict__ o1,
    unsigned short* __restrict__ o2, int C)
{
    int rel = blockIdx.y;
    const int* offs = rel == 0 ? of0 : (rel == 1 ? of1 : of2);
    const int* esrc = rel == 0 ? es0 : (rel == 1 ? es1 : es2);
    const float* alpha = rel == 0 ? al0 : (rel == 1 ? al1 : al2);
    const unsigned short* x = rel == 0 ? x0 : (rel == 1 ? x1 : x2);
    unsigned short* outp = rel == 0 ? o0 : (rel == 1 ? o1 : o2);

    int wid = threadIdx.x >> 6, lane = threadIdx.x & 63;
    int d = blockIdx.x * 4 + wid;
    int c0 = lane * CPL;
    int h = c0 >> DSH;
    int beg = offs[d], end = offs[d + 1];
    float acc[CPL];
    #pragma unroll
    for (int j = 0; j < CPL; ++j) acc[j] = 0.f;
    for (int i = beg; i < end; ++i) {
        int s = esrc[i];
        float a = alpha[(size_t)i * HH + h];
        const unsigned short* xp = x + (size_t)s * C + c0;
        if (CPL == 4) {
            ushort4 xv = *(const ushort4*)xp;
            acc[0] += a * bf2f(xv.x); acc[1] += a * bf2f(xv.y);
            acc[2] += a * bf2f(xv.z); acc[3] += a * bf2f(xv.w);
        } else {
            ushort2 xv = *(const ushort2*)xp;
            acc[0] += a * bf2f(xv.x); acc[1] += a * bf2f(xv.y);
        }
    }
    unsigned short* op = outp + (size_t)d * C + c0;
    if (CPL == 4) {
        ushort4 st;
        st.x = f2bf(fmaxf(acc[0], 0.f)); st.y = f2bf(fmaxf(acc[1], 0.f));
        st.z = f2bf(fmaxf(acc[2], 0.f)); st.w = f2bf(fmaxf(acc[3], 0.f));
        *(ushort4*)op = st;
    } else {
        ushort2 st;
        st.x = f2bf(fmaxf(acc[0], 0.f)); st.y = f2bf(fmaxf(acc[1], 0.f));
        *(ushort2*)op = st;
    }
}

__global__ void sem_weights_kernel(const float* __restrict__ partial, const float* __restrict__ q,
                                   float* __restrict__ w, int C, int n)
{
    if (threadIdx.x != 0 || blockIdx.x != 0) return;
    float inv = 1.f / (float)n;
    float s0 = 0.f, s1 = 0.f;
    for (int c = 0; c < C; ++c) {
        s0 += q[c] * partial[c] * inv;
        s1 += q[c] * partial[C + c] * inv;
    }
    float m = fmaxf(s0, s1);
    float e0 = expf(s0 - m), e1 = expf(s1 - m);
    float den = e0 + e1;
    w[0] = e0 / den;
    w[1] = e1 / den;
}

// hP(bf16) = w0*aW + w1*aC  (aggs already relu'd, weights >= 0 -> no relu/ELU needed)
__global__ void combine2_bf16_kernel(const unsigned short* __restrict__ a,
                                     const unsigned short* __restrict__ b,
                                     const float* __restrict__ w, unsigned short* __restrict__ out,
                                     int n8)
{
    int i = blockIdx.x * 256 + threadIdx.x;
    if (i >= n8) return;
    float w0 = w[0], w1 = w[1];
    u16x8 va = ((const u16x8*)a)[i];
    u16x8 vb = ((const u16x8*)b)[i];
    u16x8 o;
    #pragma unroll
    for (int j = 0; j < 8; ++j) o[j] = f2bf(w0 * bf2f(va[j]) + w1 * bf2f(vb[j]));
    ((u16x8*)out)[i] = o;
}

__global__ __launch_bounds__(128) void final_norm_kernel(
    const unsigned short* __restrict__ aggW, const unsigned short* __restrict__ aggC,
    const unsigned short* __restrict__ aggB, const float* __restrict__ w,
    float* __restrict__ out)
{
    __shared__ float red[128];
    int row = blockIdx.x;
    int c = threadIdx.x;
    float v;
    if (row < NN) {
        size_t i = (size_t)row * DOUT + c;
        v = w[0] * bf2f(aggW[i]) + w[1] * bf2f(aggC[i]);
    } else {
        size_t i = (size_t)(row - NN) * DOUT + c;
        v = bf2f(aggB[i]);
    }
    red[c] = v * v;
    __syncthreads();
    for (int s = 64; s > 0; s >>= 1) {
        if (c < s) red[c] += red[c + s];
        __syncthreads();
    }
    float norm = sqrtf(red[0]);
    out[(size_t)row * DOUT + c] = v / fmaxf(norm, 1e-12f);
}

// ------------------------------------------------------------------
static void build_csr(const int* ei, int* offs, int* esrc, int* deg, int* bsum, int* boff,
                      hipStream_t stream)
{
    const int* src = ei;
    const int* dst = ei + NE;
    const int NB = (NN + 255) / 256;
    hipMemsetAsync(deg, 0, NN * sizeof(int), stream);
    hist_kernel<<<(NE + 255) / 256, 256, 0, stream>>>(dst, deg, NE);
    block_sum_kernel<<<NB, 256, 0, stream>>>(deg, bsum, NN);
    scan_bsum_kernel<<<1, 256, 0, stream>>>(bsum, boff, NB);
    scan_final_kernel<<<NB, 256, 0, stream>>>(deg, boff, offs, NN);
    hipMemsetAsync(deg, 0, NN * sizeof(int), stream);
    place_kernel<<<(NE + 255) / 256, 256, 0, stream>>>(src, dst, offs, deg, esrc, NE);
}

extern "C" void kernel_launch(void* const* d_in, const int* in_sizes, int n_in,
                              void* d_out, int out_size, void* d_ws, size_t ws_size,
                              hipStream_t stream)
{
    const float* x_paper   = (const float*)d_in[0];
    const float* x_author  = (const float*)d_in[1];
    const int*   ei_writes = (const int*)d_in[2];
    const int*   ei_wb     = (const int*)d_in[3];
    const int*   ei_cites  = (const int*)d_in[4];
    const float* W0p = (const float*)d_in[5];  const float* b0p = (const float*)d_in[6];
    const float* W0a = (const float*)d_in[7];  const float* b0a = (const float*)d_in[8];
    const float* a0s_w  = (const float*)d_in[9];  const float* a0d_w  = (const float*)d_in[10];
    const float* a0s_wb = (const float*)d_in[11]; const float* a0d_wb = (const float*)d_in[12];
    const float* a0s_c  = (const float*)d_in[13]; const float* a0d_c  = (const float*)d_in[14];
    const float* Wk0 = (const float*)d_in[15]; const float* bk0 = (const float*)d_in[16];
    const float* q0  = (const float*)d_in[17];
    const float* W1p = (const float*)d_in[18]; const float* b1p = (const float*)d_in[19];
    const float* W1a = (const float*)d_in[20]; const float* b1a = (const float*)d_in[21];
    const float* a1s_w  = (const float*)d_in[22]; const float* a1d_w  = (const float*)d_in[23];
    const float* a1s_wb = (const float*)d_in[24]; const float* a1d_wb = (const float*)d_in[25];
    const float* a1s_c  = (const float*)d_in[26]; const float* a1d_c  = (const float*)d_in[27];
    const float* Wk1 = (const float*)d_in[28]; const float* bk1 = (const float*)d_in[29];
    const float* q1  = (const float*)d_in[30];

    float* out = (float*)d_out;

    const size_t NH = (size_t)NN * DHID;   // 12.8M elems
    const size_t NI = (size_t)NN * DIN;    // 38.4M
    const size_t NO = (size_t)NN * DOUT;   // 6.4M
    const size_t NH2 = NH * 2;             // bytes of one NH-u16 array (25.6MB)
    const size_t NI2 = NI * 2;
    const size_t NO2 = NO * 2;

    char* base = (char*)d_ws;
    // L0 phase
    unsigned short* xbhP = (unsigned short*)(base + 0);        // L0 paper features (bf16)
    unsigned short* xbhA = (unsigned short*)(base + NH2);      // L0 author features
    unsigned short* xbP  = (unsigned short*)(base + 2 * NH2);           // raw bf16 paper (dead after L0 GEMM)
    unsigned short* xbA  = (unsigned short*)(base + 2 * NH2 + NI2);     // raw bf16 author
    // L0 aggregates (bf16, relu'd) over dead xb region
    unsigned short* aggW = (unsigned short*)(base + 2 * NH2);
    unsigned short* aggC = (unsigned short*)(base + 3 * NH2);
    unsigned short* aggB = (unsigned short*)(base + 4 * NH2);  // == h_author (bf16)
    // L1 tensors
    unsigned short* hbP  = (unsigned short*)(base + 0);        // over xbhP (dead)
    unsigned short* hbA  = aggB;
    unsigned short* x1Pb = (unsigned short*)(base + NH2);      // over xbhA (dead)
    unsigned short* x1Ab = (unsigned short*)(base + NH2 + NO2);
    unsigned short* agg1W = (unsigned short*)(base + 2 * NH2 + NI2);          // 128.0MB
    unsigned short* agg1C = (unsigned short*)(base + 2 * NH2 + NI2 + NO2);
    unsigned short* agg1B = (unsigned short*)(base + 2 * NH2 + NI2 + 2 * NO2);
    // scores / alpha / ints / weights
    float* sW_src  = (float*)(base + 204800000);
    float* sW_dst  = sW_src  + NN * H0;
    float* sWB_src = sW_dst  + NN * H0;
    float* sWB_dst = sWB_src + NN * H0;
    float* sC_src  = sWB_dst + NN * H0;
    float* sC_dst  = sC_src  + NN * H0;
    float* al0 = (float*)(base + 214400000);   // NE*H0 f32 each
    float* al1 = al0 + (size_t)NE * H0;
    float* al2 = al1 + (size_t)NE * H0;
    int* ip      = (int*)(base + 243200000);
    int* offsW   = ip;               ip += NN + 4;
    int* offsWB  = ip;               ip += NN + 4;
    int* offsC   = ip;               ip += NN + 4;
    int* esrcW   = ip;               ip += NE;
    int* esrcWB  = ip;               ip += NE;
    int* esrcC   = ip;               ip += NE;
    int* deg     = ip;               ip += NN;
    int* bsum    = ip;               ip += 256;
    int* boff    = ip;               ip += 256;
    unsigned short* wt0p = (unsigned short*)ip;        // DHID*DIN u16
    unsigned short* wt0a = wt0p + (size_t)DHID * DIN;
    unsigned short* wkt  = wt0a + (size_t)DHID * DIN;
    unsigned short* wt1p = wt0p;                       // alias after L0 GEMM
    unsigned short* wt1a = wt1p + (size_t)DOUT * DHID;
    float* tsum = (float*)(wkt + (size_t)DHID * DHID);  // 512
    float* wsem = tsum + 512;

    // ---- CSR build (shared by both layers) ----
    build_csr(ei_writes, offsW,  esrcW,  deg, bsum, boff, stream);
    build_csr(ei_wb,     offsWB, esrcWB, deg, bsum, boff, stream);
    build_csr(ei_cites,  offsC,  esrcC,  deg, bsum, boff, stream);

    // ================= layer 0 =================
    hipMemsetAsync(tsum, 0, 512 * sizeof(float), stream);
    convert_bf16_kernel<<<(int)((NI / 8 + 255) / 256), 256, 0, stream>>>(x_paper,  xbP, (int)(NI / 8));
    convert_bf16_kernel<<<(int)((NI / 8 + 255) / 256), 256, 0, stream>>>(x_author, xbA, (int)(NI / 8));
    transconv_kernel<<<(DIN * DHID + 255) / 256, 256, 0, stream>>>(W0p, wt0p, DIN, DHID);
    transconv_kernel<<<(DIN * DHID + 255) / 256, 256, 0, stream>>>(W0a, wt0a, DIN, DHID);
    transconv_kernel<<<(DHID * DHID + 255) / 256, 256, 0, stream>>>(Wk0, wkt, DHID, DHID);

    dim3 g0(DHID / 128, (NN + 127) / 128, 2);
    gemm_bf16_kernel<<<g0, 256, 0, stream>>>(xbP, xbA, wt0p, wt0a, b0p, b0a, xbhP, xbhA, NN, DIN, DHID);

    // scores (one pass per ntype), alpha, gathers (relu'd bf16 out)
    scores_L0_kernel<<<(2 * NN * H0 + 255) / 256, 256, 0, stream>>>(
        xbhP, xbhA, a0d_w, a0s_wb, a0s_c, a0d_c, a0s_w, a0d_wb,
        sW_dst, sWB_src, sC_src, sC_dst, sW_src, sWB_dst);
    dim3 ga0((NN * H0 + 255) / 256, 3);
    seg_alpha3_kernel<<<ga0, 256, 0, stream>>>(
        offsW, offsWB, offsC, esrcW, esrcWB, esrcC,
        sW_src, sWB_src, sC_src, sW_dst, sWB_dst, sC_dst, al0, al1, al2, H0);
    dim3 gg0(NN / 4, 3);
    gather3_kernel<4, H0, 5><<<gg0, 256, 0, stream>>>(
        offsW, offsWB, offsC, esrcW, esrcWB, esrcC, al0, al1, al2,
        xbhA, xbhP, xbhP, aggW, aggB, aggC, DHID);

    // semantic attention (paper: M=2; author: M=1 -> identity)
    dim3 gs0(DHID / 128, (NN + 127) / 128);
    sem_bf16_kernel<<<gs0, 256, 0, stream>>>(aggW, wkt, bk0, tsum,        NN, DHID, DHID);
    sem_bf16_kernel<<<gs0, 256, 0, stream>>>(aggC, wkt, bk0, tsum + DHID, NN, DHID, DHID);
    sem_weights_kernel<<<1, 64, 0, stream>>>(tsum, q0, wsem, DHID, NN);

    combine2_bf16_kernel<<<(int)((NH / 8 + 255) / 256), 256, 0, stream>>>(aggW, aggC, wsem, hbP, (int)(NH / 8));
    // h_author = aggB directly (already relu'd bf16)

    // ================= layer 1 =================
    transconv_kernel<<<(DHID * DOUT + 255) / 256, 256, 0, stream>>>(W1p, wt1p, DHID, DOUT);
    transconv_kernel<<<(DHID * DOUT + 255) / 256, 256, 0, stream>>>(W1a, wt1a, DHID, DOUT);
    transconv_kernel<<<(DOUT * DOUT + 255) / 256, 256, 0, stream>>>(Wk1, wkt, DOUT, DOUT);

    dim3 g1(DOUT / 128, (NN + 127) / 128, 2);
    gemm_bf16_kernel<<<g1, 256, 0, stream>>>(hbP, hbA, wt1p, wt1a, b1p, b1a, x1Pb, x1Ab, NN, DHID, DOUT);

    hipMemsetAsync(tsum, 0, 2 * DOUT * sizeof(float), stream);

    scores_L1_kernel<<<(2 * NN + 255) / 256, 256, 0, stream>>>(
        x1Pb, x1Ab, a1d_w, a1s_wb, a1s_c, a1d_c, a1s_w, a1d_wb,
        sW_dst, sWB_src, sC_src, sC_dst, sW_src, sWB_dst);
    dim3 ga1((NN + 255) / 256, 3);
    seg_alpha3_kernel<<<ga1, 256, 0, stream>>>(
        offsW, offsWB, offsC, esrcW, esrcWB, esrcC,
        sW_src, sWB_src, sC_src, sW_dst, sWB_dst, sC_dst, al0, al1, al2, 1);
    dim3 gg1(NN / 4, 3);
    gather3_kernel<2, 1, 7><<<gg1, 256, 0, stream>>>(
        offsW, offsWB, offsC, esrcW, esrcWB, esrcC, al0, al1, al2,
        x1Ab, x1Pb, x1Pb, agg1W, agg1B, agg1C, DOUT);

    dim3 gs1(DOUT / 128, (NN + 127) / 128);
    sem_bf16_kernel<<<gs1, 256, 0, stream>>>(agg1W, wkt, bk1, tsum,        NN, DOUT, DOUT);
    sem_bf16_kernel<<<gs1, 256, 0, stream>>>(agg1C, wkt, bk1, tsum + DOUT, NN, DOUT, DOUT);
    sem_weights_kernel<<<1, 64, 0, stream>>>(tsum, q1, wsem, DOUT, NN);

    final_norm_kernel<<<2 * NN, 128, 0, stream>>>(agg1W, agg1C, agg1B, wsem, out);
}

// Round 8
// 779.515 us; speedup vs baseline: 8.6284x; 1.1184x over previous
//
#include <hip/hip_runtime.h>
#include <math.h>

#define NN 50000
#define NE 300000
#define DIN 768
#define DHID 256
#define DOUT 128
#define H0 8
#define D0 32
#define OFFST (NN + 4)

typedef __attribute__((ext_vector_type(8))) short bf16x8;
typedef __attribute__((ext_vector_type(8))) unsigned short u16x8;
typedef __attribute__((ext_vector_type(4))) float f32x4;

__device__ __forceinline__ unsigned short f2bf(float f) {
    unsigned u = __float_as_uint(f);
    unsigned r = (u + 0x7fffu + ((u >> 16) & 1u)) >> 16;
    return (unsigned short)r;
}
__device__ __forceinline__ float bf2f(unsigned short u) {
    return __uint_as_float(((unsigned)u) << 16);
}

__device__ __forceinline__ void gload16(const void* g, void* l) {
    __builtin_amdgcn_global_load_lds(
        (const __attribute__((address_space(1))) unsigned int*)g,
        (__attribute__((address_space(3))) unsigned int*)l, 16, 0, 0);
}

// ---------------- f32 -> bf16 stream convert, both tensors in one dispatch ----------------
__global__ void convert2_bf16_kernel(const float* __restrict__ in0, const float* __restrict__ in1,
                                     unsigned short* __restrict__ o0, unsigned short* __restrict__ o1,
                                     int n8)
{
    int gid = blockIdx.x * 256 + threadIdx.x;
    if (gid >= 2 * n8) return;
    const float* in = (gid < n8) ? in0 : in1;
    unsigned short* out = (gid < n8) ? o0 : o1;
    int i = (gid < n8) ? gid : gid - n8;
    float4 a = ((const float4*)in)[i * 2];
    float4 b = ((const float4*)in)[i * 2 + 1];
    u16x8 o;
    o[0] = f2bf(a.x); o[1] = f2bf(a.y); o[2] = f2bf(a.z); o[3] = f2bf(a.w);
    o[4] = f2bf(b.x); o[5] = f2bf(b.y); o[6] = f2bf(b.z); o[7] = f2bf(b.w);
    ((u16x8*)out)[i] = o;
}

// three transposed-converts in one dispatch (y=0,1: Kab x Nab; y=2: Kc x Ncc)
__global__ void transconv3_kernel(const float* __restrict__ Wa, const float* __restrict__ Wb,
                                  const float* __restrict__ Wc,
                                  unsigned short* __restrict__ Ta, unsigned short* __restrict__ Tb,
                                  unsigned short* __restrict__ Tc,
                                  int Kab, int Nab, int Kc, int Ncc)
{
    int y = blockIdx.y;
    const float* W = (y == 0) ? Wa : ((y == 1) ? Wb : Wc);
    unsigned short* T = (y == 0) ? Ta : ((y == 1) ? Tb : Tc);
    int K = (y == 2) ? Kc : Kab;
    int Nc = (y == 2) ? Ncc : Nab;
    int gid = blockIdx.x * 256 + threadIdx.x;
    if (gid >= K * Nc) return;
    int k = gid / Nc, n = gid - k * Nc;
    T[(size_t)n * K + k] = f2bf(W[gid]);
}

// ---------------- MFMA GEMM, double-buffered, gload_lds, chunk-XOR swizzle ----------------
__global__ __launch_bounds__(256) void gemm_bf16_kernel(
    const unsigned short* __restrict__ A0, const unsigned short* __restrict__ A1,
    const unsigned short* __restrict__ Bt0, const unsigned short* __restrict__ Bt1,
    const float* __restrict__ bias0, const float* __restrict__ bias1,
    unsigned short* __restrict__ C0, unsigned short* __restrict__ C1,
    int M, int K, int Nc)
{
    __shared__ __align__(16) unsigned short As[2][128 * 32];
    __shared__ __align__(16) unsigned short Bs[2][128 * 32];
    const int z = blockIdx.z;
    const unsigned short* A  = z ? A1  : A0;
    const unsigned short* Bt = z ? Bt1 : Bt0;
    const float* bias = z ? bias1 : bias0;
    unsigned short* C = z ? C1 : C0;
    const int t = threadIdx.x;
    const int lane = t & 63, w = t >> 6;
    const int wr = w >> 1, wc = w & 1;
    const int bm = blockIdx.y * 128, bn = blockIdx.x * 128;

    f32x4 acc[4][4];
    #pragma unroll
    for (int m = 0; m < 4; ++m)
        #pragma unroll
        for (int n = 0; n < 4; ++n)
            acc[m][n] = (f32x4){0.f, 0.f, 0.f, 0.f};

    const int c0 = w * 64 + lane, c1 = c0 + 256;
    const int row0 = c0 >> 2, row1 = c1 >> 2;
    const int g0 = (c0 & 3) ^ ((row0 >> 1) & 3);
    const int g1 = (c1 & 3) ^ ((row1 >> 1) & 3);
    const int ar0 = (bm + row0 < M) ? (bm + row0) : (M - 1);
    const int ar1 = (bm + row1 < M) ? (bm + row1) : (M - 1);
    const unsigned short* pA0 = A + (size_t)ar0 * K + g0 * 8;
    const unsigned short* pA1 = A + (size_t)ar1 * K + g1 * 8;
    const unsigned short* pB0 = Bt + (size_t)(bn + row0) * K + g0 * 8;
    const unsigned short* pB1 = Bt + (size_t)(bn + row1) * K + g1 * 8;

    const int rA = wr * 64 + (lane & 15);
    const int rB = wc * 64 + (lane & 15);
    const int gw = lane >> 4;
    const int nt = K >> 5;

    gload16(pA0, &As[0][c0 * 8]);
    gload16(pA1, &As[0][c1 * 8]);
    gload16(pB0, &Bs[0][c0 * 8]);
    gload16(pB1, &Bs[0][c1 * 8]);
    __syncthreads();
    for (int ti = 0; ti < nt; ++ti) {
        const int cur = ti & 1;
        if (ti + 1 < nt) {
            const int nk = (ti + 1) << 5;
            const int nb = cur ^ 1;
            gload16(pA0 + nk, &As[nb][c0 * 8]);
            gload16(pA1 + nk, &As[nb][c1 * 8]);
            gload16(pB0 + nk, &Bs[nb][c0 * 8]);
            gload16(pB1 + nk, &Bs[nb][c1 * 8]);
        }
        bf16x8 afr[4], bfr[4];
        #pragma unroll
        for (int m = 0; m < 4; ++m) {
            int r = rA + m * 16;
            afr[m] = *(const bf16x8*)&As[cur][r * 32 + ((gw ^ ((r >> 1) & 3)) * 8)];
        }
        #pragma unroll
        for (int n = 0; n < 4; ++n) {
            int r = rB + n * 16;
            bfr[n] = *(const bf16x8*)&Bs[cur][r * 32 + ((gw ^ ((r >> 1) & 3)) * 8)];
        }
        #pragma unroll
        for (int m = 0; m < 4; ++m)
            #pragma unroll
            for (int n = 0; n < 4; ++n)
                acc[m][n] = __builtin_amdgcn_mfma_f32_16x16x32_bf16(afr[m], bfr[n], acc[m][n], 0, 0, 0);
        __syncthreads();
    }
    #pragma unroll
    for (int m = 0; m < 4; ++m) {
        #pragma unroll
        for (int j = 0; j < 4; ++j) {
            int row = bm + wr * 64 + m * 16 + (lane >> 4) * 4 + j;
            if (row >= M) continue;
            #pragma unroll
            for (int n = 0; n < 4; ++n) {
                int col = bn + wc * 64 + n * 16 + (lane & 15);
                C[(size_t)row * Nc + col] = f2bf(acc[m][n][j] + bias[col]);
            }
        }
    }
}

// ---------------- sem GEMM: partial[c] += sum_rows tanh( A @ Wkt^T + bk )[c] ----------------
__global__ __launch_bounds__(256) void sem_bf16_kernel(
    const unsigned short* __restrict__ A, const unsigned short* __restrict__ Bt,
    const float* __restrict__ bk, float* __restrict__ partial,
    int M, int K, int Nc)
{
    __shared__ __align__(16) unsigned short As[2][128 * 32];
    __shared__ __align__(16) unsigned short Bs[2][128 * 32];
    __shared__ float red[128];
    const int t = threadIdx.x;
    const int lane = t & 63, w = t >> 6;
    const int wr = w >> 1, wc = w & 1;
    const int bm = blockIdx.y * 128, bn = blockIdx.x * 128;

    f32x4 acc[4][4];
    #pragma unroll
    for (int m = 0; m < 4; ++m)
        #pragma unroll
        for (int n = 0; n < 4; ++n)
            acc[m][n] = (f32x4){0.f, 0.f, 0.f, 0.f};

    const int c0 = w * 64 + lane, c1 = c0 + 256;
    const int row0 = c0 >> 2, row1 = c1 >> 2;
    const int g0 = (c0 & 3) ^ ((row0 >> 1) & 3);
    const int g1 = (c1 & 3) ^ ((row1 >> 1) & 3);
    const int ar0 = (bm + row0 < M) ? (bm + row0) : (M - 1);
    const int ar1 = (bm + row1 < M) ? (bm + row1) : (M - 1);
    const unsigned short* pA0 = A + (size_t)ar0 * K + g0 * 8;
    const unsigned short* pA1 = A + (size_t)ar1 * K + g1 * 8;
    const unsigned short* pB0 = Bt + (size_t)(bn + row0) * K + g0 * 8;
    const unsigned short* pB1 = Bt + (size_t)(bn + row1) * K + g1 * 8;

    const int rA = wr * 64 + (lane & 15);
    const int rB = wc * 64 + (lane & 15);
    const int gw = lane >> 4;
    const int nt = K >> 5;

    gload16(pA0, &As[0][c0 * 8]);
    gload16(pA1, &As[0][c1 * 8]);
    gload16(pB0, &Bs[0][c0 * 8]);
    gload16(pB1, &Bs[0][c1 * 8]);
    __syncthreads();
    for (int ti = 0; ti < nt; ++ti) {
        const int cur = ti & 1;
        if (ti + 1 < nt) {
            const int nk = (ti + 1) << 5;
            const int nb = cur ^ 1;
            gload16(pA0 + nk, &As[nb][c0 * 8]);
            gload16(pA1 + nk, &As[nb][c1 * 8]);
            gload16(pB0 + nk, &Bs[nb][c0 * 8]);
            gload16(pB1 + nk, &Bs[nb][c1 * 8]);
        }
        bf16x8 afr[4], bfr[4];
        #pragma unroll
        for (int m = 0; m < 4; ++m) {
            int r = rA + m * 16;
            afr[m] = *(const bf16x8*)&As[cur][r * 32 + ((gw ^ ((r >> 1) & 3)) * 8)];
        }
        #pragma unroll
        for (int n = 0; n < 4; ++n) {
            int r = rB + n * 16;
            bfr[n] = *(const bf16x8*)&Bs[cur][r * 32 + ((gw ^ ((r >> 1) & 3)) * 8)];
        }
        #pragma unroll
        for (int m = 0; m < 4; ++m)
            #pragma unroll
            for (int n = 0; n < 4; ++n)
                acc[m][n] = __builtin_amdgcn_mfma_f32_16x16x32_bf16(afr[m], bfr[n], acc[m][n], 0, 0, 0);
        __syncthreads();
    }
    if (t < 128) red[t] = 0.f;
    __syncthreads();
    #pragma unroll
    for (int n = 0; n < 4; ++n) {
        int lcol = wc * 64 + n * 16 + (lane & 15);
        float b = bk[bn + lcol];
        float s = 0.f;
        #pragma unroll
        for (int m = 0; m < 4; ++m) {
            #pragma unroll
            for (int j = 0; j < 4; ++j) {
                int row = bm + wr * 64 + m * 16 + (lane >> 4) * 4 + j;
                if (row < M) s += tanhf(acc[m][n][j] + b);
            }
        }
        atomicAdd(&red[lcol], s);
    }
    __syncthreads();
    if (t < 128) atomicAdd(&partial[bn + t], red[t]);
}

// ---------------- batched CSR build (all 3 relations per dispatch) ----------------
__global__ void hist3_kernel(const int* __restrict__ d0, const int* __restrict__ d1,
                             const int* __restrict__ d2, int* __restrict__ deg3)
{
    int gid = blockIdx.x * 256 + threadIdx.x;
    if (gid >= 3 * NE) return;
    int rel = gid / NE, e = gid - rel * NE;
    const int* dst = (rel == 0) ? d0 : ((rel == 1) ? d1 : d2);
    atomicAdd(&deg3[rel * NN + dst[e]], 1);
}

__global__ void block_sum3_kernel(const int* __restrict__ deg3, int* __restrict__ bsum3)
{
    __shared__ int buf[256];
    int rel = blockIdx.y;
    int i = blockIdx.x * 256 + threadIdx.x;
    buf[threadIdx.x] = (i < NN) ? deg3[rel * NN + i] : 0;
    __syncthreads();
    for (int s = 128; s > 0; s >>= 1) {
        if (threadIdx.x < s) buf[threadIdx.x] += buf[threadIdx.x + s];
        __syncthreads();
    }
    if (threadIdx.x == 0) bsum3[rel * 256 + blockIdx.x] = buf[0];
}

__global__ void scan_bsum3_kernel(const int* __restrict__ bsum3, int* __restrict__ boff3, int nb)
{
    __shared__ int buf[256];
    int rel = blockIdx.y;
    int tid = threadIdx.x;
    int v = (tid < nb) ? bsum3[rel * 256 + tid] : 0;
    buf[tid] = v;
    __syncthreads();
    for (int off = 1; off < 256; off <<= 1) {
        int t = (tid >= off) ? buf[tid - off] : 0;
        __syncthreads();
        buf[tid] += t;
        __syncthreads();
    }
    if (tid < nb) boff3[rel * 256 + tid] = buf[tid] - v;
}

__global__ void scan_final3_kernel(const int* __restrict__ deg3, const int* __restrict__ boff3,
                                   int* __restrict__ offs3)
{
    __shared__ int buf[256];
    int rel = blockIdx.y;
    int tid = threadIdx.x, b = blockIdx.x;
    int i = b * 256 + tid;
    int v = (i < NN) ? deg3[rel * NN + i] : 0;
    buf[tid] = v;
    __syncthreads();
    for (int off = 1; off < 256; off <<= 1) {
        int t = (tid >= off) ? buf[tid - off] : 0;
        __syncthreads();
        buf[tid] += t;
        __syncthreads();
    }
    int* offs = offs3 + rel * OFFST;
    if (i < NN) offs[i] = boff3[rel * 256 + b] + buf[tid] - v;
    if (i == NN - 1) offs[NN] = boff3[rel * 256 + b] + buf[tid];
}

__global__ void place3_kernel(const int* __restrict__ s0, const int* __restrict__ s1,
                              const int* __restrict__ s2,
                              const int* __restrict__ offs3, int* __restrict__ cnt3,
                              int* __restrict__ esrc3)
{
    int rel = blockIdx.y;
    int e = blockIdx.x * 256 + threadIdx.x;
    if (e >= NE) return;
    const int* srcdst = (rel == 0) ? s0 : ((rel == 1) ? s1 : s2);
    int src = srcdst[e];
    int d = srcdst[NE + e];
    int p = offs3[rel * OFFST + d] + atomicAdd(&cnt3[rel * NN + d], 1);
    esrc3[rel * NE + p] = src;
}

// ---------------- fused per-layer node scores ----------------
__global__ void scores_L0_kernel(
    const unsigned short* __restrict__ xp, const unsigned short* __restrict__ xa,
    const float* __restrict__ a_dw, const float* __restrict__ a_swb,
    const float* __restrict__ a_sc, const float* __restrict__ a_dc,
    const float* __restrict__ a_sw, const float* __restrict__ a_dwb,
    float* __restrict__ sW_dst, float* __restrict__ sWB_src,
    float* __restrict__ sC_src, float* __restrict__ sC_dst,
    float* __restrict__ sW_src, float* __restrict__ sWB_dst)
{
    int gid = blockIdx.x * 256 + threadIdx.x;
    int half = NN * H0;
    if (gid >= 2 * half) return;
    if (gid < half) {
        int node = gid >> 3, h = gid & 7;
        const unsigned short* xr = xp + (size_t)node * DHID + h * D0;
        float xv[D0];
        #pragma unroll
        for (int j = 0; j < 4; ++j) {
            u16x8 v = ((const u16x8*)xr)[j];
            #pragma unroll
            for (int k = 0; k < 8; ++k) xv[j * 8 + k] = bf2f(v[k]);
        }
        const float* p0 = a_dw  + h * D0;
        const float* p1 = a_swb + h * D0;
        const float* p2 = a_sc  + h * D0;
        const float* p3 = a_dc  + h * D0;
        float d0 = 0.f, d1 = 0.f, d2 = 0.f, d3 = 0.f;
        #pragma unroll
        for (int k = 0; k < D0; ++k) {
            float x = xv[k];
            d0 += x * p0[k]; d1 += x * p1[k]; d2 += x * p2[k]; d3 += x * p3[k];
        }
        sW_dst[gid] = d0; sWB_src[gid] = d1; sC_src[gid] = d2; sC_dst[gid] = d3;
    } else {
        int g = gid - half;
        int node = g >> 3, h = g & 7;
        const unsigned short* xr = xa + (size_t)node * DHID + h * D0;
        float xv[D0];
        #pragma unroll
        for (int j = 0; j < 4; ++j) {
            u16x8 v = ((const u16x8*)xr)[j];
            #pragma unroll
            for (int k = 0; k < 8; ++k) xv[j * 8 + k] = bf2f(v[k]);
        }
        const float* p0 = a_sw  + h * D0;
        const float* p1 = a_dwb + h * D0;
        float d0 = 0.f, d1 = 0.f;
        #pragma unroll
        for (int k = 0; k < D0; ++k) {
            float x = xv[k];
            d0 += x * p0[k]; d1 += x * p1[k];
        }
        sW_src[g] = d0; sWB_dst[g] = d1;
    }
}

__global__ void scores_L1_kernel(
    const unsigned short* __restrict__ xp, const unsigned short* __restrict__ xa,
    const float* __restrict__ a_dw, const float* __restrict__ a_swb,
    const float* __restrict__ a_sc, const float* __restrict__ a_dc,
    const float* __restrict__ a_sw, const float* __restrict__ a_dwb,
    float* __restrict__ sW_dst, float* __restrict__ sWB_src,
    float* __restrict__ sC_src, float* __restrict__ sC_dst,
    float* __restrict__ sW_src, float* __restrict__ sWB_dst)
{
    int gid = blockIdx.x * 256 + threadIdx.x;
    if (gid >= 2 * NN) return;
    if (gid < NN) {
        const unsigned short* xr = xp + (size_t)gid * DOUT;
        float d0 = 0.f, d1 = 0.f, d2 = 0.f, d3 = 0.f;
        for (int j = 0; j < DOUT / 8; ++j) {
            u16x8 v = ((const u16x8*)xr)[j];
            #pragma unroll
            for (int k = 0; k < 8; ++k) {
                float x = bf2f(v[k]);
                int c = j * 8 + k;
                d0 += x * a_dw[c]; d1 += x * a_swb[c]; d2 += x * a_sc[c]; d3 += x * a_dc[c];
            }
        }
        sW_dst[gid] = d0; sWB_src[gid] = d1; sC_src[gid] = d2; sC_dst[gid] = d3;
    } else {
        int g = gid - NN;
        const unsigned short* xr = xa + (size_t)g * DOUT;
        float d0 = 0.f, d1 = 0.f;
        for (int j = 0; j < DOUT / 8; ++j) {
            u16x8 v = ((const u16x8*)xr)[j];
            #pragma unroll
            for (int k = 0; k < 8; ++k) {
                float x = bf2f(v[k]);
                int c = j * 8 + k;
                d0 += x * a_sw[c]; d1 += x * a_dwb[c];
            }
        }
        sW_src[g] = d0; sWB_dst[g] = d1;
    }
}

// ---------------- batched per-(dst,head) segment softmax -> alpha ----------------
__global__ void seg_alpha3_kernel(
    const int* __restrict__ offs3, const int* __restrict__ esrc3,
    const float* __restrict__ ss0, const float* __restrict__ ss1, const float* __restrict__ ss2,
    const float* __restrict__ sd0, const float* __restrict__ sd1, const float* __restrict__ sd2,
    float* __restrict__ alpha3, int H)
{
    int rel = blockIdx.y;
    const int* offs = offs3 + rel * OFFST;
    const int* esrc = esrc3 + rel * NE;
    const float* ssrc = (rel == 0) ? ss0 : ((rel == 1) ? ss1 : ss2);
    const float* sdst = (rel == 0) ? sd0 : ((rel == 1) ? sd1 : sd2);
    float* alpha = alpha3 + (size_t)rel * NE * H0;
    int gid = blockIdx.x * 256 + threadIdx.x;
    if (gid >= NN * H) return;
    int d = gid / H, h = gid - d * H;
    int beg = offs[d], end = offs[d + 1];
    float sd = sdst[gid];
    float m = -INFINITY, den = 0.f;
    for (int i = beg; i < end; ++i) {
        int s = esrc[i];
        float v = ssrc[s * H + h] + sd;
        v = (v >= 0.f) ? v : 0.2f * v;
        if (v > m) { den = den * expf(m - v) + 1.f; m = v; }
        else       den += expf(v - m);
    }
    float inv = 1.f / (den + 1e-16f);
    for (int i = beg; i < end; ++i) {
        int s = esrc[i];
        float v = ssrc[s * H + h] + sd;
        v = (v >= 0.f) ? v : 0.2f * v;
        alpha[(size_t)i * H + h] = expf(v - m) * inv;
    }
}

// ---------------- batched weighted gather, 2-deep software pipeline ----------------
// one wave per (dst node, rel); out = bf16(relu(sum))
template<int CPL, int HH, int DSH>
__global__ __launch_bounds__(256) void gather3_kernel(
    const int* __restrict__ offs3, const int* __restrict__ esrc3,
    const float* __restrict__ alpha3,
    const unsigned short* __restrict__ x0, const unsigned short* __restrict__ x1,
    const unsigned short* __restrict__ x2,
    unsigned short* __restrict__ o0, unsigned short* __restrict__ o1,
    unsigned short* __restrict__ o2, int C)
{
    int rel = blockIdx.y;
    const int* offs = offs3 + rel * OFFST;
    const int* esrc = esrc3 + rel * NE;
    const float* alpha = alpha3 + (size_t)rel * NE * H0;
    const unsigned short* x = (rel == 0) ? x0 : ((rel == 1) ? x1 : x2);
    unsigned short* outp = (rel == 0) ? o0 : ((rel == 1) ? o1 : o2);

    int wid = threadIdx.x >> 6, lane = threadIdx.x & 63;
    int d = blockIdx.x * 4 + wid;
    int c0 = lane * CPL;
    int h = c0 >> DSH;
    int beg = offs[d], end = offs[d + 1];
    float acc0 = 0.f, acc1 = 0.f, acc2 = 0.f, acc3 = 0.f;
    int n = end - beg;
    if (n > 0) {
        int sA = esrc[beg];
        float aA = alpha[(size_t)beg * HH + h];
        int sB = sA; float aB = 0.f;
        if (n > 1) { sB = esrc[beg + 1]; aB = alpha[(size_t)(beg + 1) * HH + h]; }
        if (CPL == 4) {
            ushort4 xc = *(const ushort4*)(x + (size_t)sA * C + c0);
            for (int i = beg; i < end; ++i) {
                ushort4 xn = xc;
                if (i + 1 < end) xn = *(const ushort4*)(x + (size_t)sB * C + c0);
                int sN = sB; float aN = 0.f;
                if (i + 2 < end) { sN = esrc[i + 2]; aN = alpha[(size_t)(i + 2) * HH + h]; }
                acc0 += aA * bf2f(xc.x); acc1 += aA * bf2f(xc.y);
                acc2 += aA * bf2f(xc.z); acc3 += aA * bf2f(xc.w);
                xc = xn; aA = aB; sB = sN; aB = aN;
            }
        } else {
            ushort2 xc = *(const ushort2*)(x + (size_t)sA * C + c0);
            for (int i = beg; i < end; ++i) {
                ushort2 xn = xc;
                if (i + 1 < end) xn = *(const ushort2*)(x + (size_t)sB * C + c0);
                int sN = sB; float aN = 0.f;
                if (i + 2 < end) { sN = esrc[i + 2]; aN = alpha[(size_t)(i + 2) * HH + h]; }
                acc0 += aA * bf2f(xc.x); acc1 += aA * bf2f(xc.y);
                xc = xn; aA = aB; sB = sN; aB = aN;
            }
        }
    }
    unsigned short* op = outp + (size_t)d * C + c0;
    if (CPL == 4) {
        ushort4 st;
        st.x = f2bf(fmaxf(acc0, 0.f)); st.y = f2bf(fmaxf(acc1, 0.f));
        st.z = f2bf(fmaxf(acc2, 0.f)); st.w = f2bf(fmaxf(acc3, 0.f));
        *(ushort4*)op = st;
    } else {
        ushort2 st;
        st.x = f2bf(fmaxf(acc0, 0.f)); st.y = f2bf(fmaxf(acc1, 0.f));
        *(ushort2*)op = st;
    }
}

__global__ void sem_weights_kernel(const float* __restrict__ partial, const float* __restrict__ q,
                                   float* __restrict__ w, int C, int n)
{
    if (threadIdx.x != 0 || blockIdx.x != 0) return;
    float inv = 1.f / (float)n;
    float s0 = 0.f, s1 = 0.f;
    for (int c = 0; c < C; ++c) {
        s0 += q[c] * partial[c] * inv;
        s1 += q[c] * partial[C + c] * inv;
    }
    float m = fmaxf(s0, s1);
    float e0 = expf(s0 - m), e1 = expf(s1 - m);
    float den = e0 + e1;
    w[0] = e0 / den;
    w[1] = e1 / den;
}

__global__ void combine2_bf16_kernel(const unsigned short* __restrict__ a,
                                     const unsigned short* __restrict__ b,
                                     const float* __restrict__ w, unsigned short* __restrict__ out,
                                     int n8)
{
    int i = blockIdx.x * 256 + threadIdx.x;
    if (i >= n8) return;
    float w0 = w[0], w1 = w[1];
    u16x8 va = ((const u16x8*)a)[i];
    u16x8 vb = ((const u16x8*)b)[i];
    u16x8 o;
    #pragma unroll
    for (int j = 0; j < 8; ++j) o[j] = f2bf(w0 * bf2f(va[j]) + w1 * bf2f(vb[j]));
    ((u16x8*)out)[i] = o;
}

__global__ __launch_bounds__(128) void final_norm_kernel(
    const unsigned short* __restrict__ aggW, const unsigned short* __restrict__ aggC,
    const unsigned short* __restrict__ aggB, const float* __restrict__ w,
    float* __restrict__ out)
{
    __shared__ float red[128];
    int row = blockIdx.x;
    int c = threadIdx.x;
    float v;
    if (row < NN) {
        size_t i = (size_t)row * DOUT + c;
        v = w[0] * bf2f(aggW[i]) + w[1] * bf2f(aggC[i]);
    } else {
        size_t i = (size_t)(row - NN) * DOUT + c;
        v = bf2f(aggB[i]);
    }
    red[c] = v * v;
    __syncthreads();
    for (int s = 64; s > 0; s >>= 1) {
        if (c < s) red[c] += red[c + s];
        __syncthreads();
    }
    float norm = sqrtf(red[0]);
    out[(size_t)row * DOUT + c] = v / fmaxf(norm, 1e-12f);
}

// ------------------------------------------------------------------
extern "C" void kernel_launch(void* const* d_in, const int* in_sizes, int n_in,
                              void* d_out, int out_size, void* d_ws, size_t ws_size,
                              hipStream_t stream)
{
    const float* x_paper   = (const float*)d_in[0];
    const float* x_author  = (const float*)d_in[1];
    const int*   ei_writes = (const int*)d_in[2];
    const int*   ei_wb     = (const int*)d_in[3];
    const int*   ei_cites  = (const int*)d_in[4];
    const float* W0p = (const float*)d_in[5];  const float* b0p = (const float*)d_in[6];
    const float* W0a = (const float*)d_in[7];  const float* b0a = (const float*)d_in[8];
    const float* a0s_w  = (const float*)d_in[9];  const float* a0d_w  = (const float*)d_in[10];
    const float* a0s_wb = (const float*)d_in[11]; const float* a0d_wb = (const float*)d_in[12];
    const float* a0s_c  = (const float*)d_in[13]; const float* a0d_c  = (const float*)d_in[14];
    const float* Wk0 = (const float*)d_in[15]; const float* bk0 = (const float*)d_in[16];
    const float* q0  = (const float*)d_in[17];
    const float* W1p = (const float*)d_in[18]; const float* b1p = (const float*)d_in[19];
    const float* W1a = (const float*)d_in[20]; const float* b1a = (const float*)d_in[21];
    const float* a1s_w  = (const float*)d_in[22]; const float* a1d_w  = (const float*)d_in[23];
    const float* a1s_wb = (const float*)d_in[24]; const float* a1d_wb = (const float*)d_in[25];
    const float* a1s_c  = (const float*)d_in[26]; const float* a1d_c  = (const float*)d_in[27];
    const float* Wk1 = (const float*)d_in[28]; const float* bk1 = (const float*)d_in[29];
    const float* q1  = (const float*)d_in[30];

    float* out = (float*)d_out;

    const size_t NH = (size_t)NN * DHID;
    const size_t NI = (size_t)NN * DIN;
    const size_t NO = (size_t)NN * DOUT;
    const size_t NH2 = NH * 2;
    const size_t NI2 = NI * 2;
    const size_t NO2 = NO * 2;

    char* base = (char*)d_ws;
    unsigned short* xbhP = (unsigned short*)(base + 0);
    unsigned short* xbhA = (unsigned short*)(base + NH2);
    unsigned short* xbP  = (unsigned short*)(base + 2 * NH2);
    unsigned short* xbA  = (unsigned short*)(base + 2 * NH2 + NI2);
    unsigned short* aggW = (unsigned short*)(base + 2 * NH2);
    unsigned short* aggC = (unsigned short*)(base + 3 * NH2);
    unsigned short* aggB = (unsigned short*)(base + 4 * NH2);
    unsigned short* hbP  = (unsigned short*)(base + 0);
    unsigned short* hbA  = aggB;
    unsigned short* x1Pb = (unsigned short*)(base + NH2);
    unsigned short* x1Ab = (unsigned short*)(base + NH2 + NO2);
    unsigned short* agg1W = (unsigned short*)(base + 2 * NH2 + NI2);
    unsigned short* agg1C = (unsigned short*)(base + 2 * NH2 + NI2 + NO2);
    unsigned short* agg1B = (unsigned short*)(base + 2 * NH2 + NI2 + 2 * NO2);

    float* sW_src  = (float*)(base + 204800000);
    float* sW_dst  = sW_src  + NN * H0;
    float* sWB_src = sW_dst  + NN * H0;
    float* sWB_dst = sWB_src + NN * H0;
    float* sC_src  = sWB_dst + NN * H0;
    float* sC_dst  = sC_src  + NN * H0;
    float* alpha3  = (float*)(base + 214400000);     // 3 * NE * H0 f32 = 28.8MB
    int* ip     = (int*)(base + 243200000);
    int* offs3  = ip;  ip += 3 * OFFST;
    int* esrc3  = ip;  ip += 3 * NE;
    int* deg3   = ip;  ip += 3 * NN;
    int* bsum3  = ip;  ip += 3 * 256;
    int* boff3  = ip;  ip += 3 * 256;
    unsigned short* wt0p = (unsigned short*)ip;
    unsigned short* wt0a = wt0p + (size_t)DHID * DIN;
    unsigned short* wkt  = wt0a + (size_t)DHID * DIN;
    unsigned short* wt1p = wt0p;
    unsigned short* wt1a = wt1p + (size_t)DOUT * DHID;
    float* tsum = (float*)(wkt + (size_t)DHID * DHID);
    float* wsem = tsum + 512;

    const int NB = (NN + 255) / 256;

    // ---- CSR build (all 3 relations, batched) ----
    hipMemsetAsync(deg3, 0, 3 * NN * sizeof(int), stream);
    hist3_kernel<<<(3 * NE + 255) / 256, 256, 0, stream>>>(ei_writes + NE, ei_wb + NE, ei_cites + NE, deg3);
    block_sum3_kernel<<<dim3(NB, 3), 256, 0, stream>>>(deg3, bsum3);
    scan_bsum3_kernel<<<dim3(1, 3), 256, 0, stream>>>(bsum3, boff3, NB);
    scan_final3_kernel<<<dim3(NB, 3), 256, 0, stream>>>(deg3, boff3, offs3);
    hipMemsetAsync(deg3, 0, 3 * NN * sizeof(int), stream);
    place3_kernel<<<dim3((NE + 255) / 256, 3), 256, 0, stream>>>(ei_writes, ei_wb, ei_cites, offs3, deg3, esrc3);

    // ================= layer 0 =================
    hipMemsetAsync(tsum, 0, 512 * sizeof(float), stream);
    convert2_bf16_kernel<<<(int)((2 * NI / 8 + 255) / 256), 256, 0, stream>>>(x_paper, x_author, xbP, xbA, (int)(NI / 8));
    transconv3_kernel<<<dim3((DIN * DHID + 255) / 256, 3), 256, 0, stream>>>(
        W0p, W0a, Wk0, wt0p, wt0a, wkt, DIN, DHID, DHID, DHID);

    dim3 g0(DHID / 128, (NN + 127) / 128, 2);
    gemm_bf16_kernel<<<g0, 256, 0, stream>>>(xbP, xbA, wt0p, wt0a, b0p, b0a, xbhP, xbhA, NN, DIN, DHID);

    scores_L0_kernel<<<(2 * NN * H0 + 255) / 256, 256, 0, stream>>>(
        xbhP, xbhA, a0d_w, a0s_wb, a0s_c, a0d_c, a0s_w, a0d_wb,
        sW_dst, sWB_src, sC_src, sC_dst, sW_src, sWB_dst);
    dim3 ga0((NN * H0 + 255) / 256, 3);
    seg_alpha3_kernel<<<ga0, 256, 0, stream>>>(
        offs3, esrc3, sW_src, sWB_src, sC_src, sW_dst, sWB_dst, sC_dst, alpha3, H0);
    dim3 gg0(NN / 4, 3);
    gather3_kernel<4, H0, 5><<<gg0, 256, 0, stream>>>(
        offs3, esrc3, alpha3, xbhA, xbhP, xbhP, aggW, aggB, aggC, DHID);

    dim3 gs0(DHID / 128, (NN + 127) / 128);
    sem_bf16_kernel<<<gs0, 256, 0, stream>>>(aggW, wkt, bk0, tsum,        NN, DHID, DHID);
    sem_bf16_kernel<<<gs0, 256, 0, stream>>>(aggC, wkt, bk0, tsum + DHID, NN, DHID, DHID);
    sem_weights_kernel<<<1, 64, 0, stream>>>(tsum, q0, wsem, DHID, NN);

    combine2_bf16_kernel<<<(int)((NH / 8 + 255) / 256), 256, 0, stream>>>(aggW, aggC, wsem, hbP, (int)(NH / 8));

    // ================= layer 1 =================
    transconv3_kernel<<<dim3((DHID * DOUT + 255) / 256, 3), 256, 0, stream>>>(
        W1p, W1a, Wk1, wt1p, wt1a, wkt, DHID, DOUT, DOUT, DOUT);

    dim3 g1(DOUT / 128, (NN + 127) / 128, 2);
    gemm_bf16_kernel<<<g1, 256, 0, stream>>>(hbP, hbA, wt1p, wt1a, b1p, b1a, x1Pb, x1Ab, NN, DHID, DOUT);

    hipMemsetAsync(tsum, 0, 2 * DOUT * sizeof(float), stream);

    scores_L1_kernel<<<(2 * NN + 255) / 256, 256, 0, stream>>>(
        x1Pb, x1Ab, a1d_w, a1s_wb, a1s_c, a1d_c, a1s_w, a1d_wb,
        sW_dst, sWB_src, sC_src, sC_dst, sW_src, sWB_dst);
    dim3 ga1((NN + 255) / 256, 3);
    seg_alpha3_kernel<<<ga1, 256, 0, stream>>>(
        offs3, esrc3, sW_src, sWB_src, sC_src, sW_dst, sWB_dst, sC_dst, alpha3, 1);
    dim3 gg1(NN / 4, 3);
    gather3_kernel<2, 1, 7><<<gg1, 256, 0, stream>>>(
        offs3, esrc3, alpha3, x1Ab, x1Pb, x1Pb, agg1W, agg1B, agg1C, DOUT);

    dim3 gs1(DOUT / 128, (NN + 127) / 128);
    sem_bf16_kernel<<<gs1, 256, 0, stream>>>(agg1W, wkt, bk1, tsum,        NN, DOUT, DOUT);
    sem_bf16_kernel<<<gs1, 256, 0, stream>>>(agg1C, wkt, bk1, tsum + DOUT, NN, DOUT, DOUT);
    sem_weights_kernel<<<1, 64, 0, stream>>>(tsum, q1, wsem, DOUT, NN);

    final_norm_kernel<<<2 * NN, 128, 0, stream>>>(agg1W, agg1C, agg1B, wsem, out);
}

// Round 9
// 753.478 us; speedup vs baseline: 8.9265x; 1.0346x over previous
//
#include <hip/hip_runtime.h>
#include <math.h>

#define NN 50000
#define NE 300000
#define DIN 768
#define DHID 256
#define DOUT 128
#define H0 8
#define D0 32
#define OFFST (NN + 4)

typedef __attribute__((ext_vector_type(8))) short bf16x8;
typedef __attribute__((ext_vector_type(8))) unsigned short u16x8;
typedef __attribute__((ext_vector_type(4))) float f32x4;

__device__ __forceinline__ unsigned short f2bf(float f) {
    unsigned u = __float_as_uint(f);
    unsigned r = (u + 0x7fffu + ((u >> 16) & 1u)) >> 16;
    return (unsigned short)r;
}
__device__ __forceinline__ float bf2f(unsigned short u) {
    return __uint_as_float(((unsigned)u) << 16);
}

__device__ __forceinline__ void gload16(const void* g, void* l) {
    __builtin_amdgcn_global_load_lds(
        (const __attribute__((address_space(1))) unsigned int*)g,
        (__attribute__((address_space(3))) unsigned int*)l, 16, 0, 0);
}

// three transposed-converts in one dispatch (y=0,1: Kab x Nab; y=2: Kc x Ncc)
__global__ void transconv3_kernel(const float* __restrict__ Wa, const float* __restrict__ Wb,
                                  const float* __restrict__ Wc,
                                  unsigned short* __restrict__ Ta, unsigned short* __restrict__ Tb,
                                  unsigned short* __restrict__ Tc,
                                  int Kab, int Nab, int Kc, int Ncc)
{
    int y = blockIdx.y;
    const float* W = (y == 0) ? Wa : ((y == 1) ? Wb : Wc);
    unsigned short* T = (y == 0) ? Ta : ((y == 1) ? Tb : Tc);
    int K = (y == 2) ? Kc : Kab;
    int Nc = (y == 2) ? Ncc : Nab;
    int gid = blockIdx.x * 256 + threadIdx.x;
    if (gid >= K * Nc) return;
    int k = gid / Nc, n = gid - k * Nc;
    T[(size_t)n * K + k] = f2bf(W[gid]);
}

// ---------------- L0 MFMA GEMM: A f32 (fused convert) @ Bt bf16^T + bias -> C bf16 ----------------
// A reg-staged (f32 loads for t+1 issued before t's MFMAs, converted, ds_write bf16);
// B global_load_lds double-buffered. 128x128 tile, BK=32, chunk-XOR LDS swizzle.
__global__ __launch_bounds__(256) void gemm_f32a_kernel(
    const float* __restrict__ A0, const float* __restrict__ A1,
    const unsigned short* __restrict__ Bt0, const unsigned short* __restrict__ Bt1,
    const float* __restrict__ bias0, const float* __restrict__ bias1,
    unsigned short* __restrict__ C0, unsigned short* __restrict__ C1,
    int M, int K, int Nc)
{
    __shared__ __align__(16) unsigned short As[2][128 * 32];
    __shared__ __align__(16) unsigned short Bs[2][128 * 32];
    const int z = blockIdx.z;
    const float* A = z ? A1 : A0;
    const unsigned short* Bt = z ? Bt1 : Bt0;
    const float* bias = z ? bias1 : bias0;
    unsigned short* C = z ? C1 : C0;
    const int t = threadIdx.x;
    const int lane = t & 63, w = t >> 6;
    const int wr = w >> 1, wc = w & 1;
    const int bm = blockIdx.y * 128, bn = blockIdx.x * 128;

    f32x4 acc[4][4];
    #pragma unroll
    for (int m = 0; m < 4; ++m)
        #pragma unroll
        for (int n = 0; n < 4; ++n)
            acc[m][n] = (f32x4){0.f, 0.f, 0.f, 0.f};

    const int c0 = w * 64 + lane, c1 = c0 + 256;
    const int row0 = c0 >> 2, row1 = c1 >> 2;
    const int g0 = (c0 & 3) ^ ((row0 >> 1) & 3);
    const int g1 = (c1 & 3) ^ ((row1 >> 1) & 3);
    const int ar0 = (bm + row0 < M) ? (bm + row0) : (M - 1);
    const int ar1 = (bm + row1 < M) ? (bm + row1) : (M - 1);
    const float* pAf0 = A + (size_t)ar0 * K + g0 * 8;
    const float* pAf1 = A + (size_t)ar1 * K + g1 * 8;
    const unsigned short* pB0 = Bt + (size_t)(bn + row0) * K + g0 * 8;
    const unsigned short* pB1 = Bt + (size_t)(bn + row1) * K + g1 * 8;

    const int rA = wr * 64 + (lane & 15);
    const int rB = wc * 64 + (lane & 15);
    const int gw = lane >> 4;
    const int nt = K >> 5;

    // prologue: tile 0
    {
        float4 a0 = *(const float4*)(pAf0);
        float4 b0 = *(const float4*)(pAf0 + 4);
        float4 a1 = *(const float4*)(pAf1);
        float4 b1 = *(const float4*)(pAf1 + 4);
        gload16(pB0, &Bs[0][c0 * 8]);
        gload16(pB1, &Bs[0][c1 * 8]);
        u16x8 o0, o1;
        o0[0] = f2bf(a0.x); o0[1] = f2bf(a0.y); o0[2] = f2bf(a0.z); o0[3] = f2bf(a0.w);
        o0[4] = f2bf(b0.x); o0[5] = f2bf(b0.y); o0[6] = f2bf(b0.z); o0[7] = f2bf(b0.w);
        o1[0] = f2bf(a1.x); o1[1] = f2bf(a1.y); o1[2] = f2bf(a1.z); o1[3] = f2bf(a1.w);
        o1[4] = f2bf(b1.x); o1[5] = f2bf(b1.y); o1[6] = f2bf(b1.z); o1[7] = f2bf(b1.w);
        *(u16x8*)&As[0][c0 * 8] = o0;
        *(u16x8*)&As[0][c1 * 8] = o1;
    }
    __syncthreads();

    for (int ti = 0; ti < nt; ++ti) {
        const int cur = ti & 1;
        const int nb = cur ^ 1;
        float4 a0, b0, a1, b1;
        bool pf = (ti + 1 < nt);
        if (pf) {
            const int nk = (ti + 1) << 5;
            a0 = *(const float4*)(pAf0 + nk);
            b0 = *(const float4*)(pAf0 + nk + 4);
            a1 = *(const float4*)(pAf1 + nk);
            b1 = *(const float4*)(pAf1 + nk + 4);
            gload16(pB0 + nk, &Bs[nb][c0 * 8]);
            gload16(pB1 + nk, &Bs[nb][c1 * 8]);
        }
        bf16x8 afr[4], bfr[4];
        #pragma unroll
        for (int m = 0; m < 4; ++m) {
            int r = rA + m * 16;
            afr[m] = *(const bf16x8*)&As[cur][r * 32 + ((gw ^ ((r >> 1) & 3)) * 8)];
        }
        #pragma unroll
        for (int n = 0; n < 4; ++n) {
            int r = rB + n * 16;
            bfr[n] = *(const bf16x8*)&Bs[cur][r * 32 + ((gw ^ ((r >> 1) & 3)) * 8)];
        }
        #pragma unroll
        for (int m = 0; m < 4; ++m)
            #pragma unroll
            for (int n = 0; n < 4; ++n)
                acc[m][n] = __builtin_amdgcn_mfma_f32_16x16x32_bf16(afr[m], bfr[n], acc[m][n], 0, 0, 0);
        if (pf) {
            u16x8 o0, o1;
            o0[0] = f2bf(a0.x); o0[1] = f2bf(a0.y); o0[2] = f2bf(a0.z); o0[3] = f2bf(a0.w);
            o0[4] = f2bf(b0.x); o0[5] = f2bf(b0.y); o0[6] = f2bf(b0.z); o0[7] = f2bf(b0.w);
            o1[0] = f2bf(a1.x); o1[1] = f2bf(a1.y); o1[2] = f2bf(a1.z); o1[3] = f2bf(a1.w);
            o1[4] = f2bf(b1.x); o1[5] = f2bf(b1.y); o1[6] = f2bf(b1.z); o1[7] = f2bf(b1.w);
            *(u16x8*)&As[nb][c0 * 8] = o0;
            *(u16x8*)&As[nb][c1 * 8] = o1;
        }
        __syncthreads();
    }
    #pragma unroll
    for (int m = 0; m < 4; ++m) {
        #pragma unroll
        for (int j = 0; j < 4; ++j) {
            int row = bm + wr * 64 + m * 16 + (lane >> 4) * 4 + j;
            if (row >= M) continue;
            #pragma unroll
            for (int n = 0; n < 4; ++n) {
                int col = bn + wc * 64 + n * 16 + (lane & 15);
                C[(size_t)row * Nc + col] = f2bf(acc[m][n][j] + bias[col]);
            }
        }
    }
}

// ---------------- MFMA GEMM (bf16 A), double-buffered ----------------
__global__ __launch_bounds__(256) void gemm_bf16_kernel(
    const unsigned short* __restrict__ A0, const unsigned short* __restrict__ A1,
    const unsigned short* __restrict__ Bt0, const unsigned short* __restrict__ Bt1,
    const float* __restrict__ bias0, const float* __restrict__ bias1,
    unsigned short* __restrict__ C0, unsigned short* __restrict__ C1,
    int M, int K, int Nc)
{
    __shared__ __align__(16) unsigned short As[2][128 * 32];
    __shared__ __align__(16) unsigned short Bs[2][128 * 32];
    const int z = blockIdx.z;
    const unsigned short* A  = z ? A1  : A0;
    const unsigned short* Bt = z ? Bt1 : Bt0;
    const float* bias = z ? bias1 : bias0;
    unsigned short* C = z ? C1 : C0;
    const int t = threadIdx.x;
    const int lane = t & 63, w = t >> 6;
    const int wr = w >> 1, wc = w & 1;
    const int bm = blockIdx.y * 128, bn = blockIdx.x * 128;

    f32x4 acc[4][4];
    #pragma unroll
    for (int m = 0; m < 4; ++m)
        #pragma unroll
        for (int n = 0; n < 4; ++n)
            acc[m][n] = (f32x4){0.f, 0.f, 0.f, 0.f};

    const int c0 = w * 64 + lane, c1 = c0 + 256;
    const int row0 = c0 >> 2, row1 = c1 >> 2;
    const int g0 = (c0 & 3) ^ ((row0 >> 1) & 3);
    const int g1 = (c1 & 3) ^ ((row1 >> 1) & 3);
    const int ar0 = (bm + row0 < M) ? (bm + row0) : (M - 1);
    const int ar1 = (bm + row1 < M) ? (bm + row1) : (M - 1);
    const unsigned short* pA0 = A + (size_t)ar0 * K + g0 * 8;
    const unsigned short* pA1 = A + (size_t)ar1 * K + g1 * 8;
    const unsigned short* pB0 = Bt + (size_t)(bn + row0) * K + g0 * 8;
    const unsigned short* pB1 = Bt + (size_t)(bn + row1) * K + g1 * 8;

    const int rA = wr * 64 + (lane & 15);
    const int rB = wc * 64 + (lane & 15);
    const int gw = lane >> 4;
    const int nt = K >> 5;

    gload16(pA0, &As[0][c0 * 8]);
    gload16(pA1, &As[0][c1 * 8]);
    gload16(pB0, &Bs[0][c0 * 8]);
    gload16(pB1, &Bs[0][c1 * 8]);
    __syncthreads();
    for (int ti = 0; ti < nt; ++ti) {
        const int cur = ti & 1;
        if (ti + 1 < nt) {
            const int nk = (ti + 1) << 5;
            const int nb = cur ^ 1;
            gload16(pA0 + nk, &As[nb][c0 * 8]);
            gload16(pA1 + nk, &As[nb][c1 * 8]);
            gload16(pB0 + nk, &Bs[nb][c0 * 8]);
            gload16(pB1 + nk, &Bs[nb][c1 * 8]);
        }
        bf16x8 afr[4], bfr[4];
        #pragma unroll
        for (int m = 0; m < 4; ++m) {
            int r = rA + m * 16;
            afr[m] = *(const bf16x8*)&As[cur][r * 32 + ((gw ^ ((r >> 1) & 3)) * 8)];
        }
        #pragma unroll
        for (int n = 0; n < 4; ++n) {
            int r = rB + n * 16;
            bfr[n] = *(const bf16x8*)&Bs[cur][r * 32 + ((gw ^ ((r >> 1) & 3)) * 8)];
        }
        #pragma unroll
        for (int m = 0; m < 4; ++m)
            #pragma unroll
            for (int n = 0; n < 4; ++n)
                acc[m][n] = __builtin_amdgcn_mfma_f32_16x16x32_bf16(afr[m], bfr[n], acc[m][n], 0, 0, 0);
        __syncthreads();
    }
    #pragma unroll
    for (int m = 0; m < 4; ++m) {
        #pragma unroll
        for (int j = 0; j < 4; ++j) {
            int row = bm + wr * 64 + m * 16 + (lane >> 4) * 4 + j;
            if (row >= M) continue;
            #pragma unroll
            for (int n = 0; n < 4; ++n) {
                int col = bn + wc * 64 + n * 16 + (lane & 15);
                C[(size_t)row * Nc + col] = f2bf(acc[m][n][j] + bias[col]);
            }
        }
    }
}

// ---------------- sem GEMM: partial[c] += sum_rows tanh( A @ Wkt^T + bk )[c] ----------------
__global__ __launch_bounds__(256) void sem_bf16_kernel(
    const unsigned short* __restrict__ A, const unsigned short* __restrict__ Bt,
    const float* __restrict__ bk, float* __restrict__ partial,
    int M, int K, int Nc)
{
    __shared__ __align__(16) unsigned short As[2][128 * 32];
    __shared__ __align__(16) unsigned short Bs[2][128 * 32];
    __shared__ float red[128];
    const int t = threadIdx.x;
    const int lane = t & 63, w = t >> 6;
    const int wr = w >> 1, wc = w & 1;
    const int bm = blockIdx.y * 128, bn = blockIdx.x * 128;

    f32x4 acc[4][4];
    #pragma unroll
    for (int m = 0; m < 4; ++m)
        #pragma unroll
        for (int n = 0; n < 4; ++n)
            acc[m][n] = (f32x4){0.f, 0.f, 0.f, 0.f};

    const int c0 = w * 64 + lane, c1 = c0 + 256;
    const int row0 = c0 >> 2, row1 = c1 >> 2;
    const int g0 = (c0 & 3) ^ ((row0 >> 1) & 3);
    const int g1 = (c1 & 3) ^ ((row1 >> 1) & 3);
    const int ar0 = (bm + row0 < M) ? (bm + row0) : (M - 1);
    const int ar1 = (bm + row1 < M) ? (bm + row1) : (M - 1);
    const unsigned short* pA0 = A + (size_t)ar0 * K + g0 * 8;
    const unsigned short* pA1 = A + (size_t)ar1 * K + g1 * 8;
    const unsigned short* pB0 = Bt + (size_t)(bn + row0) * K + g0 * 8;
    const unsigned short* pB1 = Bt + (size_t)(bn + row1) * K + g1 * 8;

    const int rA = wr * 64 + (lane & 15);
    const int rB = wc * 64 + (lane & 15);
    const int gw = lane >> 4;
    const int nt = K >> 5;

    gload16(pA0, &As[0][c0 * 8]);
    gload16(pA1, &As[0][c1 * 8]);
    gload16(pB0, &Bs[0][c0 * 8]);
    gload16(pB1, &Bs[0][c1 * 8]);
    __syncthreads();
    for (int ti = 0; ti < nt; ++ti) {
        const int cur = ti & 1;
        if (ti + 1 < nt) {
            const int nk = (ti + 1) << 5;
            const int nb = cur ^ 1;
            gload16(pA0 + nk, &As[nb][c0 * 8]);
            gload16(pA1 + nk, &As[nb][c1 * 8]);
            gload16(pB0 + nk, &Bs[nb][c0 * 8]);
            gload16(pB1 + nk, &Bs[nb][c1 * 8]);
        }
        bf16x8 afr[4], bfr[4];
        #pragma unroll
        for (int m = 0; m < 4; ++m) {
            int r = rA + m * 16;
            afr[m] = *(const bf16x8*)&As[cur][r * 32 + ((gw ^ ((r >> 1) & 3)) * 8)];
        }
        #pragma unroll
        for (int n = 0; n < 4; ++n) {
            int r = rB + n * 16;
            bfr[n] = *(const bf16x8*)&Bs[cur][r * 32 + ((gw ^ ((r >> 1) & 3)) * 8)];
        }
        #pragma unroll
        for (int m = 0; m < 4; ++m)
            #pragma unroll
            for (int n = 0; n < 4; ++n)
                acc[m][n] = __builtin_amdgcn_mfma_f32_16x16x32_bf16(afr[m], bfr[n], acc[m][n], 0, 0, 0);
        __syncthreads();
    }
    if (t < 128) red[t] = 0.f;
    __syncthreads();
    #pragma unroll
    for (int n = 0; n < 4; ++n) {
        int lcol = wc * 64 + n * 16 + (lane & 15);
        float b = bk[bn + lcol];
        float s = 0.f;
        #pragma unroll
        for (int m = 0; m < 4; ++m) {
            #pragma unroll
            for (int j = 0; j < 4; ++j) {
                int row = bm + wr * 64 + m * 16 + (lane >> 4) * 4 + j;
                if (row < M) s += tanhf(acc[m][n][j] + b);
            }
        }
        atomicAdd(&red[lcol], s);
    }
    __syncthreads();
    if (t < 128) atomicAdd(&partial[bn + t], red[t]);
}

// ---------------- batched CSR build ----------------
__global__ void hist3_kernel(const int* __restrict__ d0, const int* __restrict__ d1,
                             const int* __restrict__ d2, int* __restrict__ deg3)
{
    int gid = blockIdx.x * 256 + threadIdx.x;
    if (gid >= 3 * NE) return;
    int rel = gid / NE, e = gid - rel * NE;
    const int* dst = (rel == 0) ? d0 : ((rel == 1) ? d1 : d2);
    atomicAdd(&deg3[rel * NN + dst[e]], 1);
}

__global__ void block_sum3_kernel(const int* __restrict__ deg3, int* __restrict__ bsum3)
{
    __shared__ int buf[256];
    int rel = blockIdx.y;
    int i = blockIdx.x * 256 + threadIdx.x;
    buf[threadIdx.x] = (i < NN) ? deg3[rel * NN + i] : 0;
    __syncthreads();
    for (int s = 128; s > 0; s >>= 1) {
        if (threadIdx.x < s) buf[threadIdx.x] += buf[threadIdx.x + s];
        __syncthreads();
    }
    if (threadIdx.x == 0) bsum3[rel * 256 + blockIdx.x] = buf[0];
}

__global__ void scan_bsum3_kernel(const int* __restrict__ bsum3, int* __restrict__ boff3, int nb)
{
    __shared__ int buf[256];
    int rel = blockIdx.y;
    int tid = threadIdx.x;
    int v = (tid < nb) ? bsum3[rel * 256 + tid] : 0;
    buf[tid] = v;
    __syncthreads();
    for (int off = 1; off < 256; off <<= 1) {
        int t = (tid >= off) ? buf[tid - off] : 0;
        __syncthreads();
        buf[tid] += t;
        __syncthreads();
    }
    if (tid < nb) boff3[rel * 256 + tid] = buf[tid] - v;
}

__global__ void scan_final3_kernel(const int* __restrict__ deg3, const int* __restrict__ boff3,
                                   int* __restrict__ offs3)
{
    __shared__ int buf[256];
    int rel = blockIdx.y;
    int tid = threadIdx.x, b = blockIdx.x;
    int i = b * 256 + tid;
    int v = (i < NN) ? deg3[rel * NN + i] : 0;
    buf[tid] = v;
    __syncthreads();
    for (int off = 1; off < 256; off <<= 1) {
        int t = (tid >= off) ? buf[tid - off] : 0;
        __syncthreads();
        buf[tid] += t;
        __syncthreads();
    }
    int* offs = offs3 + rel * OFFST;
    if (i < NN) offs[i] = boff3[rel * 256 + b] + buf[tid] - v;
    if (i == NN - 1) offs[NN] = boff3[rel * 256 + b] + buf[tid];
}

__global__ void place3_kernel(const int* __restrict__ s0, const int* __restrict__ s1,
                              const int* __restrict__ s2,
                              const int* __restrict__ offs3, int* __restrict__ cnt3,
                              int* __restrict__ esrc3)
{
    int rel = blockIdx.y;
    int e = blockIdx.x * 256 + threadIdx.x;
    if (e >= NE) return;
    const int* srcdst = (rel == 0) ? s0 : ((rel == 1) ? s1 : s2);
    int src = srcdst[e];
    int d = srcdst[NE + e];
    int p = offs3[rel * OFFST + d] + atomicAdd(&cnt3[rel * NN + d], 1);
    esrc3[rel * NE + p] = src;
}

// ---------------- fused per-layer node scores ----------------
__global__ void scores_L0_kernel(
    const unsigned short* __restrict__ xp, const unsigned short* __restrict__ xa,
    const float* __restrict__ a_dw, const float* __restrict__ a_swb,
    const float* __restrict__ a_sc, const float* __restrict__ a_dc,
    const float* __restrict__ a_sw, const float* __restrict__ a_dwb,
    float* __restrict__ sW_dst, float* __restrict__ sWB_src,
    float* __restrict__ sC_src, float* __restrict__ sC_dst,
    float* __restrict__ sW_src, float* __restrict__ sWB_dst)
{
    int gid = blockIdx.x * 256 + threadIdx.x;
    int half = NN * H0;
    if (gid >= 2 * half) return;
    if (gid < half) {
        int node = gid >> 3, h = gid & 7;
        const unsigned short* xr = xp + (size_t)node * DHID + h * D0;
        float xv[D0];
        #pragma unroll
        for (int j = 0; j < 4; ++j) {
            u16x8 v = ((const u16x8*)xr)[j];
            #pragma unroll
            for (int k = 0; k < 8; ++k) xv[j * 8 + k] = bf2f(v[k]);
        }
        const float* p0 = a_dw  + h * D0;
        const float* p1 = a_swb + h * D0;
        const float* p2 = a_sc  + h * D0;
        const float* p3 = a_dc  + h * D0;
        float d0 = 0.f, d1 = 0.f, d2 = 0.f, d3 = 0.f;
        #pragma unroll
        for (int k = 0; k < D0; ++k) {
            float x = xv[k];
            d0 += x * p0[k]; d1 += x * p1[k]; d2 += x * p2[k]; d3 += x * p3[k];
        }
        sW_dst[gid] = d0; sWB_src[gid] = d1; sC_src[gid] = d2; sC_dst[gid] = d3;
    } else {
        int g = gid - half;
        int node = g >> 3, h = g & 7;
        const unsigned short* xr = xa + (size_t)node * DHID + h * D0;
        float xv[D0];
        #pragma unroll
        for (int j = 0; j < 4; ++j) {
            u16x8 v = ((const u16x8*)xr)[j];
            #pragma unroll
            for (int k = 0; k < 8; ++k) xv[j * 8 + k] = bf2f(v[k]);
        }
        const float* p0 = a_sw  + h * D0;
        const float* p1 = a_dwb + h * D0;
        float d0 = 0.f, d1 = 0.f;
        #pragma unroll
        for (int k = 0; k < D0; ++k) {
            float x = xv[k];
            d0 += x * p0[k]; d1 += x * p1[k];
        }
        sW_src[g] = d0; sWB_dst[g] = d1;
    }
}

__global__ void scores_L1_kernel(
    const unsigned short* __restrict__ xp, const unsigned short* __restrict__ xa,
    const float* __restrict__ a_dw, const float* __restrict__ a_swb,
    const float* __restrict__ a_sc, const float* __restrict__ a_dc,
    const float* __restrict__ a_sw, const float* __restrict__ a_dwb,
    float* __restrict__ sW_dst, float* __restrict__ sWB_src,
    float* __restrict__ sC_src, float* __restrict__ sC_dst,
    float* __restrict__ sW_src, float* __restrict__ sWB_dst)
{
    int gid = blockIdx.x * 256 + threadIdx.x;
    if (gid >= 2 * NN) return;
    if (gid < NN) {
        const unsigned short* xr = xp + (size_t)gid * DOUT;
        float d0 = 0.f, d1 = 0.f, d2 = 0.f, d3 = 0.f;
        for (int j = 0; j < DOUT / 8; ++j) {
            u16x8 v = ((const u16x8*)xr)[j];
            #pragma unroll
            for (int k = 0; k < 8; ++k) {
                float x = bf2f(v[k]);
                int c = j * 8 + k;
                d0 += x * a_dw[c]; d1 += x * a_swb[c]; d2 += x * a_sc[c]; d3 += x * a_dc[c];
            }
        }
        sW_dst[gid] = d0; sWB_src[gid] = d1; sC_src[gid] = d2; sC_dst[gid] = d3;
    } else {
        int g = gid - NN;
        const unsigned short* xr = xa + (size_t)g * DOUT;
        float d0 = 0.f, d1 = 0.f;
        for (int j = 0; j < DOUT / 8; ++j) {
            u16x8 v = ((const u16x8*)xr)[j];
            #pragma unroll
            for (int k = 0; k < 8; ++k) {
                float x = bf2f(v[k]);
                int c = j * 8 + k;
                d0 += x * a_sw[c]; d1 += x * a_dwb[c];
            }
        }
        sW_src[g] = d0; sWB_dst[g] = d1;
    }
}

// ---------------- batched per-(dst,head) segment softmax -> alpha ----------------
__global__ void seg_alpha3_kernel(
    const int* __restrict__ offs3, const int* __restrict__ esrc3,
    const float* __restrict__ ss0, const float* __restrict__ ss1, const float* __restrict__ ss2,
    const float* __restrict__ sd0, const float* __restrict__ sd1, const float* __restrict__ sd2,
    float* __restrict__ alpha3, int H)
{
    int rel = blockIdx.y;
    const int* offs = offs3 + rel * OFFST;
    const int* esrc = esrc3 + rel * NE;
    const float* ssrc = (rel == 0) ? ss0 : ((rel == 1) ? ss1 : ss2);
    const float* sdst = (rel == 0) ? sd0 : ((rel == 1) ? sd1 : sd2);
    float* alpha = alpha3 + (size_t)rel * NE * H0;
    int gid = blockIdx.x * 256 + threadIdx.x;
    if (gid >= NN * H) return;
    int d = gid / H, h = gid - d * H;
    int beg = offs[d], end = offs[d + 1];
    float sd = sdst[gid];
    float m = -INFINITY, den = 0.f;
    for (int i = beg; i < end; ++i) {
        int s = esrc[i];
        float v = ssrc[s * H + h] + sd;
        v = (v >= 0.f) ? v : 0.2f * v;
        if (v > m) { den = den * expf(m - v) + 1.f; m = v; }
        else       den += expf(v - m);
    }
    float inv = 1.f / (den + 1e-16f);
    for (int i = beg; i < end; ++i) {
        int s = esrc[i];
        float v = ssrc[s * H + h] + sd;
        v = (v >= 0.f) ? v : 0.2f * v;
        alpha[(size_t)i * H + h] = expf(v - m) * inv;
    }
}

// ---------------- batched weighted gather, 2-deep software pipeline ----------------
template<int CPL, int HH, int DSH>
__global__ __launch_bounds__(256) void gather3_kernel(
    const int* __restrict__ offs3, const int* __restrict__ esrc3,
    const float* __restrict__ alpha3,
    const unsigned short* __restrict__ x0, const unsigned short* __restrict__ x1,
    const unsigned short* __restrict__ x2,
    unsigned short* __restrict__ o0, unsigned short* __restrict__ o1,
    unsigned short* __restrict__ o2, int C)
{
    int rel = blockIdx.y;
    const int* offs = offs3 + rel * OFFST;
    const int* esrc = esrc3 + rel * NE;
    const float* alpha = alpha3 + (size_t)rel * NE * H0;
    const unsigned short* x = (rel == 0) ? x0 : ((rel == 1) ? x1 : x2);
    unsigned short* outp = (rel == 0) ? o0 : ((rel == 1) ? o1 : o2);

    int wid = threadIdx.x >> 6, lane = threadIdx.x & 63;
    int d = blockIdx.x * 4 + wid;
    int c0 = lane * CPL;
    int h = c0 >> DSH;
    int beg = offs[d], end = offs[d + 1];
    float acc0 = 0.f, acc1 = 0.f, acc2 = 0.f, acc3 = 0.f;
    int n = end - beg;
    if (n > 0) {
        int sA = esrc[beg];
        float aA = alpha[(size_t)beg * HH + h];
        int sB = sA; float aB = 0.f;
        if (n > 1) { sB = esrc[beg + 1]; aB = alpha[(size_t)(beg + 1) * HH + h]; }
        if (CPL == 4) {
            ushort4 xc = *(const ushort4*)(x + (size_t)sA * C + c0);
            for (int i = beg; i < end; ++i) {
                ushort4 xn = xc;
                if (i + 1 < end) xn = *(const ushort4*)(x + (size_t)sB * C + c0);
                int sN = sB; float aN = 0.f;
                if (i + 2 < end) { sN = esrc[i + 2]; aN = alpha[(size_t)(i + 2) * HH + h]; }
                acc0 += aA * bf2f(xc.x); acc1 += aA * bf2f(xc.y);
                acc2 += aA * bf2f(xc.z); acc3 += aA * bf2f(xc.w);
                xc = xn; aA = aB; sB = sN; aB = aN;
            }
        } else {
            ushort2 xc = *(const ushort2*)(x + (size_t)sA * C + c0);
            for (int i = beg; i < end; ++i) {
                ushort2 xn = xc;
                if (i + 1 < end) xn = *(const ushort2*)(x + (size_t)sB * C + c0);
                int sN = sB; float aN = 0.f;
                if (i + 2 < end) { sN = esrc[i + 2]; aN = alpha[(size_t)(i + 2) * HH + h]; }
                acc0 += aA * bf2f(xc.x); acc1 += aA * bf2f(xc.y);
                xc = xn; aA = aB; sB = sN; aB = aN;
            }
        }
    }
    unsigned short* op = outp + (size_t)d * C + c0;
    if (CPL == 4) {
        ushort4 st;
        st.x = f2bf(fmaxf(acc0, 0.f)); st.y = f2bf(fmaxf(acc1, 0.f));
        st.z = f2bf(fmaxf(acc2, 0.f)); st.w = f2bf(fmaxf(acc3, 0.f));
        *(ushort4*)op = st;
    } else {
        ushort2 st;
        st.x = f2bf(fmaxf(acc0, 0.f)); st.y = f2bf(fmaxf(acc1, 0.f));
        *(ushort2*)op = st;
    }
}

__global__ void sem_weights_kernel(const float* __restrict__ partial, const float* __restrict__ q,
                                   float* __restrict__ w, int C, int n)
{
    if (threadIdx.x != 0 || blockIdx.x != 0) return;
    float inv = 1.f / (float)n;
    float s0 = 0.f, s1 = 0.f;
    for (int c = 0; c < C; ++c) {
        s0 += q[c] * partial[c] * inv;
        s1 += q[c] * partial[C + c] * inv;
    }
    float m = fmaxf(s0, s1);
    float e0 = expf(s0 - m), e1 = expf(s1 - m);
    float den = e0 + e1;
    w[0] = e0 / den;
    w[1] = e1 / den;
}

__global__ void combine2_bf16_kernel(const unsigned short* __restrict__ a,
                                     const unsigned short* __restrict__ b,
                                     const float* __restrict__ w, unsigned short* __restrict__ out,
                                     int n8)
{
    int i = blockIdx.x * 256 + threadIdx.x;
    if (i >= n8) return;
    float w0 = w[0], w1 = w[1];
    u16x8 va = ((const u16x8*)a)[i];
    u16x8 vb = ((const u16x8*)b)[i];
    u16x8 o;
    #pragma unroll
    for (int j = 0; j < 8; ++j) o[j] = f2bf(w0 * bf2f(va[j]) + w1 * bf2f(vb[j]));
    ((u16x8*)out)[i] = o;
}

__global__ __launch_bounds__(128) void final_norm_kernel(
    const unsigned short* __restrict__ aggW, const unsigned short* __restrict__ aggC,
    const unsigned short* __restrict__ aggB, const float* __restrict__ w,
    float* __restrict__ out)
{
    __shared__ float red[128];
    int row = blockIdx.x;
    int c = threadIdx.x;
    float v;
    if (row < NN) {
        size_t i = (size_t)row * DOUT + c;
        v = w[0] * bf2f(aggW[i]) + w[1] * bf2f(aggC[i]);
    } else {
        size_t i = (size_t)(row - NN) * DOUT + c;
        v = bf2f(aggB[i]);
    }
    red[c] = v * v;
    __syncthreads();
    for (int s = 64; s > 0; s >>= 1) {
        if (c < s) red[c] += red[c + s];
        __syncthreads();
    }
    float norm = sqrtf(red[0]);
    out[(size_t)row * DOUT + c] = v / fmaxf(norm, 1e-12f);
}

// ------------------------------------------------------------------
extern "C" void kernel_launch(void* const* d_in, const int* in_sizes, int n_in,
                              void* d_out, int out_size, void* d_ws, size_t ws_size,
                              hipStream_t stream)
{
    const float* x_paper   = (const float*)d_in[0];
    const float* x_author  = (const float*)d_in[1];
    const int*   ei_writes = (const int*)d_in[2];
    const int*   ei_wb     = (const int*)d_in[3];
    const int*   ei_cites  = (const int*)d_in[4];
    const float* W0p = (const float*)d_in[5];  const float* b0p = (const float*)d_in[6];
    const float* W0a = (const float*)d_in[7];  const float* b0a = (const float*)d_in[8];
    const float* a0s_w  = (const float*)d_in[9];  const float* a0d_w  = (const float*)d_in[10];
    const float* a0s_wb = (const float*)d_in[11]; const float* a0d_wb = (const float*)d_in[12];
    const float* a0s_c  = (const float*)d_in[13]; const float* a0d_c  = (const float*)d_in[14];
    const float* Wk0 = (const float*)d_in[15]; const float* bk0 = (const float*)d_in[16];
    const float* q0  = (const float*)d_in[17];
    const float* W1p = (const float*)d_in[18]; const float* b1p = (const float*)d_in[19];
    const float* W1a = (const float*)d_in[20]; const float* b1a = (const float*)d_in[21];
    const float* a1s_w  = (const float*)d_in[22]; const float* a1d_w  = (const float*)d_in[23];
    const float* a1s_wb = (const float*)d_in[24]; const float* a1d_wb = (const float*)d_in[25];
    const float* a1s_c  = (const float*)d_in[26]; const float* a1d_c  = (const float*)d_in[27];
    const float* Wk1 = (const float*)d_in[28]; const float* bk1 = (const float*)d_in[29];
    const float* q1  = (const float*)d_in[30];

    float* out = (float*)d_out;

    const size_t NH = (size_t)NN * DHID;
    const size_t NI = (size_t)NN * DIN;
    const size_t NO = (size_t)NN * DOUT;
    const size_t NH2 = NH * 2;
    const size_t NI2 = NI * 2;
    const size_t NO2 = NO * 2;

    char* base = (char*)d_ws;
    unsigned short* xbhP = (unsigned short*)(base + 0);
    unsigned short* xbhA = (unsigned short*)(base + NH2);
    unsigned short* aggW = (unsigned short*)(base + 2 * NH2);
    unsigned short* aggC = (unsigned short*)(base + 3 * NH2);
    unsigned short* aggB = (unsigned short*)(base + 4 * NH2);
    unsigned short* hbP  = (unsigned short*)(base + 0);
    unsigned short* hbA  = aggB;
    unsigned short* x1Pb = (unsigned short*)(base + NH2);
    unsigned short* x1Ab = (unsigned short*)(base + NH2 + NO2);
    unsigned short* agg1W = (unsigned short*)(base + 2 * NH2 + NI2);
    unsigned short* agg1C = (unsigned short*)(base + 2 * NH2 + NI2 + NO2);
    unsigned short* agg1B = (unsigned short*)(base + 2 * NH2 + NI2 + 2 * NO2);

    float* sW_src  = (float*)(base + 204800000);
    float* sW_dst  = sW_src  + NN * H0;
    float* sWB_src = sW_dst  + NN * H0;
    float* sWB_dst = sWB_src + NN * H0;
    float* sC_src  = sWB_dst + NN * H0;
    float* sC_dst  = sC_src  + NN * H0;
    float* alpha3  = (float*)(base + 214400000);     // 3 * NE * H0 f32 = 28.8MB
    int* ip     = (int*)(base + 243200000);
    int* offs3  = ip;  ip += 3 * OFFST;
    int* esrc3  = ip;  ip += 3 * NE;
    int* deg3   = ip;  ip += 3 * NN;
    int* bsum3  = ip;  ip += 3 * 256;
    int* boff3  = ip;  ip += 3 * 256;
    unsigned short* wt0p = (unsigned short*)ip;
    unsigned short* wt0a = wt0p + (size_t)DHID * DIN;
    unsigned short* wkt  = wt0a + (size_t)DHID * DIN;
    unsigned short* wt1p = wt0p;
    unsigned short* wt1a = wt1p + (size_t)DOUT * DHID;
    float* tsum = (float*)(wkt + (size_t)DHID * DHID);
    float* wsem = tsum + 512;

    const int NB = (NN + 255) / 256;

    // ---- CSR build (all 3 relations, batched) ----
    hipMemsetAsync(deg3, 0, 3 * NN * sizeof(int), stream);
    hist3_kernel<<<(3 * NE + 255) / 256, 256, 0, stream>>>(ei_writes + NE, ei_wb + NE, ei_cites + NE, deg3);
    block_sum3_kernel<<<dim3(NB, 3), 256, 0, stream>>>(deg3, bsum3);
    scan_bsum3_kernel<<<dim3(1, 3), 256, 0, stream>>>(bsum3, boff3, NB);
    scan_final3_kernel<<<dim3(NB, 3), 256, 0, stream>>>(deg3, boff3, offs3);
    hipMemsetAsync(deg3, 0, 3 * NN * sizeof(int), stream);
    place3_kernel<<<dim3((NE + 255) / 256, 3), 256, 0, stream>>>(ei_writes, ei_wb, ei_cites, offs3, deg3, esrc3);

    // ================= layer 0 =================
    hipMemsetAsync(tsum, 0, 512 * sizeof(float), stream);
    transconv3_kernel<<<dim3((DIN * DHID + 255) / 256, 3), 256, 0, stream>>>(
        W0p, W0a, Wk0, wt0p, wt0a, wkt, DIN, DHID, DHID, DHID);

    dim3 g0(DHID / 128, (NN + 127) / 128, 2);
    gemm_f32a_kernel<<<g0, 256, 0, stream>>>(x_paper, x_author, wt0p, wt0a, b0p, b0a, xbhP, xbhA, NN, DIN, DHID);

    scores_L0_kernel<<<(2 * NN * H0 + 255) / 256, 256, 0, stream>>>(
        xbhP, xbhA, a0d_w, a0s_wb, a0s_c, a0d_c, a0s_w, a0d_wb,
        sW_dst, sWB_src, sC_src, sC_dst, sW_src, sWB_dst);
    dim3 ga0((NN * H0 + 255) / 256, 3);
    seg_alpha3_kernel<<<ga0, 256, 0, stream>>>(
        offs3, esrc3, sW_src, sWB_src, sC_src, sW_dst, sWB_dst, sC_dst, alpha3, H0);
    dim3 gg0(NN / 4, 3);
    gather3_kernel<4, H0, 5><<<gg0, 256, 0, stream>>>(
        offs3, esrc3, alpha3, xbhA, xbhP, xbhP, aggW, aggB, aggC, DHID);

    dim3 gs0(DHID / 128, (NN + 127) / 128);
    sem_bf16_kernel<<<gs0, 256, 0, stream>>>(aggW, wkt, bk0, tsum,        NN, DHID, DHID);
    sem_bf16_kernel<<<gs0, 256, 0, stream>>>(aggC, wkt, bk0, tsum + DHID, NN, DHID, DHID);
    sem_weights_kernel<<<1, 64, 0, stream>>>(tsum, q0, wsem, DHID, NN);

    combine2_bf16_kernel<<<(int)((NH / 8 + 255) / 256), 256, 0, stream>>>(aggW, aggC, wsem, hbP, (int)(NH / 8));

    // ================= layer 1 =================
    transconv3_kernel<<<dim3((DHID * DOUT + 255) / 256, 3), 256, 0, stream>>>(
        W1p, W1a, Wk1, wt1p, wt1a, wkt, DHID, DOUT, DOUT, DOUT);

    dim3 g1(DOUT / 128, (NN + 127) / 128, 2);
    gemm_bf16_kernel<<<g1, 256, 0, stream>>>(hbP, hbA, wt1p, wt1a, b1p, b1a, x1Pb, x1Ab, NN, DHID, DOUT);

    hipMemsetAsync(tsum, 0, 2 * DOUT * sizeof(float), stream);

    scores_L1_kernel<<<(2 * NN + 255) / 256, 256, 0, stream>>>(
        x1Pb, x1Ab, a1d_w, a1s_wb, a1s_c, a1d_c, a1s_w, a1d_wb,
        sW_dst, sWB_src, sC_src, sC_dst, sW_src, sWB_dst);
    dim3 ga1((NN + 255) / 256, 3);
    seg_alpha3_kernel<<<ga1, 256, 0, stream>>>(
        offs3, esrc3, sW_src, sWB_src, sC_src, sW_dst, sWB_dst, sC_dst, alpha3, 1);
    dim3 gg1(NN / 4, 3);
    gather3_kernel<2, 1, 7><<<gg1, 256, 0, stream>>>(
        offs3, esrc3, alpha3, x1Ab, x1Pb, x1Pb, agg1W, agg1B, agg1C, DOUT);

    dim3 gs1(DOUT / 128, (NN + 127) / 128);
    sem_bf16_kernel<<<gs1, 256, 0, stream>>>(agg1W, wkt, bk1, tsum,        NN, DOUT, DOUT);
    sem_bf16_kernel<<<gs1, 256, 0, stream>>>(agg1C, wkt, bk1, tsum + DOUT, NN, DOUT, DOUT);
    sem_weights_kernel<<<1, 64, 0, stream>>>(tsum, q1, wsem, DOUT, NN);

    final_norm_kernel<<<2 * NN, 128, 0, stream>>>(agg1W, agg1C, agg1B, wsem, out);
}